// Round 2
// baseline (2646.052 us; speedup 1.0000x reference)
//
#include <hip/hip_runtime.h>
#include <hip/hip_bf16.h>
#include <math.h>

#define D_MODEL   768
#define D_SSM     1536
#define D_STATE   128
#define D_CONV    4
#define HEADDIM   64
#define NHEADS    24
#define CONV_DIM  1792          // D_SSM + 2*D_STATE
#define D_IN_PROJ 3352          // 2*D_SSM + 2*D_STATE + NHEADS
#define BATCH     4
#define SEQLEN    2048
#define NROWS     (BATCH * SEQLEN)   // 8192
#define EPS       1e-5f

__device__ __forceinline__ float sigmoidf_(float x) {
    return 1.0f / (1.0f + __expf(-x));
}

// ---------------------------------------------------------------------------
// GEMM (NT): C[M,N] = A[M,K] * B[N,K]^T, all row-major, K contiguous in both.
// 64x64 tile, BK=16, 256 threads, 4x4 per thread, transposed-k LDS layout.
// ---------------------------------------------------------------------------
template<int BM, int BN, int BK>
__global__ __launch_bounds__(256) void gemm_nt(
    const float* __restrict__ A, const float* __restrict__ B,
    float* __restrict__ C, int M, int N, int K)
{
    __shared__ float As[BK][BM];
    __shared__ float Bs[BK][BN];
    const int tid = threadIdx.x;
    const int bm  = blockIdx.y * BM;
    const int bn  = blockIdx.x * BN;
    const int tm  = (tid & 15) << 2;   // 0..60
    const int tn  = (tid >> 4) << 2;   // 0..60
    const int am  = tid & 63;          // row within tile
    const int ak  = (tid >> 6) << 2;   // k offset (float4)

    float acc[4][4] = {};

    for (int k0 = 0; k0 < K; k0 += BK) {
        const float4 av = *(const float4*)(A + (size_t)(bm + am) * K + (k0 + ak));
        float4 bv = make_float4(0.f, 0.f, 0.f, 0.f);
        if (bn + am < N)
            bv = *(const float4*)(B + (size_t)(bn + am) * K + (k0 + ak));
        __syncthreads();   // previous iteration's reads finished
        As[ak + 0][am] = av.x; As[ak + 1][am] = av.y;
        As[ak + 2][am] = av.z; As[ak + 3][am] = av.w;
        Bs[ak + 0][am] = bv.x; Bs[ak + 1][am] = bv.y;
        Bs[ak + 2][am] = bv.z; Bs[ak + 3][am] = bv.w;
        __syncthreads();
#pragma unroll
        for (int kk = 0; kk < BK; ++kk) {
            const float4 a4 = *(const float4*)&As[kk][tm];
            const float4 b4 = *(const float4*)&Bs[kk][tn];
            const float a[4]  = {a4.x, a4.y, a4.z, a4.w};
            const float bb[4] = {b4.x, b4.y, b4.z, b4.w};
#pragma unroll
            for (int i = 0; i < 4; ++i)
#pragma unroll
                for (int j = 0; j < 4; ++j)
                    acc[i][j] = fmaf(a[i], bb[j], acc[i][j]);
        }
    }
#pragma unroll
    for (int i = 0; i < 4; ++i)
#pragma unroll
        for (int j = 0; j < 4; ++j) {
            const int cn = bn + tn + j;
            if (cn < N)
                C[(size_t)(bm + tm + i) * N + cn] = acc[i][j];
        }
}

// ---------------------------------------------------------------------------
// Depthwise causal conv (width 4) + bias + SiLU over the xBC slice of zxbcdt.
// One thread per (row, 4 channels).
// ---------------------------------------------------------------------------
__global__ __launch_bounds__(256) void conv_silu_kernel(
    const float* __restrict__ zx, const float* __restrict__ cw,
    const float* __restrict__ cb, float* __restrict__ xc)
{
    const int idx = blockIdx.x * 256 + threadIdx.x;
    if (idx >= NROWS * (CONV_DIM / 4)) return;
    const int row = idx / (CONV_DIM / 4);
    const int c   = (idx % (CONV_DIM / 4)) * 4;
    const int l   = row & (SEQLEN - 1);

    const float* base = zx + (size_t)row * D_IN_PROJ + D_SSM + c;
    const float4 cbv = *(const float4*)(cb + c);
    float acc[4] = {cbv.x, cbv.y, cbv.z, cbv.w};
    const float* w = cw + (size_t)c * D_CONV;   // w[(c+i)*4 + k]
#pragma unroll
    for (int k = 0; k < D_CONV; ++k) {
        const int ls = l + k - 3;
        if (ls >= 0) {
            const float4 xv = *(const float4*)(base + (ptrdiff_t)(k - 3) * D_IN_PROJ);
            acc[0] = fmaf(w[0 * D_CONV + k], xv.x, acc[0]);
            acc[1] = fmaf(w[1 * D_CONV + k], xv.y, acc[1]);
            acc[2] = fmaf(w[2 * D_CONV + k], xv.z, acc[2]);
            acc[3] = fmaf(w[3 * D_CONV + k], xv.w, acc[3]);
        }
    }
    float4 o;
    o.x = acc[0] * sigmoidf_(acc[0]);
    o.y = acc[1] * sigmoidf_(acc[1]);
    o.z = acc[2] * sigmoidf_(acc[2]);
    o.w = acc[3] * sigmoidf_(acc[3]);
    *(float4*)(xc + (size_t)row * CONV_DIM + c) = o;
}

// ---------------------------------------------------------------------------
// dt = softplus(dt_raw + dt_bias) : (NROWS, NHEADS)
// ---------------------------------------------------------------------------
__global__ __launch_bounds__(64) void dt_kernel(
    const float* __restrict__ zx, const float* __restrict__ dt_bias,
    float* __restrict__ dtw)
{
    const int row = blockIdx.x;
    const int tid = threadIdx.x;
    if (tid < NHEADS) {
        const float x = zx[(size_t)row * D_IN_PROJ + (D_SSM + CONV_DIM) + tid] + dt_bias[tid];
        const float sp = fmaxf(x, 0.f) + log1pf(__expf(-fabsf(x)));
        dtw[(size_t)row * NHEADS + tid] = sp;
    }
}

// ---------------------------------------------------------------------------
// Selective scan. One block per (b, h). 256 threads.
// thread t: p = t>>2 (0..63), q = t&3 -> n in [q*32, q*32+32).
// h state: 32 regs/thread. B/C/x staged in LDS (padded), prefetch t+1 to regs.
// y[b,t,h*64+p] = sum_n h[p,n]*C[n] + D[h]*x[p]
// ---------------------------------------------------------------------------
__global__ __launch_bounds__(256) void scan_kernel(
    const float* __restrict__ xc,    // (NROWS, CONV_DIM)
    const float* __restrict__ dtw,   // (NROWS, NHEADS)
    const float* __restrict__ A_log,
    const float* __restrict__ Dp,
    float* __restrict__ y)           // (NROWS, D_SSM)
{
    const int b   = blockIdx.x / NHEADS;
    const int h   = blockIdx.x % NHEADS;
    const int tid = threadIdx.x;
    const int p   = tid >> 2;
    const int q   = tid & 3;

    __shared__ float dt_s[SEQLEN];
    __shared__ float Bs[4][36];   // padded: q-group base offset 36 words -> disjoint banks
    __shared__ float Cs[4][36];
    __shared__ float xs[64];

    for (int i = tid; i < SEQLEN; i += 256)
        dt_s[i] = dtw[((size_t)b * SEQLEN + i) * NHEADS + h];

    const float Aneg = -__expf(A_log[h]);
    const float Dh   = Dp[h];

    float hst[32];
#pragma unroll
    for (int i = 0; i < 32; ++i) hst[i] = 0.f;

    const float* row0 = xc + (size_t)b * SEQLEN * CONV_DIM;

    // prefetch t = 0
    float rBC = row0[D_SSM + tid];            // tid<128 -> B, tid>=128 -> C
    float rx  = (tid < 64) ? row0[h * HEADDIM + tid] : 0.f;

    for (int t = 0; t < SEQLEN; ++t) {
        __syncthreads();   // previous iteration done reading LDS (also fences dt_s at t=0)
        if (tid < 128) Bs[tid >> 5][tid & 31] = rBC;
        else           Cs[(tid >> 5) & 3][tid & 31] = rBC;
        if (tid < 64)  xs[tid] = rx;
        if (t + 1 < SEQLEN) {   // prefetch next step while computing this one
            const float* rp = row0 + (size_t)(t + 1) * CONV_DIM;
            rBC = rp[D_SSM + tid];
            if (tid < 64) rx = rp[h * HEADDIM + tid];
        }
        __syncthreads();

        const float dtv = dt_s[t];
        const float dA  = __expf(dtv * Aneg);
        const float dtx = dtv * xs[p];
        float ysum = 0.f;
#pragma unroll
        for (int j4 = 0; j4 < 8; ++j4) {
            const float4 Bv = *(const float4*)&Bs[q][j4 * 4];
            const float4 Cv = *(const float4*)&Cs[q][j4 * 4];
            float* hp = &hst[j4 * 4];
            hp[0] = fmaf(hp[0], dA, dtx * Bv.x); ysum = fmaf(hp[0], Cv.x, ysum);
            hp[1] = fmaf(hp[1], dA, dtx * Bv.y); ysum = fmaf(hp[1], Cv.y, ysum);
            hp[2] = fmaf(hp[2], dA, dtx * Bv.z); ysum = fmaf(hp[2], Cv.z, ysum);
            hp[3] = fmaf(hp[3], dA, dtx * Bv.w); ysum = fmaf(hp[3], Cv.w, ysum);
        }
        // reduce over the 4 n-groups (adjacent lanes)
        ysum += __shfl_xor(ysum, 1);
        ysum += __shfl_xor(ysum, 2);
        if (q == 0)
            y[((size_t)b * SEQLEN + t) * D_SSM + h * HEADDIM + p] = ysum + Dh * xs[p];
    }
}

// ---------------------------------------------------------------------------
// In-place: y <- (y * silu(z)) * rsqrt(mean(.^2) + eps) * norm_w. Block per row.
// ---------------------------------------------------------------------------
__global__ __launch_bounds__(256) void gatenorm_kernel(
    float* y, const float* __restrict__ zx, const float* __restrict__ norm_w)
{
    const int row = blockIdx.x;
    const int tid = threadIdx.x;
    float* yr = y + (size_t)row * D_SSM;
    const float* zr = zx + (size_t)row * D_IN_PROJ;   // z = first D_SSM cols

    float v[6];
    float ss = 0.f;
#pragma unroll
    for (int i = 0; i < 6; ++i) {
        const int e = tid + i * 256;
        const float yv = yr[e];
        const float zv = zr[e];
        const float g  = yv * (zv * sigmoidf_(zv));
        v[i] = g;
        ss = fmaf(g, g, ss);
    }
#pragma unroll
    for (int m = 1; m < 64; m <<= 1) ss += __shfl_xor(ss, m);
    __shared__ float ws[4];
    if ((tid & 63) == 0) ws[tid >> 6] = ss;
    __syncthreads();
    const float tot = ws[0] + ws[1] + ws[2] + ws[3];
    const float r = rsqrtf(tot * (1.0f / D_SSM) + EPS);
#pragma unroll
    for (int i = 0; i < 6; ++i) {
        const int e = tid + i * 256;
        yr[e] = v[i] * r * norm_w[e];
    }
}

// ---------------------------------------------------------------------------
extern "C" void kernel_launch(void* const* d_in, const int* in_sizes, int n_in,
                              void* d_out, int out_size, void* d_ws, size_t ws_size,
                              hipStream_t stream)
{
    const float* u       = (const float*)d_in[0];
    const float* W_in    = (const float*)d_in[1];
    const float* conv_w  = (const float*)d_in[2];
    const float* conv_b  = (const float*)d_in[3];
    const float* dt_bias = (const float*)d_in[4];
    const float* A_log   = (const float*)d_in[5];
    const float* Dp      = (const float*)d_in[6];
    const float* norm_w  = (const float*)d_in[7];
    const float* W_out   = (const float*)d_in[8];
    float* out = (float*)d_out;

    float* zxbcdt = (float*)d_ws;                            // NROWS * D_IN_PROJ
    float* xc     = zxbcdt + (size_t)NROWS * D_IN_PROJ;      // NROWS * CONV_DIM
    float* dtw    = xc     + (size_t)NROWS * CONV_DIM;       // NROWS * NHEADS
    float* yb     = dtw    + (size_t)NROWS * NHEADS;         // NROWS * D_SSM

    // 1. in-projection: zxbcdt = u @ W_in^T   (M=8192, N=3352, K=768)
    gemm_nt<64, 64, 16><<<dim3((D_IN_PROJ + 63) / 64, NROWS / 64), 256, 0, stream>>>(
        u, W_in, zxbcdt, NROWS, D_IN_PROJ, D_MODEL);

    // 2. depthwise conv + bias + SiLU on xBC slice
    conv_silu_kernel<<<(NROWS * (CONV_DIM / 4) + 255) / 256, 256, 0, stream>>>(
        zxbcdt, conv_w, conv_b, xc);

    // 3. dt = softplus(dt_raw + dt_bias)
    dt_kernel<<<NROWS, 64, 0, stream>>>(zxbcdt, dt_bias, dtw);

    // 4. selective scan
    scan_kernel<<<BATCH * NHEADS, 256, 0, stream>>>(xc, dtw, A_log, Dp, yb);

    // 5. gate + RMSNorm (in-place on yb)
    gatenorm_kernel<<<NROWS, 256, 0, stream>>>(yb, zxbcdt, norm_w);

    // 6. out-projection: out = yb @ W_out^T   (M=8192, N=768, K=1536)
    gemm_nt<64, 64, 16><<<dim3(D_MODEL / 64, NROWS / 64), 256, 0, stream>>>(
        yb, W_out, out, NROWS, D_MODEL, D_SSM);
}

// Round 3
// 2627.515 us; speedup vs baseline: 1.0071x; 1.0071x over previous
//
#include <hip/hip_runtime.h>
#include <hip/hip_bf16.h>
#include <math.h>

#define D_MODEL   768
#define D_SSM     1536
#define D_STATE   128
#define D_CONV    4
#define HEADDIM   64
#define NHEADS    24
#define CONV_DIM  1792          // D_SSM + 2*D_STATE
#define D_IN_PROJ 3352          // 2*D_SSM + 2*D_STATE + NHEADS
#define BATCH     4
#define SEQLEN    2048
#define NROWS     (BATCH * SEQLEN)   // 8192
#define EPS       1e-5f

#define CHUNK     64
#define NC        (SEQLEN / CHUNK)   // 32
#define NBH       (BATCH * NHEADS)   // 96
#define HSTATE    (HEADDIM * D_STATE) // 8192

__device__ __forceinline__ float sigmoidf_(float x) {
    return 1.0f / (1.0f + __expf(-x));
}

// ---------------------------------------------------------------------------
// GEMM (NT): C[M,N] = A[M,K] * B[N,K]^T, all row-major, K contiguous in both.
// ---------------------------------------------------------------------------
template<int BM, int BN, int BK>
__global__ __launch_bounds__(256) void gemm_nt(
    const float* __restrict__ A, const float* __restrict__ B,
    float* __restrict__ C, int M, int N, int K)
{
    __shared__ float As[BK][BM];
    __shared__ float Bs[BK][BN];
    const int tid = threadIdx.x;
    const int bm  = blockIdx.y * BM;
    const int bn  = blockIdx.x * BN;
    const int tm  = (tid & 15) << 2;
    const int tn  = (tid >> 4) << 2;
    const int am  = tid & 63;
    const int ak  = (tid >> 6) << 2;

    float acc[4][4] = {};

    for (int k0 = 0; k0 < K; k0 += BK) {
        const float4 av = *(const float4*)(A + (size_t)(bm + am) * K + (k0 + ak));
        float4 bv = make_float4(0.f, 0.f, 0.f, 0.f);
        if (bn + am < N)
            bv = *(const float4*)(B + (size_t)(bn + am) * K + (k0 + ak));
        __syncthreads();
        As[ak + 0][am] = av.x; As[ak + 1][am] = av.y;
        As[ak + 2][am] = av.z; As[ak + 3][am] = av.w;
        Bs[ak + 0][am] = bv.x; Bs[ak + 1][am] = bv.y;
        Bs[ak + 2][am] = bv.z; Bs[ak + 3][am] = bv.w;
        __syncthreads();
#pragma unroll
        for (int kk = 0; kk < BK; ++kk) {
            const float4 a4 = *(const float4*)&As[kk][tm];
            const float4 b4 = *(const float4*)&Bs[kk][tn];
            const float a[4]  = {a4.x, a4.y, a4.z, a4.w};
            const float bb[4] = {b4.x, b4.y, b4.z, b4.w};
#pragma unroll
            for (int i = 0; i < 4; ++i)
#pragma unroll
                for (int j = 0; j < 4; ++j)
                    acc[i][j] = fmaf(a[i], bb[j], acc[i][j]);
        }
    }
#pragma unroll
    for (int i = 0; i < 4; ++i)
#pragma unroll
        for (int j = 0; j < 4; ++j) {
            const int cn = bn + tn + j;
            if (cn < N)
                C[(size_t)(bm + tm + i) * N + cn] = acc[i][j];
        }
}

// ---------------------------------------------------------------------------
// Depthwise causal conv (width 4) + bias + SiLU.
// ---------------------------------------------------------------------------
__global__ __launch_bounds__(256) void conv_silu_kernel(
    const float* __restrict__ zx, const float* __restrict__ cw,
    const float* __restrict__ cb, float* __restrict__ xc)
{
    const int idx = blockIdx.x * 256 + threadIdx.x;
    if (idx >= NROWS * (CONV_DIM / 4)) return;
    const int row = idx / (CONV_DIM / 4);
    const int c   = (idx % (CONV_DIM / 4)) * 4;
    const int l   = row & (SEQLEN - 1);

    const float* base = zx + (size_t)row * D_IN_PROJ + D_SSM + c;
    const float4 cbv = *(const float4*)(cb + c);
    float acc[4] = {cbv.x, cbv.y, cbv.z, cbv.w};
    const float* w = cw + (size_t)c * D_CONV;
#pragma unroll
    for (int k = 0; k < D_CONV; ++k) {
        const int ls = l + k - 3;
        if (ls >= 0) {
            const float4 xv = *(const float4*)(base + (ptrdiff_t)(k - 3) * D_IN_PROJ);
            acc[0] = fmaf(w[0 * D_CONV + k], xv.x, acc[0]);
            acc[1] = fmaf(w[1 * D_CONV + k], xv.y, acc[1]);
            acc[2] = fmaf(w[2 * D_CONV + k], xv.z, acc[2]);
            acc[3] = fmaf(w[3 * D_CONV + k], xv.w, acc[3]);
        }
    }
    float4 o;
    o.x = acc[0] * sigmoidf_(acc[0]);
    o.y = acc[1] * sigmoidf_(acc[1]);
    o.z = acc[2] * sigmoidf_(acc[2]);
    o.w = acc[3] * sigmoidf_(acc[3]);
    *(float4*)(xc + (size_t)row * CONV_DIM + c) = o;
}

// ---------------------------------------------------------------------------
// dt = softplus(dt_raw + dt_bias)
// ---------------------------------------------------------------------------
__global__ __launch_bounds__(64) void dt_kernel(
    const float* __restrict__ zx, const float* __restrict__ dt_bias,
    float* __restrict__ dtw)
{
    const int row = blockIdx.x;
    const int tid = threadIdx.x;
    if (tid < NHEADS) {
        const float x = zx[(size_t)row * D_IN_PROJ + (D_SSM + CONV_DIM) + tid] + dt_bias[tid];
        const float sp = fmaxf(x, 0.f) + log1pf(__expf(-fabsf(x)));
        dtw[(size_t)row * NHEADS + tid] = sp;
    }
}

// ---------------------------------------------------------------------------
// Chunked scan, pass A: per (bh, c): chunk-local cumsum of a=A*dt (stored to
// cumws), and S_local[p][n] = sum_s exp(cum_last-cum_s)*dt_s*x_s[p]*B_s[n].
// ---------------------------------------------------------------------------
__global__ __launch_bounds__(256) void chunk_state_kernel(
    const float* __restrict__ xc, const float* __restrict__ dtw,
    const float* __restrict__ A_log,
    float* __restrict__ Sbuf, float* __restrict__ cumws)
{
    const int c  = blockIdx.x / NBH;     // consecutive blocks share chunk -> B/C L2 reuse
    const int bh = blockIdx.x % NBH;
    const int b  = bh / NHEADS, h = bh % NHEADS;
    const int tid = threadIdx.x;
    const int rowbase = b * SEQLEN + c * CHUNK;

    __shared__ float cums[CHUNK];
    __shared__ float wls[CHUNK];
    __shared__ float Xw[CHUNK][HEADDIM];    // [s][p], premultiplied by w_s
    __shared__ float Bsh[CHUNK][D_STATE];   // [s][n]

    const float Aneg = -__expf(A_log[h]);

    float dtv = 0.f, a = 0.f;
    if (tid < CHUNK) {
        dtv = dtw[(size_t)(rowbase + tid) * NHEADS + h];
        a = Aneg * dtv;
    }
    // wave-0 inclusive scan over 64 lanes
    float v = a;
#pragma unroll
    for (int d = 1; d < 64; d <<= 1) {
        const float o = __shfl_up(v, d);
        if ((tid & 63) >= d) v += o;
    }
    if (tid < CHUNK) {
        cums[tid] = v;
        cumws[(size_t)bh * SEQLEN + c * CHUNK + tid] = v;
    }
    __syncthreads();
    const float clast = cums[CHUNK - 1];
    if (tid < CHUNK) wls[tid] = __expf(clast - v) * dtv;
    __syncthreads();

    // stage Xw (x * w) and B
    {
        const int p0 = (tid & 15) * 4, s0 = tid >> 4;
        for (int s = s0; s < CHUNK; s += 16) {
            const float4 xv = *(const float4*)(xc + (size_t)(rowbase + s) * CONV_DIM + h * HEADDIM + p0);
            const float w = wls[s];
            *(float4*)&Xw[s][p0] = make_float4(xv.x * w, xv.y * w, xv.z * w, xv.w * w);
        }
        const int n0 = (tid & 31) * 4, s1 = tid >> 5;
        for (int s = s1; s < CHUNK; s += 8) {
            *(float4*)&Bsh[s][n0] = *(const float4*)(xc + (size_t)(rowbase + s) * CONV_DIM + D_SSM + n0);
        }
    }
    __syncthreads();

    // S[p][n] = sum_s Xw[s][p] * B[s][n]  (64x128, K=64)
    const int tp = (tid & 15) * 4;
    const int tn = (tid >> 4) * 8;
    float acc[4][8] = {};
    for (int s = 0; s < CHUNK; ++s) {
        const float4 xa = *(const float4*)&Xw[s][tp];
        const float4 b0 = *(const float4*)&Bsh[s][tn];
        const float4 b1 = *(const float4*)&Bsh[s][tn + 4];
        const float xr[4] = {xa.x, xa.y, xa.z, xa.w};
        const float br[8] = {b0.x, b0.y, b0.z, b0.w, b1.x, b1.y, b1.z, b1.w};
#pragma unroll
        for (int i = 0; i < 4; ++i)
#pragma unroll
            for (int j = 0; j < 8; ++j)
                acc[i][j] = fmaf(xr[i], br[j], acc[i][j]);
    }
    float* Sp = Sbuf + (size_t)(bh * NC + c) * HSTATE;
#pragma unroll
    for (int i = 0; i < 4; ++i) {
        *(float4*)(Sp + (size_t)(tp + i) * D_STATE + tn)     = make_float4(acc[i][0], acc[i][1], acc[i][2], acc[i][3]);
        *(float4*)(Sp + (size_t)(tp + i) * D_STATE + tn + 4) = make_float4(acc[i][4], acc[i][5], acc[i][6], acc[i][7]);
    }
}

// ---------------------------------------------------------------------------
// Chunked scan, pass B: per-element scan over chunks; in-place S -> H_in.
// H_in[0]=0; H_in[c] = P_{c-1}*H_in[c-1] + S[c-1].
// ---------------------------------------------------------------------------
__global__ __launch_bounds__(256) void state_scan_kernel(
    const float* __restrict__ cumws, float* __restrict__ Sbuf)
{
    const int bh = blockIdx.x;
    const int e  = blockIdx.y * 256 + threadIdx.x;
    float* base = Sbuf + (size_t)bh * NC * HSTATE + e;
    const float* cw = cumws + (size_t)bh * SEQLEN;
    float H = 0.f;
    for (int c = 0; c < NC; ++c) {
        const float P = __expf(cw[c * CHUNK + CHUNK - 1]);
        const float s = base[(size_t)c * HSTATE];
        base[(size_t)c * HSTATE] = H;       // slot becomes H_in for chunk c
        H = fmaf(P, H, s);
    }
}

// ---------------------------------------------------------------------------
// Chunked scan, pass C: per (bh, c):
//   G = C @ B^T (64x64, K=128); M = G * exp(cum_t - cum_s) * dt_s, s<=t
//   y = M @ X + exp(cum_t) * (C @ H_in^T) + D*x
// ---------------------------------------------------------------------------
__global__ __launch_bounds__(256) void chunk_output_kernel(
    const float* __restrict__ xc, const float* __restrict__ dtw,
    const float* __restrict__ Dp,
    const float* __restrict__ Hbuf,      // = Sbuf after pass B
    const float* __restrict__ cumws, float* __restrict__ y)
{
    const int c  = blockIdx.x / NBH;
    const int bh = blockIdx.x % NBH;
    const int b  = bh / NHEADS, h = bh % NHEADS;
    const int tid = threadIdx.x;
    const int rowbase = b * SEQLEN + c * CHUNK;

    __shared__ float cums[CHUNK], dts[CHUNK], Es[CHUNK];
    __shared__ float CsT[D_STATE][CHUNK];   // [n][t]
    __shared__ float BsT[D_STATE][CHUNK];   // [n][s]
    __shared__ float HsT[D_STATE][HEADDIM]; // [n][p]
    __shared__ float Xs[CHUNK][HEADDIM];    // [s][p]
    __shared__ float Ms[CHUNK][CHUNK + 1];  // [t][s], padded

    if (tid < CHUNK) {
        const float cv = cumws[(size_t)bh * SEQLEN + c * CHUNK + tid];
        cums[tid] = cv;
        Es[tid] = __expf(cv);
        dts[tid] = dtw[(size_t)(rowbase + tid) * NHEADS + h];
    }

    // stage C^T, B^T (k-major [n][t]); conflict-free LDS writes
    {
        const int t = tid & 63;
        const int nq = (tid >> 6) * 4;
        const float* rowp = xc + (size_t)(rowbase + t) * CONV_DIM;
        for (int n = nq; n < D_STATE; n += 16) {
            const float4 cv = *(const float4*)(rowp + D_SSM + D_STATE + n);
            CsT[n + 0][t] = cv.x; CsT[n + 1][t] = cv.y;
            CsT[n + 2][t] = cv.z; CsT[n + 3][t] = cv.w;
            const float4 bv = *(const float4*)(rowp + D_SSM + n);
            BsT[n + 0][t] = bv.x; BsT[n + 1][t] = bv.y;
            BsT[n + 2][t] = bv.z; BsT[n + 3][t] = bv.w;
        }
        // H_in^T
        const float* Hp = Hbuf + (size_t)(bh * NC + c) * HSTATE;
        for (int n = nq; n < D_STATE; n += 16) {
            const float4 hv = *(const float4*)(Hp + (size_t)t * D_STATE + n);
            HsT[n + 0][t] = hv.x; HsT[n + 1][t] = hv.y;
            HsT[n + 2][t] = hv.z; HsT[n + 3][t] = hv.w;
        }
        // X [s][p]
        const int p0 = (tid & 15) * 4, s0 = tid >> 4;
        for (int s = s0; s < CHUNK; s += 16) {
            *(float4*)&Xs[s][p0] =
                *(const float4*)(xc + (size_t)(rowbase + s) * CONV_DIM + h * HEADDIM + p0);
        }
    }
    __syncthreads();

    const int tm = (tid & 15) * 4;   // t rows
    const int tn = (tid >> 4) * 4;   // s cols (G) / p cols (Y)

    // G = C @ B^T
    float g[4][4] = {};
    for (int n = 0; n < D_STATE; ++n) {
        const float4 ca = *(const float4*)&CsT[n][tm];
        const float4 bb = *(const float4*)&BsT[n][tn];
        const float ar[4] = {ca.x, ca.y, ca.z, ca.w};
        const float br[4] = {bb.x, bb.y, bb.z, bb.w};
#pragma unroll
        for (int i = 0; i < 4; ++i)
#pragma unroll
            for (int j = 0; j < 4; ++j)
                g[i][j] = fmaf(ar[i], br[j], g[i][j]);
    }
    __syncthreads();   // all G reads done before CsT rescale

    // write masked/decayed M; rescale CsT by exp(cum_t)
#pragma unroll
    for (int i = 0; i < 4; ++i) {
        const int t = tm + i;
        float4 mv;
        float* mp = (float*)&mv;
#pragma unroll
        for (int j = 0; j < 4; ++j) {
            const int s = tn + j;
            mp[j] = (s <= t) ? g[i][j] * __expf(cums[t] - cums[s]) * dts[s] : 0.f;
        }
        *(float4*)&Ms[t][tn] = mv;
    }
    for (int e = tid; e < D_STATE * CHUNK; e += 256) {
        const int n = e >> 6, t = e & 63;
        CsT[n][t] *= Es[t];
    }
    __syncthreads();

    // y = M @ X + Cresc @ H^T
    float acc[4][4] = {};
    for (int s = 0; s < CHUNK; ++s) {
        const float m0 = Ms[tm + 0][s], m1 = Ms[tm + 1][s];
        const float m2 = Ms[tm + 2][s], m3 = Ms[tm + 3][s];
        const float4 xv = *(const float4*)&Xs[s][tn];
        const float xr[4] = {xv.x, xv.y, xv.z, xv.w};
        const float mr[4] = {m0, m1, m2, m3};
#pragma unroll
        for (int i = 0; i < 4; ++i)
#pragma unroll
            for (int j = 0; j < 4; ++j)
                acc[i][j] = fmaf(mr[i], xr[j], acc[i][j]);
    }
    for (int n = 0; n < D_STATE; ++n) {
        const float4 ca = *(const float4*)&CsT[n][tm];
        const float4 hv = *(const float4*)&HsT[n][tn];
        const float ar[4] = {ca.x, ca.y, ca.z, ca.w};
        const float hr[4] = {hv.x, hv.y, hv.z, hv.w};
#pragma unroll
        for (int i = 0; i < 4; ++i)
#pragma unroll
            for (int j = 0; j < 4; ++j)
                acc[i][j] = fmaf(ar[i], hr[j], acc[i][j]);
    }

    const float Dh = Dp[h];
#pragma unroll
    for (int i = 0; i < 4; ++i) {
        float4 ov;
        ov.x = acc[i][0] + Dh * Xs[tm + i][tn + 0];
        ov.y = acc[i][1] + Dh * Xs[tm + i][tn + 1];
        ov.z = acc[i][2] + Dh * Xs[tm + i][tn + 2];
        ov.w = acc[i][3] + Dh * Xs[tm + i][tn + 3];
        *(float4*)(y + (size_t)(rowbase + tm + i) * D_SSM + h * HEADDIM + tn) = ov;
    }
}

// ---------------------------------------------------------------------------
// Fallback sequential scan (used only if ws_size too small for chunked path).
// ---------------------------------------------------------------------------
__global__ __launch_bounds__(256) void scan_kernel(
    const float* __restrict__ xc, const float* __restrict__ dtw,
    const float* __restrict__ A_log, const float* __restrict__ Dp,
    float* __restrict__ y)
{
    const int b   = blockIdx.x / NHEADS;
    const int h   = blockIdx.x % NHEADS;
    const int tid = threadIdx.x;
    const int p   = tid >> 2;
    const int q   = tid & 3;

    __shared__ float dt_s[SEQLEN];
    __shared__ float Bs[4][36];
    __shared__ float Cs[4][36];
    __shared__ float xs[64];

    for (int i = tid; i < SEQLEN; i += 256)
        dt_s[i] = dtw[((size_t)b * SEQLEN + i) * NHEADS + h];

    const float Aneg = -__expf(A_log[h]);
    const float Dh   = Dp[h];

    float hst[32];
#pragma unroll
    for (int i = 0; i < 32; ++i) hst[i] = 0.f;

    const float* row0 = xc + (size_t)b * SEQLEN * CONV_DIM;
    float rBC = row0[D_SSM + tid];
    float rx  = (tid < 64) ? row0[h * HEADDIM + tid] : 0.f;

    for (int t = 0; t < SEQLEN; ++t) {
        __syncthreads();
        if (tid < 128) Bs[tid >> 5][tid & 31] = rBC;
        else           Cs[(tid >> 5) & 3][tid & 31] = rBC;
        if (tid < 64)  xs[tid] = rx;
        if (t + 1 < SEQLEN) {
            const float* rp = row0 + (size_t)(t + 1) * CONV_DIM;
            rBC = rp[D_SSM + tid];
            if (tid < 64) rx = rp[h * HEADDIM + tid];
        }
        __syncthreads();

        const float dtv = dt_s[t];
        const float dA  = __expf(dtv * Aneg);
        const float dtx = dtv * xs[p];
        float ysum = 0.f;
#pragma unroll
        for (int j4 = 0; j4 < 8; ++j4) {
            const float4 Bv = *(const float4*)&Bs[q][j4 * 4];
            const float4 Cv = *(const float4*)&Cs[q][j4 * 4];
            float* hp = &hst[j4 * 4];
            hp[0] = fmaf(hp[0], dA, dtx * Bv.x); ysum = fmaf(hp[0], Cv.x, ysum);
            hp[1] = fmaf(hp[1], dA, dtx * Bv.y); ysum = fmaf(hp[1], Cv.y, ysum);
            hp[2] = fmaf(hp[2], dA, dtx * Bv.z); ysum = fmaf(hp[2], Cv.z, ysum);
            hp[3] = fmaf(hp[3], dA, dtx * Bv.w); ysum = fmaf(hp[3], Cv.w, ysum);
        }
        ysum += __shfl_xor(ysum, 1);
        ysum += __shfl_xor(ysum, 2);
        if (q == 0)
            y[((size_t)b * SEQLEN + t) * D_SSM + h * HEADDIM + p] = ysum + Dh * xs[p];
    }
}

// ---------------------------------------------------------------------------
// In-place gate + RMSNorm.
// ---------------------------------------------------------------------------
__global__ __launch_bounds__(256) void gatenorm_kernel(
    float* y, const float* __restrict__ zx, const float* __restrict__ norm_w)
{
    const int row = blockIdx.x;
    const int tid = threadIdx.x;
    float* yr = y + (size_t)row * D_SSM;
    const float* zr = zx + (size_t)row * D_IN_PROJ;

    float v[6];
    float ss = 0.f;
#pragma unroll
    for (int i = 0; i < 6; ++i) {
        const int e = tid + i * 256;
        const float yv = yr[e];
        const float zv = zr[e];
        const float g  = yv * (zv * sigmoidf_(zv));
        v[i] = g;
        ss = fmaf(g, g, ss);
    }
#pragma unroll
    for (int m = 1; m < 64; m <<= 1) ss += __shfl_xor(ss, m);
    __shared__ float ws[4];
    if ((tid & 63) == 0) ws[tid >> 6] = ss;
    __syncthreads();
    const float tot = ws[0] + ws[1] + ws[2] + ws[3];
    const float r = rsqrtf(tot * (1.0f / D_SSM) + EPS);
#pragma unroll
    for (int i = 0; i < 6; ++i) {
        const int e = tid + i * 256;
        yr[e] = v[i] * r * norm_w[e];
    }
}

// ---------------------------------------------------------------------------
extern "C" void kernel_launch(void* const* d_in, const int* in_sizes, int n_in,
                              void* d_out, int out_size, void* d_ws, size_t ws_size,
                              hipStream_t stream)
{
    const float* u       = (const float*)d_in[0];
    const float* W_in    = (const float*)d_in[1];
    const float* conv_w  = (const float*)d_in[2];
    const float* conv_b  = (const float*)d_in[3];
    const float* dt_bias = (const float*)d_in[4];
    const float* A_log   = (const float*)d_in[5];
    const float* Dp      = (const float*)d_in[6];
    const float* norm_w  = (const float*)d_in[7];
    const float* W_out   = (const float*)d_in[8];
    float* out = (float*)d_out;

    float* zxbcdt = (float*)d_ws;                            // NROWS * D_IN_PROJ
    float* xc     = zxbcdt + (size_t)NROWS * D_IN_PROJ;      // NROWS * CONV_DIM
    float* dtw    = xc     + (size_t)NROWS * CONV_DIM;       // NROWS * NHEADS
    float* yb     = dtw    + (size_t)NROWS * NHEADS;         // NROWS * D_SSM
    float* cumws  = yb     + (size_t)NROWS * D_SSM;          // NBH * SEQLEN
    float* Sbuf   = cumws  + (size_t)NBH * SEQLEN;           // NBH * NC * HSTATE

    const size_t need_floats = (size_t)NROWS * D_IN_PROJ + (size_t)NROWS * CONV_DIM
                             + (size_t)NROWS * NHEADS + (size_t)NROWS * D_SSM
                             + (size_t)NBH * SEQLEN + (size_t)NBH * NC * HSTATE;
    const bool use_chunked = ws_size >= need_floats * sizeof(float);

    // 1. in-projection
    gemm_nt<64, 64, 16><<<dim3((D_IN_PROJ + 63) / 64, NROWS / 64), 256, 0, stream>>>(
        u, W_in, zxbcdt, NROWS, D_IN_PROJ, D_MODEL);

    // 2. conv + SiLU
    conv_silu_kernel<<<(NROWS * (CONV_DIM / 4) + 255) / 256, 256, 0, stream>>>(
        zxbcdt, conv_w, conv_b, xc);

    // 3. dt
    dt_kernel<<<NROWS, 64, 0, stream>>>(zxbcdt, dt_bias, dtw);

    // 4. scan
    if (use_chunked) {
        chunk_state_kernel<<<NBH * NC, 256, 0, stream>>>(xc, dtw, A_log, Sbuf, cumws);
        state_scan_kernel<<<dim3(NBH, HSTATE / 256), 256, 0, stream>>>(cumws, Sbuf);
        chunk_output_kernel<<<NBH * NC, 256, 0, stream>>>(xc, dtw, Dp, Sbuf, cumws, yb);
    } else {
        scan_kernel<<<NBH, 256, 0, stream>>>(xc, dtw, A_log, Dp, yb);
    }

    // 5. gate + RMSNorm (in-place)
    gatenorm_kernel<<<NROWS, 256, 0, stream>>>(yb, zxbcdt, norm_w);

    // 6. out-projection
    gemm_nt<64, 64, 16><<<dim3(D_MODEL / 64, NROWS / 64), 256, 0, stream>>>(
        yb, W_out, out, NROWS, D_MODEL, D_SSM);
}

// Round 4
// 1427.379 us; speedup vs baseline: 1.8538x; 1.8408x over previous
//
#include <hip/hip_runtime.h>
#include <hip/hip_bf16.h>
#include <math.h>

#define D_MODEL   768
#define D_SSM     1536
#define D_STATE   128
#define D_CONV    4
#define HEADDIM   64
#define NHEADS    24
#define CONV_DIM  1792          // D_SSM + 2*D_STATE
#define D_IN_PROJ 3352          // 2*D_SSM + 2*D_STATE + NHEADS
#define BATCH     4
#define SEQLEN    2048
#define NROWS     (BATCH * SEQLEN)   // 8192
#define EPS       1e-5f

#define CHUNK     64
#define NC        (SEQLEN / CHUNK)    // 32
#define NBH       (BATCH * NHEADS)    // 96
#define HSTATE    (HEADDIM * D_STATE) // 8192

__device__ __forceinline__ float sigmoidf_(float x) {
    return 1.0f / (1.0f + __expf(-x));
}

// ---------------------------------------------------------------------------
// Generic GEMM (NT): C[M,N] = A[M,K] * B[N,K]^T.
// ---------------------------------------------------------------------------
template<int BM, int BN, int BK>
__global__ __launch_bounds__(256) void gemm_nt(
    const float* __restrict__ A, const float* __restrict__ B,
    float* __restrict__ C, int M, int N, int K)
{
    __shared__ float As[BK][BM];
    __shared__ float Bs[BK][BN];
    const int tid = threadIdx.x;
    const int bm  = blockIdx.y * BM;
    const int bn  = blockIdx.x * BN;
    const int tm  = (tid & 15) << 2;
    const int tn  = (tid >> 4) << 2;
    const int am  = tid & 63;
    const int ak  = (tid >> 6) << 2;

    float acc[4][4] = {};

    for (int k0 = 0; k0 < K; k0 += BK) {
        const float4 av = *(const float4*)(A + (size_t)(bm + am) * K + (k0 + ak));
        float4 bv = make_float4(0.f, 0.f, 0.f, 0.f);
        if (bn + am < N)
            bv = *(const float4*)(B + (size_t)(bn + am) * K + (k0 + ak));
        __syncthreads();
        As[ak + 0][am] = av.x; As[ak + 1][am] = av.y;
        As[ak + 2][am] = av.z; As[ak + 3][am] = av.w;
        Bs[ak + 0][am] = bv.x; Bs[ak + 1][am] = bv.y;
        Bs[ak + 2][am] = bv.z; Bs[ak + 3][am] = bv.w;
        __syncthreads();
#pragma unroll
        for (int kk = 0; kk < BK; ++kk) {
            const float4 a4 = *(const float4*)&As[kk][tm];
            const float4 b4 = *(const float4*)&Bs[kk][tn];
            const float a[4]  = {a4.x, a4.y, a4.z, a4.w};
            const float bb[4] = {b4.x, b4.y, b4.z, b4.w};
#pragma unroll
            for (int i = 0; i < 4; ++i)
#pragma unroll
                for (int j = 0; j < 4; ++j)
                    acc[i][j] = fmaf(a[i], bb[j], acc[i][j]);
        }
    }
#pragma unroll
    for (int i = 0; i < 4; ++i)
#pragma unroll
        for (int j = 0; j < 4; ++j) {
            const int cn = bn + tn + j;
            if (cn < N)
                C[(size_t)(bm + tm + i) * N + cn] = acc[i][j];
        }
}

// ---------------------------------------------------------------------------
// In-proj GEMM with split outputs: cols [0,1536)->zbuf, [1536,3328)->xbc,
// [3328,3352)->dtraw. Tile boundaries are multiples of BN=64.
// ---------------------------------------------------------------------------
__global__ __launch_bounds__(256) void gemm_inproj(
    const float* __restrict__ A, const float* __restrict__ B,
    float* __restrict__ zbuf, float* __restrict__ xbc, float* __restrict__ dtraw)
{
    constexpr int BM = 64, BN = 64, BK = 16;
    __shared__ float As[BK][BM];
    __shared__ float Bs[BK][BN];
    const int tid = threadIdx.x;
    const int bm  = blockIdx.y * BM;
    const int bn  = blockIdx.x * BN;
    const int tm  = (tid & 15) << 2;
    const int tn  = (tid >> 4) << 2;
    const int am  = tid & 63;
    const int ak  = (tid >> 6) << 2;

    float acc[4][4] = {};

    for (int k0 = 0; k0 < D_MODEL; k0 += BK) {
        const float4 av = *(const float4*)(A + (size_t)(bm + am) * D_MODEL + (k0 + ak));
        float4 bv = make_float4(0.f, 0.f, 0.f, 0.f);
        if (bn + am < D_IN_PROJ)
            bv = *(const float4*)(B + (size_t)(bn + am) * D_MODEL + (k0 + ak));
        __syncthreads();
        As[ak + 0][am] = av.x; As[ak + 1][am] = av.y;
        As[ak + 2][am] = av.z; As[ak + 3][am] = av.w;
        Bs[ak + 0][am] = bv.x; Bs[ak + 1][am] = bv.y;
        Bs[ak + 2][am] = bv.z; Bs[ak + 3][am] = bv.w;
        __syncthreads();
#pragma unroll
        for (int kk = 0; kk < BK; ++kk) {
            const float4 a4 = *(const float4*)&As[kk][tm];
            const float4 b4 = *(const float4*)&Bs[kk][tn];
            const float a[4]  = {a4.x, a4.y, a4.z, a4.w};
            const float bb[4] = {b4.x, b4.y, b4.z, b4.w};
#pragma unroll
            for (int i = 0; i < 4; ++i)
#pragma unroll
                for (int j = 0; j < 4; ++j)
                    acc[i][j] = fmaf(a[i], bb[j], acc[i][j]);
        }
    }

    float* Cp; int ldc, cb, nlim = BN;
    if (bn < D_SSM)                  { Cp = zbuf;  ldc = D_SSM;    cb = bn; }
    else if (bn < D_SSM + CONV_DIM)  { Cp = xbc;   ldc = CONV_DIM; cb = bn - D_SSM; }
    else { Cp = dtraw; ldc = NHEADS; cb = bn - (D_SSM + CONV_DIM); nlim = NHEADS; }
#pragma unroll
    for (int i = 0; i < 4; ++i)
#pragma unroll
        for (int j = 0; j < 4; ++j)
            if (tn + j < nlim)
                Cp[(size_t)(bm + tm + i) * ldc + cb + tn + j] = acc[i][j];
}

// ---------------------------------------------------------------------------
// Depthwise causal conv (width 4) + bias + SiLU; xbc stride CONV_DIM.
// ---------------------------------------------------------------------------
__global__ __launch_bounds__(256) void conv_silu_kernel(
    const float* __restrict__ xbc, const float* __restrict__ cw,
    const float* __restrict__ cb, float* __restrict__ xc)
{
    const int idx = blockIdx.x * 256 + threadIdx.x;
    if (idx >= NROWS * (CONV_DIM / 4)) return;
    const int row = idx / (CONV_DIM / 4);
    const int c   = (idx % (CONV_DIM / 4)) * 4;
    const int l   = row & (SEQLEN - 1);

    const float* base = xbc + (size_t)row * CONV_DIM + c;
    const float4 cbv = *(const float4*)(cb + c);
    float acc[4] = {cbv.x, cbv.y, cbv.z, cbv.w};
    const float* w = cw + (size_t)c * D_CONV;
#pragma unroll
    for (int k = 0; k < D_CONV; ++k) {
        const int ls = l + k - 3;
        if (ls >= 0) {
            const float4 xv = *(const float4*)(base + (ptrdiff_t)(k - 3) * CONV_DIM);
            acc[0] = fmaf(w[0 * D_CONV + k], xv.x, acc[0]);
            acc[1] = fmaf(w[1 * D_CONV + k], xv.y, acc[1]);
            acc[2] = fmaf(w[2 * D_CONV + k], xv.z, acc[2]);
            acc[3] = fmaf(w[3 * D_CONV + k], xv.w, acc[3]);
        }
    }
    float4 o;
    o.x = acc[0] * sigmoidf_(acc[0]);
    o.y = acc[1] * sigmoidf_(acc[1]);
    o.z = acc[2] * sigmoidf_(acc[2]);
    o.w = acc[3] * sigmoidf_(acc[3]);
    *(float4*)(xc + (size_t)row * CONV_DIM + c) = o;
}

// ---------------------------------------------------------------------------
// dt = softplus(dt_raw + dt_bias); dtraw stride NHEADS.
// ---------------------------------------------------------------------------
__global__ __launch_bounds__(64) void dt_kernel(
    const float* __restrict__ dtraw, const float* __restrict__ dt_bias,
    float* __restrict__ dtw)
{
    const int row = blockIdx.x;
    const int tid = threadIdx.x;
    if (tid < NHEADS) {
        const float x = dtraw[(size_t)row * NHEADS + tid] + dt_bias[tid];
        const float sp = fmaxf(x, 0.f) + log1pf(__expf(-fabsf(x)));
        dtw[(size_t)row * NHEADS + tid] = sp;
    }
}

// ---------------------------------------------------------------------------
// Pass A: chunk-local cumsum of a=A*dt (-> cumws) and local end-state
// S[p][n] = sum_s exp(cum_last - cum_s)*dt_s*x_s[p]*B_s[n].
// ---------------------------------------------------------------------------
__global__ __launch_bounds__(256) void chunk_state_kernel(
    const float* __restrict__ xc, const float* __restrict__ dtw,
    const float* __restrict__ A_log,
    float* __restrict__ Sbuf, float* __restrict__ cumws)
{
    const int c  = blockIdx.x / NBH;
    const int bh = blockIdx.x % NBH;
    const int b  = bh / NHEADS, h = bh % NHEADS;
    const int tid = threadIdx.x;
    const int rowbase = b * SEQLEN + c * CHUNK;

    __shared__ float cums[CHUNK];
    __shared__ float wls[CHUNK];
    __shared__ float Xw[CHUNK][HEADDIM];
    __shared__ float Bsh[CHUNK][D_STATE];

    const float Aneg = -__expf(A_log[h]);

    float dtv = 0.f;
    if (tid < CHUNK) dtv = dtw[(size_t)(rowbase + tid) * NHEADS + h];
    float v = Aneg * dtv;
#pragma unroll
    for (int d = 1; d < 64; d <<= 1) {
        const float o = __shfl_up(v, d);
        if ((tid & 63) >= d) v += o;
    }
    if (tid < CHUNK) {
        cums[tid] = v;
        cumws[(size_t)bh * SEQLEN + c * CHUNK + tid] = v;
    }
    __syncthreads();
    const float clast = cums[CHUNK - 1];
    if (tid < CHUNK) wls[tid] = __expf(clast - v) * dtv;
    __syncthreads();

    {
        const int p0 = (tid & 15) * 4, s0 = tid >> 4;
        for (int s = s0; s < CHUNK; s += 16) {
            const float4 xv = *(const float4*)(xc + (size_t)(rowbase + s) * CONV_DIM + h * HEADDIM + p0);
            const float w = wls[s];
            *(float4*)&Xw[s][p0] = make_float4(xv.x * w, xv.y * w, xv.z * w, xv.w * w);
        }
        const int n0 = (tid & 31) * 4, s1 = tid >> 5;
        for (int s = s1; s < CHUNK; s += 8)
            *(float4*)&Bsh[s][n0] = *(const float4*)(xc + (size_t)(rowbase + s) * CONV_DIM + D_SSM + n0);
    }
    __syncthreads();

    const int tp = (tid & 15) * 4;
    const int tn = (tid >> 4) * 8;
    float acc[4][8] = {};
    for (int s = 0; s < CHUNK; ++s) {
        const float4 xa = *(const float4*)&Xw[s][tp];
        const float4 b0 = *(const float4*)&Bsh[s][tn];
        const float4 b1 = *(const float4*)&Bsh[s][tn + 4];
        const float xr[4] = {xa.x, xa.y, xa.z, xa.w};
        const float br[8] = {b0.x, b0.y, b0.z, b0.w, b1.x, b1.y, b1.z, b1.w};
#pragma unroll
        for (int i = 0; i < 4; ++i)
#pragma unroll
            for (int j = 0; j < 8; ++j)
                acc[i][j] = fmaf(xr[i], br[j], acc[i][j]);
    }
    float* Sp = Sbuf + (size_t)(bh * NC + c) * HSTATE;
#pragma unroll
    for (int i = 0; i < 4; ++i) {
        *(float4*)(Sp + (size_t)(tp + i) * D_STATE + tn)     = make_float4(acc[i][0], acc[i][1], acc[i][2], acc[i][3]);
        *(float4*)(Sp + (size_t)(tp + i) * D_STATE + tn + 4) = make_float4(acc[i][4], acc[i][5], acc[i][6], acc[i][7]);
    }
}

// ---------------------------------------------------------------------------
// Pass B: per-element scan over chunks, in-place S -> H_in.
// ---------------------------------------------------------------------------
__global__ __launch_bounds__(256) void state_scan_kernel(
    const float* __restrict__ cumws, float* __restrict__ Sbuf)
{
    const int bh = blockIdx.x;
    const int e  = blockIdx.y * 256 + threadIdx.x;
    float* base = Sbuf + (size_t)bh * NC * HSTATE + e;
    const float* cw = cumws + (size_t)bh * SEQLEN;
    float H = 0.f;
    for (int c = 0; c < NC; ++c) {
        const float P = __expf(cw[c * CHUNK + CHUNK - 1]);
        const float s = base[(size_t)c * HSTATE];
        base[(size_t)c * HSTATE] = H;
        H = fmaf(P, H, s);
    }
}

// ---------------------------------------------------------------------------
// Pass C: G = C@B^T; M = G*exp(cum_t-cum_s)*dt_s (s<=t);
// y = M@X + exp(cum_t)*(C@H_in^T) + D*x.
// ---------------------------------------------------------------------------
__global__ __launch_bounds__(256) void chunk_output_kernel(
    const float* __restrict__ xc, const float* __restrict__ dtw,
    const float* __restrict__ Dp,
    const float* __restrict__ Hbuf, const float* __restrict__ cumws,
    float* __restrict__ y)
{
    const int c  = blockIdx.x / NBH;
    const int bh = blockIdx.x % NBH;
    const int b  = bh / NHEADS, h = bh % NHEADS;
    const int tid = threadIdx.x;
    const int rowbase = b * SEQLEN + c * CHUNK;

    __shared__ float cums[CHUNK], dts[CHUNK], Es[CHUNK];
    __shared__ float CsT[D_STATE][CHUNK];
    __shared__ float BsT[D_STATE][CHUNK];
    __shared__ float HsT[D_STATE][HEADDIM];
    __shared__ float Xs[CHUNK][HEADDIM];
    __shared__ float Ms[CHUNK][CHUNK + 1];

    if (tid < CHUNK) {
        const float cv = cumws[(size_t)bh * SEQLEN + c * CHUNK + tid];
        cums[tid] = cv;
        Es[tid] = __expf(cv);
        dts[tid] = dtw[(size_t)(rowbase + tid) * NHEADS + h];
    }

    {
        const int t = tid & 63;
        const int nq = (tid >> 6) * 4;
        const float* rowp = xc + (size_t)(rowbase + t) * CONV_DIM;
        for (int n = nq; n < D_STATE; n += 16) {
            const float4 cv = *(const float4*)(rowp + D_SSM + D_STATE + n);
            CsT[n + 0][t] = cv.x; CsT[n + 1][t] = cv.y;
            CsT[n + 2][t] = cv.z; CsT[n + 3][t] = cv.w;
            const float4 bv = *(const float4*)(rowp + D_SSM + n);
            BsT[n + 0][t] = bv.x; BsT[n + 1][t] = bv.y;
            BsT[n + 2][t] = bv.z; BsT[n + 3][t] = bv.w;
        }
        const float* Hp = Hbuf + (size_t)(bh * NC + c) * HSTATE;
        for (int n = nq; n < D_STATE; n += 16) {
            const float4 hv = *(const float4*)(Hp + (size_t)t * D_STATE + n);
            HsT[n + 0][t] = hv.x; HsT[n + 1][t] = hv.y;
            HsT[n + 2][t] = hv.z; HsT[n + 3][t] = hv.w;
        }
        const int p0 = (tid & 15) * 4, s0 = tid >> 4;
        for (int s = s0; s < CHUNK; s += 16)
            *(float4*)&Xs[s][p0] =
                *(const float4*)(xc + (size_t)(rowbase + s) * CONV_DIM + h * HEADDIM + p0);
    }
    __syncthreads();

    const int tm = (tid & 15) * 4;
    const int tn = (tid >> 4) * 4;

    float g[4][4] = {};
    for (int n = 0; n < D_STATE; ++n) {
        const float4 ca = *(const float4*)&CsT[n][tm];
        const float4 bb = *(const float4*)&BsT[n][tn];
        const float ar[4] = {ca.x, ca.y, ca.z, ca.w};
        const float br[4] = {bb.x, bb.y, bb.z, bb.w};
#pragma unroll
        for (int i = 0; i < 4; ++i)
#pragma unroll
            for (int j = 0; j < 4; ++j)
                g[i][j] = fmaf(ar[i], br[j], g[i][j]);
    }
    __syncthreads();

#pragma unroll
    for (int i = 0; i < 4; ++i) {
        const int t = tm + i;
        float4 mv;
        float* mp = (float*)&mv;
#pragma unroll
        for (int j = 0; j < 4; ++j) {
            const int s = tn + j;
            mp[j] = (s <= t) ? g[i][j] * __expf(cums[t] - cums[s]) * dts[s] : 0.f;
        }
        *(float4*)&Ms[t][tn] = mv;
    }
    for (int e = tid; e < D_STATE * CHUNK; e += 256) {
        const int n = e >> 6, t = e & 63;
        CsT[n][t] *= Es[t];
    }
    __syncthreads();

    float acc[4][4] = {};
    for (int s = 0; s < CHUNK; ++s) {
        const float mr[4] = {Ms[tm + 0][s], Ms[tm + 1][s], Ms[tm + 2][s], Ms[tm + 3][s]};
        const float4 xv = *(const float4*)&Xs[s][tn];
        const float xr[4] = {xv.x, xv.y, xv.z, xv.w};
#pragma unroll
        for (int i = 0; i < 4; ++i)
#pragma unroll
            for (int j = 0; j < 4; ++j)
                acc[i][j] = fmaf(mr[i], xr[j], acc[i][j]);
    }
    for (int n = 0; n < D_STATE; ++n) {
        const float4 ca = *(const float4*)&CsT[n][tm];
        const float4 hv = *(const float4*)&HsT[n][tn];
        const float ar[4] = {ca.x, ca.y, ca.z, ca.w};
        const float hr[4] = {hv.x, hv.y, hv.z, hv.w};
#pragma unroll
        for (int i = 0; i < 4; ++i)
#pragma unroll
            for (int j = 0; j < 4; ++j)
                acc[i][j] = fmaf(ar[i], hr[j], acc[i][j]);
    }

    const float Dh = Dp[h];
#pragma unroll
    for (int i = 0; i < 4; ++i) {
        float4 ov;
        ov.x = acc[i][0] + Dh * Xs[tm + i][tn + 0];
        ov.y = acc[i][1] + Dh * Xs[tm + i][tn + 1];
        ov.z = acc[i][2] + Dh * Xs[tm + i][tn + 2];
        ov.w = acc[i][3] + Dh * Xs[tm + i][tn + 3];
        *(float4*)(y + (size_t)(rowbase + tm + i) * D_SSM + h * HEADDIM + tn) = ov;
    }
}

// ---------------------------------------------------------------------------
// Fallback sequential scan (only if ws too small for chunked path).
// ---------------------------------------------------------------------------
__global__ __launch_bounds__(256) void scan_kernel(
    const float* __restrict__ xc, const float* __restrict__ dtw,
    const float* __restrict__ A_log, const float* __restrict__ Dp,
    float* __restrict__ y)
{
    const int b   = blockIdx.x / NHEADS;
    const int h   = blockIdx.x % NHEADS;
    const int tid = threadIdx.x;
    const int p   = tid >> 2;
    const int q   = tid & 3;

    __shared__ float dt_s[SEQLEN];
    __shared__ float Bs[4][36];
    __shared__ float Cs[4][36];
    __shared__ float xs[64];

    for (int i = tid; i < SEQLEN; i += 256)
        dt_s[i] = dtw[((size_t)b * SEQLEN + i) * NHEADS + h];

    const float Aneg = -__expf(A_log[h]);
    const float Dh   = Dp[h];

    float hst[32];
#pragma unroll
    for (int i = 0; i < 32; ++i) hst[i] = 0.f;

    const float* row0 = xc + (size_t)b * SEQLEN * CONV_DIM;
    float rBC = row0[D_SSM + tid];
    float rx  = (tid < 64) ? row0[h * HEADDIM + tid] : 0.f;

    for (int t = 0; t < SEQLEN; ++t) {
        __syncthreads();
        if (tid < 128) Bs[tid >> 5][tid & 31] = rBC;
        else           Cs[(tid >> 5) & 3][tid & 31] = rBC;
        if (tid < 64)  xs[tid] = rx;
        if (t + 1 < SEQLEN) {
            const float* rp = row0 + (size_t)(t + 1) * CONV_DIM;
            rBC = rp[D_SSM + tid];
            if (tid < 64) rx = rp[h * HEADDIM + tid];
        }
        __syncthreads();

        const float dtv = dt_s[t];
        const float dA  = __expf(dtv * Aneg);
        const float dtx = dtv * xs[p];
        float ysum = 0.f;
#pragma unroll
        for (int j4 = 0; j4 < 8; ++j4) {
            const float4 Bv = *(const float4*)&Bs[q][j4 * 4];
            const float4 Cv = *(const float4*)&Cs[q][j4 * 4];
            float* hp = &hst[j4 * 4];
            hp[0] = fmaf(hp[0], dA, dtx * Bv.x); ysum = fmaf(hp[0], Cv.x, ysum);
            hp[1] = fmaf(hp[1], dA, dtx * Bv.y); ysum = fmaf(hp[1], Cv.y, ysum);
            hp[2] = fmaf(hp[2], dA, dtx * Bv.z); ysum = fmaf(hp[2], Cv.z, ysum);
            hp[3] = fmaf(hp[3], dA, dtx * Bv.w); ysum = fmaf(hp[3], Cv.w, ysum);
        }
        ysum += __shfl_xor(ysum, 1);
        ysum += __shfl_xor(ysum, 2);
        if (q == 0)
            y[((size_t)b * SEQLEN + t) * D_SSM + h * HEADDIM + p] = ysum + Dh * xs[p];
    }
}

// ---------------------------------------------------------------------------
// In-place gate + RMSNorm; z from zbuf (stride D_SSM).
// ---------------------------------------------------------------------------
__global__ __launch_bounds__(256) void gatenorm_kernel(
    float* y, const float* __restrict__ zbuf, const float* __restrict__ norm_w)
{
    const int row = blockIdx.x;
    const int tid = threadIdx.x;
    float* yr = y + (size_t)row * D_SSM;
    const float* zr = zbuf + (size_t)row * D_SSM;

    float v[6];
    float ss = 0.f;
#pragma unroll
    for (int i = 0; i < 6; ++i) {
        const int e = tid + i * 256;
        const float yv = yr[e];
        const float zv = zr[e];
        const float g  = yv * (zv * sigmoidf_(zv));
        v[i] = g;
        ss = fmaf(g, g, ss);
    }
#pragma unroll
    for (int m = 1; m < 64; m <<= 1) ss += __shfl_xor(ss, m);
    __shared__ float ws[4];
    if ((tid & 63) == 0) ws[tid >> 6] = ss;
    __syncthreads();
    const float tot = ws[0] + ws[1] + ws[2] + ws[3];
    const float r = rsqrtf(tot * (1.0f / D_SSM) + EPS);
#pragma unroll
    for (int i = 0; i < 6; ++i) {
        const int e = tid + i * 256;
        yr[e] = v[i] * r * norm_w[e];
    }
}

// ---------------------------------------------------------------------------
extern "C" void kernel_launch(void* const* d_in, const int* in_sizes, int n_in,
                              void* d_out, int out_size, void* d_ws, size_t ws_size,
                              hipStream_t stream)
{
    const float* u       = (const float*)d_in[0];
    const float* W_in    = (const float*)d_in[1];
    const float* conv_w  = (const float*)d_in[2];
    const float* conv_b  = (const float*)d_in[3];
    const float* dt_bias = (const float*)d_in[4];
    const float* A_log   = (const float*)d_in[5];
    const float* Dp      = (const float*)d_in[6];
    const float* norm_w  = (const float*)d_in[7];
    const float* W_out   = (const float*)d_in[8];
    float* out = (float*)d_out;

    const size_t SZ_Z   = (size_t)NROWS * D_SSM;      // 12,582,912
    const size_t SZ_XBC = (size_t)NROWS * CONV_DIM;   // 14,680,064
    const size_t SZ_DT  = (size_t)NROWS * NHEADS;     //    196,608
    const size_t SZ_S   = (size_t)NBH * NC * HSTATE;  // 25,165,824
    const size_t SZ_CUM = (size_t)NBH * SEQLEN;       //    196,608

    // chunked layout: zbuf | R(=max(xbc, Sbuf+yb)) | dtraw | xc | dtw | cumws
    const size_t R_CH   = SZ_S + SZ_Z;
    const size_t need_chunked = (SZ_Z + R_CH + SZ_DT + SZ_XBC + SZ_DT + SZ_CUM) * sizeof(float);
    const bool use_chunked = ws_size >= need_chunked;
    const size_t R_SZ = use_chunked ? R_CH : SZ_XBC;

    float* zbuf  = (float*)d_ws;
    float* Rp    = zbuf + SZ_Z;
    float* xbc   = Rp;                         // phase 1 (dead after conv)
    float* Sbuf  = Rp;                         // phase 2 (chunked only)
    float* yb    = use_chunked ? (Rp + SZ_S) : Rp;   // phase 2
    float* dtraw = Rp + R_SZ;
    float* xc    = dtraw + SZ_DT;
    float* dtw   = xc + SZ_XBC;
    float* cumws = dtw + SZ_DT;                // chunked only

    // 1. in-projection with split outputs
    gemm_inproj<<<dim3((D_IN_PROJ + 63) / 64, NROWS / 64), 256, 0, stream>>>(
        u, W_in, zbuf, xbc, dtraw);

    // 2. conv + SiLU
    conv_silu_kernel<<<(NROWS * (CONV_DIM / 4) + 255) / 256, 256, 0, stream>>>(
        xbc, conv_w, conv_b, xc);

    // 3. dt
    dt_kernel<<<NROWS, 64, 0, stream>>>(dtraw, dt_bias, dtw);

    // 4. scan
    if (use_chunked) {
        chunk_state_kernel<<<NBH * NC, 256, 0, stream>>>(xc, dtw, A_log, Sbuf, cumws);
        state_scan_kernel<<<dim3(NBH, HSTATE / 256), 256, 0, stream>>>(cumws, Sbuf);
        chunk_output_kernel<<<NBH * NC, 256, 0, stream>>>(xc, dtw, Dp, Sbuf, cumws, yb);
    } else {
        scan_kernel<<<NBH, 256, 0, stream>>>(xc, dtw, A_log, Dp, yb);
    }

    // 5. gate + RMSNorm (in-place on yb)
    gatenorm_kernel<<<NROWS, 256, 0, stream>>>(yb, zbuf, norm_w);

    // 6. out-projection
    gemm_nt<64, 64, 16><<<dim3(D_MODEL / 64, NROWS / 64), 256, 0, stream>>>(
        yb, W_out, out, NROWS, D_MODEL, D_SSM);
}

// Round 5
// 860.802 us; speedup vs baseline: 3.0739x; 1.6582x over previous
//
#include <hip/hip_runtime.h>
#include <hip/hip_bf16.h>
#include <math.h>

#define D_MODEL   768
#define D_SSM     1536
#define D_STATE   128
#define D_CONV    4
#define HEADDIM   64
#define NHEADS    24
#define CONV_DIM  1792          // D_SSM + 2*D_STATE
#define D_IN_PROJ 3352          // 2*D_SSM + 2*D_STATE + NHEADS
#define BATCH     4
#define SEQLEN    2048
#define NROWS     (BATCH * SEQLEN)   // 8192
#define EPS       1e-5f

#define CHUNK     64
#define NC        (SEQLEN / CHUNK)    // 32
#define NBH       (BATCH * NHEADS)    // 96
#define HSTATE    (HEADDIM * D_STATE) // 8192

#define K3_IN     (3 * D_MODEL)       // 2304
#define K3_OUT    (3 * D_SSM)         // 4608
#define NPAD_IN   3456                // 27 * 128 (>= D_IN_PROJ)

typedef __attribute__((ext_vector_type(8))) short bf16x8;
typedef __attribute__((ext_vector_type(4))) float f32x4;

__device__ __forceinline__ float sigmoidf_(float x) {
    return 1.0f / (1.0f + __expf(-x));
}

__device__ __forceinline__ void gload16(void* lds, const void* g) {
    __builtin_amdgcn_global_load_lds(
        (const __attribute__((address_space(1))) unsigned int*)g,
        (__attribute__((address_space(3))) unsigned int*)lds, 16, 0, 0);
}

// ---------------------------------------------------------------------------
// Decompose fp32 [R][K] -> bf16 [Rpad][3K].
// APAT=1 (A-side): [hi | hi | lo]   APAT=0 (B-side): [hi | lo | hi]
// so that tripled-K dot = hi*hi + hi*lo + lo*hi ≈ full fp32 product.
// ---------------------------------------------------------------------------
template<int APAT>
__global__ __launch_bounds__(256) void decompose3(
    const float* __restrict__ X, __hip_bfloat16* __restrict__ X3,
    int R, int Rpad, int K)
{
    const int idx = blockIdx.x * 256 + threadIdx.x;
    if (idx >= Rpad * (K / 4)) return;
    const int r = idx / (K / 4);
    const int k = (idx % (K / 4)) * 4;

    union { __hip_bfloat16 h[4]; uint2 u; } phi, plo;
    if (r < R) {
        const float4 x = *(const float4*)(X + (size_t)r * K + k);
        const float xs[4] = {x.x, x.y, x.z, x.w};
#pragma unroll
        for (int j = 0; j < 4; ++j) {
            phi.h[j] = __float2bfloat16(xs[j]);
            plo.h[j] = __float2bfloat16(xs[j] - __bfloat162float(phi.h[j]));
        }
    } else {
#pragma unroll
        for (int j = 0; j < 4; ++j) { phi.h[j] = __float2bfloat16(0.f); plo.h[j] = phi.h[j]; }
    }
    __hip_bfloat16* row = X3 + (size_t)r * (3 * K);
    *(uint2*)(row + k)         = phi.u;
    *(uint2*)(row + K + k)     = APAT ? phi.u : plo.u;
    *(uint2*)(row + 2 * K + k) = APAT ? plo.u : phi.u;
}

// ---------------------------------------------------------------------------
// MFMA GEMM (NT): C[M,N] = A''[M,K3] * B''[N,K3]^T, bf16 in / fp32 out.
// 128x128 tile, 4 waves (2x2), 16x16x32 MFMA, BK=32.
// global_load_lds(16B) staging, double-buffered LDS, 2-phase pipeline.
// LDS slot swizzle swz(r) = (r ^ (r>>2)) & 3 applied on the GLOBAL source
// (linear LDS dest, rule #21) and on the ds_read side -> conflict-free b128.
// MODE 0: plain store to C0[M][Nreal].  MODE 1: in-proj column split.
// ---------------------------------------------------------------------------
template<int MODE>
__global__ __launch_bounds__(256) void gemm_bf16x3(
    const __hip_bfloat16* __restrict__ Ab, const __hip_bfloat16* __restrict__ Bb,
    float* __restrict__ C0, float* __restrict__ C1, float* __restrict__ C2,
    int Nreal, int K3)
{
    __shared__ __hip_bfloat16 Asm[2][128][32];
    __shared__ __hip_bfloat16 Bsm[2][128][32];
    const int tid  = threadIdx.x;
    const int lane = tid & 63;
    const int w    = tid >> 6;
    const int wr   = w >> 1, wc = w & 1;
    const int bm   = blockIdx.y * 128;
    const int bn   = blockIdx.x * 128;

    // staging: wave w covers tile rows [w*32, w*32+32), 2 instr x 16 rows.
    const __hip_bfloat16* gA[2];
    const __hip_bfloat16* gB[2];
    int ldsrow[2];
#pragma unroll
    for (int i = 0; i < 2; ++i) {
        const int r  = w * 32 + i * 16 + (lane >> 2);
        const int sl = (lane & 3) ^ ((r ^ (r >> 2)) & 3);   // inverse-swizzled source slot
        ldsrow[i] = w * 32 + i * 16;
        gA[i] = Ab + (size_t)(bm + r) * K3 + sl * 8;
        gB[i] = Bb + (size_t)(bn + r) * K3 + sl * 8;
    }

    // fragment LDS byte offsets (constant over K-loop)
    int aoff[4], boff[4];
#pragma unroll
    for (int mi = 0; mi < 4; ++mi) {
        const int ra = wr * 64 + mi * 16 + (lane & 15);
        aoff[mi] = ra * 64 + (((lane >> 4) ^ ((ra ^ (ra >> 2)) & 3)) << 4);
        const int rb = wc * 64 + mi * 16 + (lane & 15);
        boff[mi] = rb * 64 + (((lane >> 4) ^ ((rb ^ (rb >> 2)) & 3)) << 4);
    }

    f32x4 acc[4][4] = {};

    const int nk = K3 / 32;
    // prologue: stage kt=0 into buf 0
#pragma unroll
    for (int i = 0; i < 2; ++i) {
        gload16(&Asm[0][ldsrow[i]][0], gA[i]);
        gload16(&Bsm[0][ldsrow[i]][0], gB[i]);
    }
    __syncthreads();

    int buf = 0;
    for (int kt = 0; kt < nk; ++kt) {
        if (kt + 1 < nk) {
            const int ko = (kt + 1) * 32;
#pragma unroll
            for (int i = 0; i < 2; ++i) {
                gload16(&Asm[buf ^ 1][ldsrow[i]][0], gA[i] + ko);
                gload16(&Bsm[buf ^ 1][ldsrow[i]][0], gB[i] + ko);
            }
        }
        const char* ab = (const char*)&Asm[buf][0][0];
        const char* bb = (const char*)&Bsm[buf][0][0];
        bf16x8 afr[4], bfr[4];
#pragma unroll
        for (int i = 0; i < 4; ++i) {
            afr[i] = *(const bf16x8*)(ab + aoff[i]);
            bfr[i] = *(const bf16x8*)(bb + boff[i]);
        }
#pragma unroll
        for (int mi = 0; mi < 4; ++mi)
#pragma unroll
            for (int ni = 0; ni < 4; ++ni)
                acc[mi][ni] = __builtin_amdgcn_mfma_f32_16x16x32_bf16(
                    afr[mi], bfr[ni], acc[mi][ni], 0, 0, 0);
        __syncthreads();   // vmcnt(0): prefetch landed; lgkmcnt: reads of buf done
        buf ^= 1;
    }

    // epilogue: C/D layout col = lane&15, row = (lane>>4)*4 + j  [m89/m91]
#pragma unroll
    for (int mi = 0; mi < 4; ++mi) {
        const int rn = bm + wr * 64 + mi * 16 + ((lane >> 4) << 2);
#pragma unroll
        for (int ni = 0; ni < 4; ++ni) {
            const int cn = bn + wc * 64 + ni * 16 + (lane & 15);
#pragma unroll
            for (int j = 0; j < 4; ++j) {
                const float v = acc[mi][ni][j];
                const int r = rn + j;
                if (MODE == 0) {
                    C0[(size_t)r * Nreal + cn] = v;
                } else {
                    if (cn < D_SSM)                 C0[(size_t)r * D_SSM + cn] = v;
                    else if (cn < D_SSM + CONV_DIM) C1[(size_t)r * CONV_DIM + (cn - D_SSM)] = v;
                    else if (cn < D_IN_PROJ)        C2[(size_t)r * NHEADS + (cn - D_SSM - CONV_DIM)] = v;
                }
            }
        }
    }
}

// ---------------------------------------------------------------------------
// fp32 GEMM kernels (fallback path only)
// ---------------------------------------------------------------------------
template<int BM, int BN, int BK>
__global__ __launch_bounds__(256) void gemm_nt(
    const float* __restrict__ A, const float* __restrict__ B,
    float* __restrict__ C, int M, int N, int K)
{
    __shared__ float As[BK][BM];
    __shared__ float Bs[BK][BN];
    const int tid = threadIdx.x;
    const int bm  = blockIdx.y * BM;
    const int bn  = blockIdx.x * BN;
    const int tm  = (tid & 15) << 2;
    const int tn  = (tid >> 4) << 2;
    const int am  = tid & 63;
    const int ak  = (tid >> 6) << 2;
    float acc[4][4] = {};
    for (int k0 = 0; k0 < K; k0 += BK) {
        const float4 av = *(const float4*)(A + (size_t)(bm + am) * K + (k0 + ak));
        float4 bv = make_float4(0.f, 0.f, 0.f, 0.f);
        if (bn + am < N)
            bv = *(const float4*)(B + (size_t)(bn + am) * K + (k0 + ak));
        __syncthreads();
        As[ak + 0][am] = av.x; As[ak + 1][am] = av.y;
        As[ak + 2][am] = av.z; As[ak + 3][am] = av.w;
        Bs[ak + 0][am] = bv.x; Bs[ak + 1][am] = bv.y;
        Bs[ak + 2][am] = bv.z; Bs[ak + 3][am] = bv.w;
        __syncthreads();
#pragma unroll
        for (int kk = 0; kk < BK; ++kk) {
            const float4 a4 = *(const float4*)&As[kk][tm];
            const float4 b4 = *(const float4*)&Bs[kk][tn];
            const float a[4]  = {a4.x, a4.y, a4.z, a4.w};
            const float bb[4] = {b4.x, b4.y, b4.z, b4.w};
#pragma unroll
            for (int i = 0; i < 4; ++i)
#pragma unroll
                for (int j = 0; j < 4; ++j)
                    acc[i][j] = fmaf(a[i], bb[j], acc[i][j]);
        }
    }
#pragma unroll
    for (int i = 0; i < 4; ++i)
#pragma unroll
        for (int j = 0; j < 4; ++j) {
            const int cn = bn + tn + j;
            if (cn < N)
                C[(size_t)(bm + tm + i) * N + cn] = acc[i][j];
        }
}

__global__ __launch_bounds__(256) void gemm_inproj(
    const float* __restrict__ A, const float* __restrict__ B,
    float* __restrict__ zbuf, float* __restrict__ xbc, float* __restrict__ dtraw)
{
    constexpr int BM = 64, BN = 64, BK = 16;
    __shared__ float As[BK][BM];
    __shared__ float Bs[BK][BN];
    const int tid = threadIdx.x;
    const int bm  = blockIdx.y * BM;
    const int bn  = blockIdx.x * BN;
    const int tm  = (tid & 15) << 2;
    const int tn  = (tid >> 4) << 2;
    const int am  = tid & 63;
    const int ak  = (tid >> 6) << 2;
    float acc[4][4] = {};
    for (int k0 = 0; k0 < D_MODEL; k0 += BK) {
        const float4 av = *(const float4*)(A + (size_t)(bm + am) * D_MODEL + (k0 + ak));
        float4 bv = make_float4(0.f, 0.f, 0.f, 0.f);
        if (bn + am < D_IN_PROJ)
            bv = *(const float4*)(B + (size_t)(bn + am) * D_MODEL + (k0 + ak));
        __syncthreads();
        As[ak + 0][am] = av.x; As[ak + 1][am] = av.y;
        As[ak + 2][am] = av.z; As[ak + 3][am] = av.w;
        Bs[ak + 0][am] = bv.x; Bs[ak + 1][am] = bv.y;
        Bs[ak + 2][am] = bv.z; Bs[ak + 3][am] = bv.w;
        __syncthreads();
#pragma unroll
        for (int kk = 0; kk < BK; ++kk) {
            const float4 a4 = *(const float4*)&As[kk][tm];
            const float4 b4 = *(const float4*)&Bs[kk][tn];
            const float a[4]  = {a4.x, a4.y, a4.z, a4.w};
            const float bb[4] = {b4.x, b4.y, b4.z, b4.w};
#pragma unroll
            for (int i = 0; i < 4; ++i)
#pragma unroll
                for (int j = 0; j < 4; ++j)
                    acc[i][j] = fmaf(a[i], bb[j], acc[i][j]);
        }
    }
    float* Cp; int ldc, cb, nlim = BN;
    if (bn < D_SSM)                  { Cp = zbuf;  ldc = D_SSM;    cb = bn; }
    else if (bn < D_SSM + CONV_DIM)  { Cp = xbc;   ldc = CONV_DIM; cb = bn - D_SSM; }
    else { Cp = dtraw; ldc = NHEADS; cb = bn - (D_SSM + CONV_DIM); nlim = NHEADS; }
#pragma unroll
    for (int i = 0; i < 4; ++i)
#pragma unroll
        for (int j = 0; j < 4; ++j)
            if (tn + j < nlim)
                Cp[(size_t)(bm + tm + i) * ldc + cb + tn + j] = acc[i][j];
}

// ---------------------------------------------------------------------------
// Depthwise causal conv (width 4) + bias + SiLU.
// ---------------------------------------------------------------------------
__global__ __launch_bounds__(256) void conv_silu_kernel(
    const float* __restrict__ xbc, const float* __restrict__ cw,
    const float* __restrict__ cb, float* __restrict__ xc)
{
    const int idx = blockIdx.x * 256 + threadIdx.x;
    if (idx >= NROWS * (CONV_DIM / 4)) return;
    const int row = idx / (CONV_DIM / 4);
    const int c   = (idx % (CONV_DIM / 4)) * 4;
    const int l   = row & (SEQLEN - 1);

    const float* base = xbc + (size_t)row * CONV_DIM + c;
    const float4 cbv = *(const float4*)(cb + c);
    float acc[4] = {cbv.x, cbv.y, cbv.z, cbv.w};
    const float* w = cw + (size_t)c * D_CONV;
#pragma unroll
    for (int k = 0; k < D_CONV; ++k) {
        const int ls = l + k - 3;
        if (ls >= 0) {
            const float4 xv = *(const float4*)(base + (ptrdiff_t)(k - 3) * CONV_DIM);
            acc[0] = fmaf(w[0 * D_CONV + k], xv.x, acc[0]);
            acc[1] = fmaf(w[1 * D_CONV + k], xv.y, acc[1]);
            acc[2] = fmaf(w[2 * D_CONV + k], xv.z, acc[2]);
            acc[3] = fmaf(w[3 * D_CONV + k], xv.w, acc[3]);
        }
    }
    float4 o;
    o.x = acc[0] * sigmoidf_(acc[0]);
    o.y = acc[1] * sigmoidf_(acc[1]);
    o.z = acc[2] * sigmoidf_(acc[2]);
    o.w = acc[3] * sigmoidf_(acc[3]);
    *(float4*)(xc + (size_t)row * CONV_DIM + c) = o;
}

// ---------------------------------------------------------------------------
// dt = softplus(dt_raw + dt_bias)
// ---------------------------------------------------------------------------
__global__ __launch_bounds__(64) void dt_kernel(
    const float* __restrict__ dtraw, const float* __restrict__ dt_bias,
    float* __restrict__ dtw)
{
    const int row = blockIdx.x;
    const int tid = threadIdx.x;
    if (tid < NHEADS) {
        const float x = dtraw[(size_t)row * NHEADS + tid] + dt_bias[tid];
        const float sp = fmaxf(x, 0.f) + log1pf(__expf(-fabsf(x)));
        dtw[(size_t)row * NHEADS + tid] = sp;
    }
}

// ---------------------------------------------------------------------------
// Pass A: chunk-local cumsum of a=A*dt (-> cumws) and local end-state.
// ---------------------------------------------------------------------------
__global__ __launch_bounds__(256) void chunk_state_kernel(
    const float* __restrict__ xc, const float* __restrict__ dtw,
    const float* __restrict__ A_log,
    float* __restrict__ Sbuf, float* __restrict__ cumws)
{
    const int c  = blockIdx.x / NBH;
    const int bh = blockIdx.x % NBH;
    const int b  = bh / NHEADS, h = bh % NHEADS;
    const int tid = threadIdx.x;
    const int rowbase = b * SEQLEN + c * CHUNK;

    __shared__ float cums[CHUNK];
    __shared__ float wls[CHUNK];
    __shared__ float Xw[CHUNK][HEADDIM];
    __shared__ float Bsh[CHUNK][D_STATE];

    const float Aneg = -__expf(A_log[h]);

    float dtv = 0.f;
    if (tid < CHUNK) dtv = dtw[(size_t)(rowbase + tid) * NHEADS + h];
    float v = Aneg * dtv;
#pragma unroll
    for (int d = 1; d < 64; d <<= 1) {
        const float o = __shfl_up(v, d);
        if ((tid & 63) >= d) v += o;
    }
    if (tid < CHUNK) {
        cums[tid] = v;
        cumws[(size_t)bh * SEQLEN + c * CHUNK + tid] = v;
    }
    __syncthreads();
    const float clast = cums[CHUNK - 1];
    if (tid < CHUNK) wls[tid] = __expf(clast - v) * dtv;
    __syncthreads();

    {
        const int p0 = (tid & 15) * 4, s0 = tid >> 4;
        for (int s = s0; s < CHUNK; s += 16) {
            const float4 xv = *(const float4*)(xc + (size_t)(rowbase + s) * CONV_DIM + h * HEADDIM + p0);
            const float w = wls[s];
            *(float4*)&Xw[s][p0] = make_float4(xv.x * w, xv.y * w, xv.z * w, xv.w * w);
        }
        const int n0 = (tid & 31) * 4, s1 = tid >> 5;
        for (int s = s1; s < CHUNK; s += 8)
            *(float4*)&Bsh[s][n0] = *(const float4*)(xc + (size_t)(rowbase + s) * CONV_DIM + D_SSM + n0);
    }
    __syncthreads();

    const int tp = (tid & 15) * 4;
    const int tn = (tid >> 4) * 8;
    float acc[4][8] = {};
    for (int s = 0; s < CHUNK; ++s) {
        const float4 xa = *(const float4*)&Xw[s][tp];
        const float4 b0 = *(const float4*)&Bsh[s][tn];
        const float4 b1 = *(const float4*)&Bsh[s][tn + 4];
        const float xr[4] = {xa.x, xa.y, xa.z, xa.w};
        const float br[8] = {b0.x, b0.y, b0.z, b0.w, b1.x, b1.y, b1.z, b1.w};
#pragma unroll
        for (int i = 0; i < 4; ++i)
#pragma unroll
            for (int j = 0; j < 8; ++j)
                acc[i][j] = fmaf(xr[i], br[j], acc[i][j]);
    }
    float* Sp = Sbuf + (size_t)(bh * NC + c) * HSTATE;
#pragma unroll
    for (int i = 0; i < 4; ++i) {
        *(float4*)(Sp + (size_t)(tp + i) * D_STATE + tn)     = make_float4(acc[i][0], acc[i][1], acc[i][2], acc[i][3]);
        *(float4*)(Sp + (size_t)(tp + i) * D_STATE + tn + 4) = make_float4(acc[i][4], acc[i][5], acc[i][6], acc[i][7]);
    }
}

// ---------------------------------------------------------------------------
// Pass B: per-element scan over chunks, in-place S -> H_in.
// ---------------------------------------------------------------------------
__global__ __launch_bounds__(256) void state_scan_kernel(
    const float* __restrict__ cumws, float* __restrict__ Sbuf)
{
    const int bh = blockIdx.x;
    const int e  = blockIdx.y * 256 + threadIdx.x;
    float* base = Sbuf + (size_t)bh * NC * HSTATE + e;
    const float* cw = cumws + (size_t)bh * SEQLEN;
    float H = 0.f;
    for (int c = 0; c < NC; ++c) {
        const float P = __expf(cw[c * CHUNK + CHUNK - 1]);
        const float s = base[(size_t)c * HSTATE];
        base[(size_t)c * HSTATE] = H;
        H = fmaf(P, H, s);
    }
}

// ---------------------------------------------------------------------------
// Pass C: intra-chunk output + carry-in.
// ---------------------------------------------------------------------------
__global__ __launch_bounds__(256) void chunk_output_kernel(
    const float* __restrict__ xc, const float* __restrict__ dtw,
    const float* __restrict__ Dp,
    const float* __restrict__ Hbuf, const float* __restrict__ cumws,
    float* __restrict__ y)
{
    const int c  = blockIdx.x / NBH;
    const int bh = blockIdx.x % NBH;
    const int b  = bh / NHEADS, h = bh % NHEADS;
    const int tid = threadIdx.x;
    const int rowbase = b * SEQLEN + c * CHUNK;

    __shared__ float cums[CHUNK], dts[CHUNK], Es[CHUNK];
    __shared__ float CsT[D_STATE][CHUNK];
    __shared__ float BsT[D_STATE][CHUNK];
    __shared__ float HsT[D_STATE][HEADDIM];
    __shared__ float Xs[CHUNK][HEADDIM];
    __shared__ float Ms[CHUNK][CHUNK + 1];

    if (tid < CHUNK) {
        const float cv = cumws[(size_t)bh * SEQLEN + c * CHUNK + tid];
        cums[tid] = cv;
        Es[tid] = __expf(cv);
        dts[tid] = dtw[(size_t)(rowbase + tid) * NHEADS + h];
    }

    {
        const int t = tid & 63;
        const int nq = (tid >> 6) * 4;
        const float* rowp = xc + (size_t)(rowbase + t) * CONV_DIM;
        for (int n = nq; n < D_STATE; n += 16) {
            const float4 cv = *(const float4*)(rowp + D_SSM + D_STATE + n);
            CsT[n + 0][t] = cv.x; CsT[n + 1][t] = cv.y;
            CsT[n + 2][t] = cv.z; CsT[n + 3][t] = cv.w;
            const float4 bv = *(const float4*)(rowp + D_SSM + n);
            BsT[n + 0][t] = bv.x; BsT[n + 1][t] = bv.y;
            BsT[n + 2][t] = bv.z; BsT[n + 3][t] = bv.w;
        }
        const float* Hp = Hbuf + (size_t)(bh * NC + c) * HSTATE;
        for (int n = nq; n < D_STATE; n += 16) {
            const float4 hv = *(const float4*)(Hp + (size_t)t * D_STATE + n);
            HsT[n + 0][t] = hv.x; HsT[n + 1][t] = hv.y;
            HsT[n + 2][t] = hv.z; HsT[n + 3][t] = hv.w;
        }
        const int p0 = (tid & 15) * 4, s0 = tid >> 4;
        for (int s = s0; s < CHUNK; s += 16)
            *(float4*)&Xs[s][p0] =
                *(const float4*)(xc + (size_t)(rowbase + s) * CONV_DIM + h * HEADDIM + p0);
    }
    __syncthreads();

    const int tm = (tid & 15) * 4;
    const int tn = (tid >> 4) * 4;

    float g[4][4] = {};
    for (int n = 0; n < D_STATE; ++n) {
        const float4 ca = *(const float4*)&CsT[n][tm];
        const float4 bb = *(const float4*)&BsT[n][tn];
        const float ar[4] = {ca.x, ca.y, ca.z, ca.w};
        const float br[4] = {bb.x, bb.y, bb.z, bb.w};
#pragma unroll
        for (int i = 0; i < 4; ++i)
#pragma unroll
            for (int j = 0; j < 4; ++j)
                g[i][j] = fmaf(ar[i], br[j], g[i][j]);
    }
    __syncthreads();

#pragma unroll
    for (int i = 0; i < 4; ++i) {
        const int t = tm + i;
        float4 mv;
        float* mp = (float*)&mv;
#pragma unroll
        for (int j = 0; j < 4; ++j) {
            const int s = tn + j;
            mp[j] = (s <= t) ? g[i][j] * __expf(cums[t] - cums[s]) * dts[s] : 0.f;
        }
        *(float4*)&Ms[t][tn] = mv;
    }
    for (int e = tid; e < D_STATE * CHUNK; e += 256) {
        const int n = e >> 6, t = e & 63;
        CsT[n][t] *= Es[t];
    }
    __syncthreads();

    float acc[4][4] = {};
    for (int s = 0; s < CHUNK; ++s) {
        const float mr[4] = {Ms[tm + 0][s], Ms[tm + 1][s], Ms[tm + 2][s], Ms[tm + 3][s]};
        const float4 xv = *(const float4*)&Xs[s][tn];
        const float xr[4] = {xv.x, xv.y, xv.z, xv.w};
#pragma unroll
        for (int i = 0; i < 4; ++i)
#pragma unroll
            for (int j = 0; j < 4; ++j)
                acc[i][j] = fmaf(mr[i], xr[j], acc[i][j]);
    }
    for (int n = 0; n < D_STATE; ++n) {
        const float4 ca = *(const float4*)&CsT[n][tm];
        const float4 hv = *(const float4*)&HsT[n][tn];
        const float ar[4] = {ca.x, ca.y, ca.z, ca.w};
        const float hr[4] = {hv.x, hv.y, hv.z, hv.w};
#pragma unroll
        for (int i = 0; i < 4; ++i)
#pragma unroll
            for (int j = 0; j < 4; ++j)
                acc[i][j] = fmaf(ar[i], hr[j], acc[i][j]);
    }

    const float Dh = Dp[h];
#pragma unroll
    for (int i = 0; i < 4; ++i) {
        float4 ov;
        ov.x = acc[i][0] + Dh * Xs[tm + i][tn + 0];
        ov.y = acc[i][1] + Dh * Xs[tm + i][tn + 1];
        ov.z = acc[i][2] + Dh * Xs[tm + i][tn + 2];
        ov.w = acc[i][3] + Dh * Xs[tm + i][tn + 3];
        *(float4*)(y + (size_t)(rowbase + tm + i) * D_SSM + h * HEADDIM + tn) = ov;
    }
}

// ---------------------------------------------------------------------------
// Fallback sequential scan.
// ---------------------------------------------------------------------------
__global__ __launch_bounds__(256) void scan_kernel(
    const float* __restrict__ xc, const float* __restrict__ dtw,
    const float* __restrict__ A_log, const float* __restrict__ Dp,
    float* __restrict__ y)
{
    const int b   = blockIdx.x / NHEADS;
    const int h   = blockIdx.x % NHEADS;
    const int tid = threadIdx.x;
    const int p   = tid >> 2;
    const int q   = tid & 3;

    __shared__ float dt_s[SEQLEN];
    __shared__ float Bs[4][36];
    __shared__ float Cs[4][36];
    __shared__ float xs[64];

    for (int i = tid; i < SEQLEN; i += 256)
        dt_s[i] = dtw[((size_t)b * SEQLEN + i) * NHEADS + h];

    const float Aneg = -__expf(A_log[h]);
    const float Dh   = Dp[h];

    float hst[32];
#pragma unroll
    for (int i = 0; i < 32; ++i) hst[i] = 0.f;

    const float* row0 = xc + (size_t)b * SEQLEN * CONV_DIM;
    float rBC = row0[D_SSM + tid];
    float rx  = (tid < 64) ? row0[h * HEADDIM + tid] : 0.f;

    for (int t = 0; t < SEQLEN; ++t) {
        __syncthreads();
        if (tid < 128) Bs[tid >> 5][tid & 31] = rBC;
        else           Cs[(tid >> 5) & 3][tid & 31] = rBC;
        if (tid < 64)  xs[tid] = rx;
        if (t + 1 < SEQLEN) {
            const float* rp = row0 + (size_t)(t + 1) * CONV_DIM;
            rBC = rp[D_SSM + tid];
            if (tid < 64) rx = rp[h * HEADDIM + tid];
        }
        __syncthreads();

        const float dtv = dt_s[t];
        const float dA  = __expf(dtv * Aneg);
        const float dtx = dtv * xs[p];
        float ysum = 0.f;
#pragma unroll
        for (int j4 = 0; j4 < 8; ++j4) {
            const float4 Bv = *(const float4*)&Bs[q][j4 * 4];
            const float4 Cv = *(const float4*)&Cs[q][j4 * 4];
            float* hp = &hst[j4 * 4];
            hp[0] = fmaf(hp[0], dA, dtx * Bv.x); ysum = fmaf(hp[0], Cv.x, ysum);
            hp[1] = fmaf(hp[1], dA, dtx * Bv.y); ysum = fmaf(hp[1], Cv.y, ysum);
            hp[2] = fmaf(hp[2], dA, dtx * Bv.z); ysum = fmaf(hp[2], Cv.z, ysum);
            hp[3] = fmaf(hp[3], dA, dtx * Bv.w); ysum = fmaf(hp[3], Cv.w, ysum);
        }
        ysum += __shfl_xor(ysum, 1);
        ysum += __shfl_xor(ysum, 2);
        if (q == 0)
            y[((size_t)b * SEQLEN + t) * D_SSM + h * HEADDIM + p] = ysum + Dh * xs[p];
    }
}

// ---------------------------------------------------------------------------
// Gate + RMSNorm -> bf16x3 rows (A-pattern [hi|hi|lo], K=1536 -> 4608).
// ---------------------------------------------------------------------------
__global__ __launch_bounds__(256) void gatenorm_x3_kernel(
    const float* __restrict__ y, const float* __restrict__ zbuf,
    const float* __restrict__ norm_w, __hip_bfloat16* __restrict__ ybx3)
{
    const int row = blockIdx.x;
    const int tid = threadIdx.x;
    const float* yr = y + (size_t)row * D_SSM;
    const float* zr = zbuf + (size_t)row * D_SSM;

    float v[6];
    float ss = 0.f;
#pragma unroll
    for (int i = 0; i < 6; ++i) {
        const int e = tid + i * 256;
        const float yv = yr[e];
        const float zv = zr[e];
        const float g  = yv * (zv * sigmoidf_(zv));
        v[i] = g;
        ss = fmaf(g, g, ss);
    }
#pragma unroll
    for (int m = 1; m < 64; m <<= 1) ss += __shfl_xor(ss, m);
    __shared__ float ws[4];
    if ((tid & 63) == 0) ws[tid >> 6] = ss;
    __syncthreads();
    const float tot = ws[0] + ws[1] + ws[2] + ws[3];
    const float r = rsqrtf(tot * (1.0f / D_SSM) + EPS);
    __hip_bfloat16* orow = ybx3 + (size_t)row * K3_OUT;
#pragma unroll
    for (int i = 0; i < 6; ++i) {
        const int e = tid + i * 256;
        const float g = v[i] * r * norm_w[e];
        const __hip_bfloat16 hi = __float2bfloat16(g);
        const __hip_bfloat16 lo = __float2bfloat16(g - __bfloat162float(hi));
        orow[e] = hi;
        orow[D_SSM + e] = hi;
        orow[2 * D_SSM + e] = lo;
    }
}

// ---------------------------------------------------------------------------
// Gate + RMSNorm in place (fallback path).
// ---------------------------------------------------------------------------
__global__ __launch_bounds__(256) void gatenorm_kernel(
    float* y, const float* __restrict__ zbuf, const float* __restrict__ norm_w)
{
    const int row = blockIdx.x;
    const int tid = threadIdx.x;
    float* yr = y + (size_t)row * D_SSM;
    const float* zr = zbuf + (size_t)row * D_SSM;

    float v[6];
    float ss = 0.f;
#pragma unroll
    for (int i = 0; i < 6; ++i) {
        const int e = tid + i * 256;
        const float yv = yr[e];
        const float zv = zr[e];
        const float g  = yv * (zv * sigmoidf_(zv));
        v[i] = g;
        ss = fmaf(g, g, ss);
    }
#pragma unroll
    for (int m = 1; m < 64; m <<= 1) ss += __shfl_xor(ss, m);
    __shared__ float ws[4];
    if ((tid & 63) == 0) ws[tid >> 6] = ss;
    __syncthreads();
    const float tot = ws[0] + ws[1] + ws[2] + ws[3];
    const float r = rsqrtf(tot * (1.0f / D_SSM) + EPS);
#pragma unroll
    for (int i = 0; i < 6; ++i) {
        const int e = tid + i * 256;
        yr[e] = v[i] * r * norm_w[e];
    }
}

// ---------------------------------------------------------------------------
extern "C" void kernel_launch(void* const* d_in, const int* in_sizes, int n_in,
                              void* d_out, int out_size, void* d_ws, size_t ws_size,
                              hipStream_t stream)
{
    const float* u       = (const float*)d_in[0];
    const float* W_in    = (const float*)d_in[1];
    const float* conv_w  = (const float*)d_in[2];
    const float* conv_b  = (const float*)d_in[3];
    const float* dt_bias = (const float*)d_in[4];
    const float* A_log   = (const float*)d_in[5];
    const float* Dp      = (const float*)d_in[6];
    const float* norm_w  = (const float*)d_in[7];
    const float* W_out   = (const float*)d_in[8];
    float* out = (float*)d_out;

    const size_t SZ_Z   = (size_t)NROWS * D_SSM;      // 12,582,912
    const size_t SZ_XBC = (size_t)NROWS * CONV_DIM;   // 14,680,064
    const size_t SZ_DT  = (size_t)NROWS * NHEADS;     //    196,608
    const size_t SZ_S   = (size_t)NBH * NC * HSTATE;  // 25,165,824
    const size_t SZ_CUM = (size_t)NBH * SEQLEN;       //    196,608

    // new layout: zbuf | B(xbc+dtraw | Sbuf | ybx3) | C(u3 | yb) | X(W_in3 | xc | W_out3) | dtw | cumws
    const size_t need_new = (SZ_Z + SZ_S + SZ_Z + SZ_XBC + SZ_DT + SZ_CUM) * sizeof(float);
    const bool use_new = ws_size >= need_new;

    if (use_new) {
        float* zbuf = (float*)d_ws;
        float* Breg = zbuf + SZ_Z;     // 25,165,824 f
        float* Creg = Breg + SZ_S;     // 12,582,912 f
        float* Xreg = Creg + SZ_Z;     // 14,680,064 f
        float* dtw   = Xreg + SZ_XBC;
        float* cumws = dtw + SZ_DT;

        float* xbc   = Breg;
        float* dtraw = Breg + SZ_XBC;
        float* Sbuf  = Breg;
        __hip_bfloat16* ybx3 = (__hip_bfloat16*)Breg;
        __hip_bfloat16* u3   = (__hip_bfloat16*)Creg;
        float* yb    = Creg;
        __hip_bfloat16* W_in3  = (__hip_bfloat16*)Xreg;
        float* xc    = Xreg;
        __hip_bfloat16* W_out3 = (__hip_bfloat16*)Xreg;

        // 1. decompose operands for in-projection
        decompose3<1><<<(NROWS * (D_MODEL / 4) + 255) / 256, 256, 0, stream>>>(
            u, u3, NROWS, NROWS, D_MODEL);
        decompose3<0><<<(NPAD_IN * (D_MODEL / 4) + 255) / 256, 256, 0, stream>>>(
            W_in, W_in3, D_IN_PROJ, NPAD_IN, D_MODEL);

        // 2. in-projection (MFMA bf16x3, split outputs)
        gemm_bf16x3<1><<<dim3(NPAD_IN / 128, NROWS / 128), 256, 0, stream>>>(
            u3, W_in3, zbuf, xbc, dtraw, 0, K3_IN);

        // 3. conv + SiLU
        conv_silu_kernel<<<(NROWS * (CONV_DIM / 4) + 255) / 256, 256, 0, stream>>>(
            xbc, conv_w, conv_b, xc);

        // 4. dt
        dt_kernel<<<NROWS, 64, 0, stream>>>(dtraw, dt_bias, dtw);

        // 5. chunked scan
        chunk_state_kernel<<<NBH * NC, 256, 0, stream>>>(xc, dtw, A_log, Sbuf, cumws);
        state_scan_kernel<<<dim3(NBH, HSTATE / 256), 256, 0, stream>>>(cumws, Sbuf);
        chunk_output_kernel<<<NBH * NC, 256, 0, stream>>>(xc, dtw, Dp, Sbuf, cumws, yb);

        // 6. decompose W_out (xc now dead)
        decompose3<0><<<(D_MODEL * (D_SSM / 4) + 255) / 256, 256, 0, stream>>>(
            W_out, W_out3, D_MODEL, D_MODEL, D_SSM);

        // 7. gate + RMSNorm -> bf16x3 A-operand (Sbuf now dead)
        gatenorm_x3_kernel<<<NROWS, 256, 0, stream>>>(yb, zbuf, norm_w, ybx3);

        // 8. out-projection (MFMA bf16x3)
        gemm_bf16x3<0><<<dim3(D_MODEL / 128, NROWS / 128), 256, 0, stream>>>(
            ybx3, W_out3, out, nullptr, nullptr, D_MODEL, K3_OUT);
    } else {
        // fp32 fallback (round-4 path)
        float* zbuf  = (float*)d_ws;
        float* Rp    = zbuf + SZ_Z;
        float* xbc   = Rp;
        float* yb    = Rp;
        float* dtraw = Rp + SZ_XBC;
        float* xc    = dtraw + SZ_DT;
        float* dtw   = xc + SZ_XBC;

        gemm_inproj<<<dim3((D_IN_PROJ + 63) / 64, NROWS / 64), 256, 0, stream>>>(
            u, W_in, zbuf, xbc, dtraw);
        conv_silu_kernel<<<(NROWS * (CONV_DIM / 4) + 255) / 256, 256, 0, stream>>>(
            xbc, conv_w, conv_b, xc);
        dt_kernel<<<NROWS, 64, 0, stream>>>(dtraw, dt_bias, dtw);
        scan_kernel<<<NBH, 256, 0, stream>>>(xc, dtw, A_log, Dp, yb);
        gatenorm_kernel<<<NROWS, 256, 0, stream>>>(yb, zbuf, norm_w);
        gemm_nt<64, 64, 16><<<dim3(D_MODEL / 64, NROWS / 64), 256, 0, stream>>>(
            yb, W_out, out, NROWS, D_MODEL, D_SSM);
    }
}

// Round 6
// 841.731 us; speedup vs baseline: 3.1436x; 1.0227x over previous
//
#include <hip/hip_runtime.h>
#include <hip/hip_bf16.h>
#include <math.h>

#define D_MODEL   768
#define D_SSM     1536
#define D_STATE   128
#define D_CONV    4
#define HEADDIM   64
#define NHEADS    24
#define CONV_DIM  1792          // D_SSM + 2*D_STATE
#define D_IN_PROJ 3352          // 2*D_SSM + 2*D_STATE + NHEADS
#define BATCH     4
#define SEQLEN    2048
#define NROWS     (BATCH * SEQLEN)   // 8192
#define EPS       1e-5f

#define CHUNK     64
#define NC        (SEQLEN / CHUNK)    // 32
#define NBH       (BATCH * NHEADS)    // 96
#define HSTATE    (HEADDIM * D_STATE) // 8192

#define K3_IN     (3 * D_MODEL)       // 2304
#define K3_OUT    (3 * D_SSM)         // 4608
#define NPAD_IN   3456                // 27 * 128 (>= D_IN_PROJ)

typedef __attribute__((ext_vector_type(8))) short bf16x8;
typedef __attribute__((ext_vector_type(4))) float f32x4;

__device__ __forceinline__ float sigmoidf_(float x) {
    return 1.0f / (1.0f + __expf(-x));
}

__device__ __forceinline__ void gload16(void* lds, const void* g) {
    __builtin_amdgcn_global_load_lds(
        (const __attribute__((address_space(1))) unsigned int*)g,
        (__attribute__((address_space(3))) unsigned int*)lds, 16, 0, 0);
}

// ---------------------------------------------------------------------------
// Decompose fp32 [R][K] -> bf16 [Rpad][3K].
// APAT=1 (A-side): [hi | hi | lo]   APAT=0 (B-side): [hi | lo | hi]
// ---------------------------------------------------------------------------
template<int APAT>
__global__ __launch_bounds__(256) void decompose3(
    const float* __restrict__ X, __hip_bfloat16* __restrict__ X3,
    int R, int Rpad, int K)
{
    const int idx = blockIdx.x * 256 + threadIdx.x;
    if (idx >= Rpad * (K / 4)) return;
    const int r = idx / (K / 4);
    const int k = (idx % (K / 4)) * 4;

    union { __hip_bfloat16 h[4]; uint2 u; } phi, plo;
    if (r < R) {
        const float4 x = *(const float4*)(X + (size_t)r * K + k);
        const float xs[4] = {x.x, x.y, x.z, x.w};
#pragma unroll
        for (int j = 0; j < 4; ++j) {
            phi.h[j] = __float2bfloat16(xs[j]);
            plo.h[j] = __float2bfloat16(xs[j] - __bfloat162float(phi.h[j]));
        }
    } else {
#pragma unroll
        for (int j = 0; j < 4; ++j) { phi.h[j] = __float2bfloat16(0.f); plo.h[j] = phi.h[j]; }
    }
    __hip_bfloat16* row = X3 + (size_t)r * (3 * K);
    *(uint2*)(row + k)         = phi.u;
    *(uint2*)(row + K + k)     = APAT ? phi.u : plo.u;
    *(uint2*)(row + 2 * K + k) = APAT ? plo.u : phi.u;
}

// ---------------------------------------------------------------------------
// MFMA GEMM (NT): C[M,N] = A''[M,K3] * B''[N,K3]^T, bf16 in / fp32 out.
// 128x128 tile, 4 waves, 16x16x32 MFMA, BK=32, gload_lds dbuf.
// ---------------------------------------------------------------------------
template<int MODE>
__global__ __launch_bounds__(256) void gemm_bf16x3(
    const __hip_bfloat16* __restrict__ Ab, const __hip_bfloat16* __restrict__ Bb,
    float* __restrict__ C0, float* __restrict__ C1, float* __restrict__ C2,
    int Nreal, int K3)
{
    __shared__ __hip_bfloat16 Asm[2][128][32];
    __shared__ __hip_bfloat16 Bsm[2][128][32];
    const int tid  = threadIdx.x;
    const int lane = tid & 63;
    const int w    = tid >> 6;
    const int wr   = w >> 1, wc = w & 1;
    const int bm   = blockIdx.y * 128;
    const int bn   = blockIdx.x * 128;

    const __hip_bfloat16* gA[2];
    const __hip_bfloat16* gB[2];
    int ldsrow[2];
#pragma unroll
    for (int i = 0; i < 2; ++i) {
        const int r  = w * 32 + i * 16 + (lane >> 2);
        const int sl = (lane & 3) ^ ((r ^ (r >> 2)) & 3);
        ldsrow[i] = w * 32 + i * 16;
        gA[i] = Ab + (size_t)(bm + r) * K3 + sl * 8;
        gB[i] = Bb + (size_t)(bn + r) * K3 + sl * 8;
    }

    int aoff[4], boff[4];
#pragma unroll
    for (int mi = 0; mi < 4; ++mi) {
        const int ra = wr * 64 + mi * 16 + (lane & 15);
        aoff[mi] = ra * 64 + (((lane >> 4) ^ ((ra ^ (ra >> 2)) & 3)) << 4);
        const int rb = wc * 64 + mi * 16 + (lane & 15);
        boff[mi] = rb * 64 + (((lane >> 4) ^ ((rb ^ (rb >> 2)) & 3)) << 4);
    }

    f32x4 acc[4][4] = {};

    const int nk = K3 / 32;
#pragma unroll
    for (int i = 0; i < 2; ++i) {
        gload16(&Asm[0][ldsrow[i]][0], gA[i]);
        gload16(&Bsm[0][ldsrow[i]][0], gB[i]);
    }
    __syncthreads();

    int buf = 0;
    for (int kt = 0; kt < nk; ++kt) {
        if (kt + 1 < nk) {
            const int ko = (kt + 1) * 32;
#pragma unroll
            for (int i = 0; i < 2; ++i) {
                gload16(&Asm[buf ^ 1][ldsrow[i]][0], gA[i] + ko);
                gload16(&Bsm[buf ^ 1][ldsrow[i]][0], gB[i] + ko);
            }
        }
        const char* ab = (const char*)&Asm[buf][0][0];
        const char* bb = (const char*)&Bsm[buf][0][0];
        bf16x8 afr[4], bfr[4];
#pragma unroll
        for (int i = 0; i < 4; ++i) {
            afr[i] = *(const bf16x8*)(ab + aoff[i]);
            bfr[i] = *(const bf16x8*)(bb + boff[i]);
        }
#pragma unroll
        for (int mi = 0; mi < 4; ++mi)
#pragma unroll
            for (int ni = 0; ni < 4; ++ni)
                acc[mi][ni] = __builtin_amdgcn_mfma_f32_16x16x32_bf16(
                    afr[mi], bfr[ni], acc[mi][ni], 0, 0, 0);
        __syncthreads();
        buf ^= 1;
    }

#pragma unroll
    for (int mi = 0; mi < 4; ++mi) {
        const int rn = bm + wr * 64 + mi * 16 + ((lane >> 4) << 2);
#pragma unroll
        for (int ni = 0; ni < 4; ++ni) {
            const int cn = bn + wc * 64 + ni * 16 + (lane & 15);
#pragma unroll
            for (int j = 0; j < 4; ++j) {
                const float v = acc[mi][ni][j];
                const int r = rn + j;
                if (MODE == 0) {
                    C0[(size_t)r * Nreal + cn] = v;
                } else {
                    if (cn < D_SSM)                 C0[(size_t)r * D_SSM + cn] = v;
                    else if (cn < D_SSM + CONV_DIM) C1[(size_t)r * CONV_DIM + (cn - D_SSM)] = v;
                    else if (cn < D_IN_PROJ)        C2[(size_t)r * NHEADS + (cn - D_SSM - CONV_DIM)] = v;
                }
            }
        }
    }
}

// ---------------------------------------------------------------------------
// fp32 GEMM kernels (fallback path only)
// ---------------------------------------------------------------------------
template<int BM, int BN, int BK>
__global__ __launch_bounds__(256) void gemm_nt(
    const float* __restrict__ A, const float* __restrict__ B,
    float* __restrict__ C, int M, int N, int K)
{
    __shared__ float As[BK][BM];
    __shared__ float Bs[BK][BN];
    const int tid = threadIdx.x;
    const int bm  = blockIdx.y * BM;
    const int bn  = blockIdx.x * BN;
    const int tm  = (tid & 15) << 2;
    const int tn  = (tid >> 4) << 2;
    const int am  = tid & 63;
    const int ak  = (tid >> 6) << 2;
    float acc[4][4] = {};
    for (int k0 = 0; k0 < K; k0 += BK) {
        const float4 av = *(const float4*)(A + (size_t)(bm + am) * K + (k0 + ak));
        float4 bv = make_float4(0.f, 0.f, 0.f, 0.f);
        if (bn + am < N)
            bv = *(const float4*)(B + (size_t)(bn + am) * K + (k0 + ak));
        __syncthreads();
        As[ak + 0][am] = av.x; As[ak + 1][am] = av.y;
        As[ak + 2][am] = av.z; As[ak + 3][am] = av.w;
        Bs[ak + 0][am] = bv.x; Bs[ak + 1][am] = bv.y;
        Bs[ak + 2][am] = bv.z; Bs[ak + 3][am] = bv.w;
        __syncthreads();
#pragma unroll
        for (int kk = 0; kk < BK; ++kk) {
            const float4 a4 = *(const float4*)&As[kk][tm];
            const float4 b4 = *(const float4*)&Bs[kk][tn];
            const float a[4]  = {a4.x, a4.y, a4.z, a4.w};
            const float bb[4] = {b4.x, b4.y, b4.z, b4.w};
#pragma unroll
            for (int i = 0; i < 4; ++i)
#pragma unroll
                for (int j = 0; j < 4; ++j)
                    acc[i][j] = fmaf(a[i], bb[j], acc[i][j]);
        }
    }
#pragma unroll
    for (int i = 0; i < 4; ++i)
#pragma unroll
        for (int j = 0; j < 4; ++j) {
            const int cn = bn + tn + j;
            if (cn < N)
                C[(size_t)(bm + tm + i) * N + cn] = acc[i][j];
        }
}

__global__ __launch_bounds__(256) void gemm_inproj(
    const float* __restrict__ A, const float* __restrict__ B,
    float* __restrict__ zbuf, float* __restrict__ xbc, float* __restrict__ dtraw)
{
    constexpr int BM = 64, BN = 64, BK = 16;
    __shared__ float As[BK][BM];
    __shared__ float Bs[BK][BN];
    const int tid = threadIdx.x;
    const int bm  = blockIdx.y * BM;
    const int bn  = blockIdx.x * BN;
    const int tm  = (tid & 15) << 2;
    const int tn  = (tid >> 4) << 2;
    const int am  = tid & 63;
    const int ak  = (tid >> 6) << 2;
    float acc[4][4] = {};
    for (int k0 = 0; k0 < D_MODEL; k0 += BK) {
        const float4 av = *(const float4*)(A + (size_t)(bm + am) * D_MODEL + (k0 + ak));
        float4 bv = make_float4(0.f, 0.f, 0.f, 0.f);
        if (bn + am < D_IN_PROJ)
            bv = *(const float4*)(B + (size_t)(bn + am) * D_MODEL + (k0 + ak));
        __syncthreads();
        As[ak + 0][am] = av.x; As[ak + 1][am] = av.y;
        As[ak + 2][am] = av.z; As[ak + 3][am] = av.w;
        Bs[ak + 0][am] = bv.x; Bs[ak + 1][am] = bv.y;
        Bs[ak + 2][am] = bv.z; Bs[ak + 3][am] = bv.w;
        __syncthreads();
#pragma unroll
        for (int kk = 0; kk < BK; ++kk) {
            const float4 a4 = *(const float4*)&As[kk][tm];
            const float4 b4 = *(const float4*)&Bs[kk][tn];
            const float a[4]  = {a4.x, a4.y, a4.z, a4.w};
            const float bb[4] = {b4.x, b4.y, b4.z, b4.w};
#pragma unroll
            for (int i = 0; i < 4; ++i)
#pragma unroll
                for (int j = 0; j < 4; ++j)
                    acc[i][j] = fmaf(a[i], bb[j], acc[i][j]);
        }
    }
    float* Cp; int ldc, cb, nlim = BN;
    if (bn < D_SSM)                  { Cp = zbuf;  ldc = D_SSM;    cb = bn; }
    else if (bn < D_SSM + CONV_DIM)  { Cp = xbc;   ldc = CONV_DIM; cb = bn - D_SSM; }
    else { Cp = dtraw; ldc = NHEADS; cb = bn - (D_SSM + CONV_DIM); nlim = NHEADS; }
#pragma unroll
    for (int i = 0; i < 4; ++i)
#pragma unroll
        for (int j = 0; j < 4; ++j)
            if (tn + j < nlim)
                Cp[(size_t)(bm + tm + i) * ldc + cb + tn + j] = acc[i][j];
}

// ---------------------------------------------------------------------------
// Depthwise causal conv (width 4) + bias + SiLU.
// ---------------------------------------------------------------------------
__global__ __launch_bounds__(256) void conv_silu_kernel(
    const float* __restrict__ xbc, const float* __restrict__ cw,
    const float* __restrict__ cb, float* __restrict__ xc)
{
    const int idx = blockIdx.x * 256 + threadIdx.x;
    if (idx >= NROWS * (CONV_DIM / 4)) return;
    const int row = idx / (CONV_DIM / 4);
    const int c   = (idx % (CONV_DIM / 4)) * 4;
    const int l   = row & (SEQLEN - 1);

    const float* base = xbc + (size_t)row * CONV_DIM + c;
    const float4 cbv = *(const float4*)(cb + c);
    float acc[4] = {cbv.x, cbv.y, cbv.z, cbv.w};
    const float* w = cw + (size_t)c * D_CONV;
#pragma unroll
    for (int k = 0; k < D_CONV; ++k) {
        const int ls = l + k - 3;
        if (ls >= 0) {
            const float4 xv = *(const float4*)(base + (ptrdiff_t)(k - 3) * CONV_DIM);
            acc[0] = fmaf(w[0 * D_CONV + k], xv.x, acc[0]);
            acc[1] = fmaf(w[1 * D_CONV + k], xv.y, acc[1]);
            acc[2] = fmaf(w[2 * D_CONV + k], xv.z, acc[2]);
            acc[3] = fmaf(w[3 * D_CONV + k], xv.w, acc[3]);
        }
    }
    float4 o;
    o.x = acc[0] * sigmoidf_(acc[0]);
    o.y = acc[1] * sigmoidf_(acc[1]);
    o.z = acc[2] * sigmoidf_(acc[2]);
    o.w = acc[3] * sigmoidf_(acc[3]);
    *(float4*)(xc + (size_t)row * CONV_DIM + c) = o;
}

// ---------------------------------------------------------------------------
// dt = softplus(dt_raw + dt_bias)
// ---------------------------------------------------------------------------
__global__ __launch_bounds__(64) void dt_kernel(
    const float* __restrict__ dtraw, const float* __restrict__ dt_bias,
    float* __restrict__ dtw)
{
    const int row = blockIdx.x;
    const int tid = threadIdx.x;
    if (tid < NHEADS) {
        const float x = dtraw[(size_t)row * NHEADS + tid] + dt_bias[tid];
        const float sp = fmaxf(x, 0.f) + log1pf(__expf(-fabsf(x)));
        dtw[(size_t)row * NHEADS + tid] = sp;
    }
}

// ---------------------------------------------------------------------------
// Pass A: chunk-local cumsum of a=A*dt (-> cumws) and local end-state.
// ---------------------------------------------------------------------------
__global__ __launch_bounds__(256) void chunk_state_kernel(
    const float* __restrict__ xc, const float* __restrict__ dtw,
    const float* __restrict__ A_log,
    float* __restrict__ Sbuf, float* __restrict__ cumws)
{
    const int c  = blockIdx.x / NBH;
    const int bh = blockIdx.x % NBH;
    const int b  = bh / NHEADS, h = bh % NHEADS;
    const int tid = threadIdx.x;
    const int rowbase = b * SEQLEN + c * CHUNK;

    __shared__ float cums[CHUNK];
    __shared__ float wls[CHUNK];
    __shared__ float Xw[CHUNK][HEADDIM];
    __shared__ float Bsh[CHUNK][D_STATE];

    const float Aneg = -__expf(A_log[h]);

    float dtv = 0.f;
    if (tid < CHUNK) dtv = dtw[(size_t)(rowbase + tid) * NHEADS + h];
    float v = Aneg * dtv;
#pragma unroll
    for (int d = 1; d < 64; d <<= 1) {
        const float o = __shfl_up(v, d);
        if ((tid & 63) >= d) v += o;
    }
    if (tid < CHUNK) {
        cums[tid] = v;
        cumws[(size_t)bh * SEQLEN + c * CHUNK + tid] = v;
    }
    __syncthreads();
    const float clast = cums[CHUNK - 1];
    if (tid < CHUNK) wls[tid] = __expf(clast - v) * dtv;
    __syncthreads();

    {
        const int p0 = (tid & 15) * 4, s0 = tid >> 4;
        for (int s = s0; s < CHUNK; s += 16) {
            const float4 xv = *(const float4*)(xc + (size_t)(rowbase + s) * CONV_DIM + h * HEADDIM + p0);
            const float w = wls[s];
            *(float4*)&Xw[s][p0] = make_float4(xv.x * w, xv.y * w, xv.z * w, xv.w * w);
        }
        const int n0 = (tid & 31) * 4, s1 = tid >> 5;
        for (int s = s1; s < CHUNK; s += 8)
            *(float4*)&Bsh[s][n0] = *(const float4*)(xc + (size_t)(rowbase + s) * CONV_DIM + D_SSM + n0);
    }
    __syncthreads();

    const int tp = (tid & 15) * 4;
    const int tn = (tid >> 4) * 8;
    float acc[4][8] = {};
    for (int s = 0; s < CHUNK; ++s) {
        const float4 xa = *(const float4*)&Xw[s][tp];
        const float4 b0 = *(const float4*)&Bsh[s][tn];
        const float4 b1 = *(const float4*)&Bsh[s][tn + 4];
        const float xr[4] = {xa.x, xa.y, xa.z, xa.w};
        const float br[8] = {b0.x, b0.y, b0.z, b0.w, b1.x, b1.y, b1.z, b1.w};
#pragma unroll
        for (int i = 0; i < 4; ++i)
#pragma unroll
            for (int j = 0; j < 8; ++j)
                acc[i][j] = fmaf(xr[i], br[j], acc[i][j]);
    }
    float* Sp = Sbuf + (size_t)(bh * NC + c) * HSTATE;
#pragma unroll
    for (int i = 0; i < 4; ++i) {
        *(float4*)(Sp + (size_t)(tp + i) * D_STATE + tn)     = make_float4(acc[i][0], acc[i][1], acc[i][2], acc[i][3]);
        *(float4*)(Sp + (size_t)(tp + i) * D_STATE + tn + 4) = make_float4(acc[i][4], acc[i][5], acc[i][6], acc[i][7]);
    }
}

// ---------------------------------------------------------------------------
// Pass B: per-element scan over chunks, in-place S -> H_in.
// ---------------------------------------------------------------------------
__global__ __launch_bounds__(256) void state_scan_kernel(
    const float* __restrict__ cumws, float* __restrict__ Sbuf)
{
    const int bh = blockIdx.x;
    const int e  = blockIdx.y * 256 + threadIdx.x;
    float* base = Sbuf + (size_t)bh * NC * HSTATE + e;
    const float* cw = cumws + (size_t)bh * SEQLEN;
    float H = 0.f;
    for (int c = 0; c < NC; ++c) {
        const float P = __expf(cw[c * CHUNK + CHUNK - 1]);
        const float s = base[(size_t)c * HSTATE];
        base[(size_t)c * HSTATE] = H;
        H = fmaf(P, H, s);
    }
}

// ---------------------------------------------------------------------------
// Pass C (t-split): block = (bh, c, half). Computes 32 output rows
// t in [half*32, half*32+32); s range [0, ns), ns = half*32+32.
// LDS ~73 KB -> 2 blocks/CU. B^T/H^T time-share one buffer.
// D*x folded into M diagonal.
// ---------------------------------------------------------------------------
__global__ __launch_bounds__(256) void chunk_output_kernel(
    const float* __restrict__ xc, const float* __restrict__ dtw,
    const float* __restrict__ Dp,
    const float* __restrict__ Hbuf, const float* __restrict__ cumws,
    float* __restrict__ y)
{
    const int half = blockIdx.x & 1;
    const int rest = blockIdx.x >> 1;
    const int c  = rest / NBH;
    const int bh = rest % NBH;
    const int b  = bh / NHEADS, h = bh % NHEADS;
    const int tid = threadIdx.x;
    const int rowbase = b * SEQLEN + c * CHUNK;
    const int tbase = half * 32;
    const int ns = tbase + 32;

    __shared__ float cums[CHUNK], dts[CHUNK], Es32[32];
    __shared__ float CsT[D_STATE][32];      // [n][t-local]
    __shared__ float BHs[D_STATE][64];      // B^T (P1) then H^T (P3)
    __shared__ float Xs[CHUNK][HEADDIM];    // [s][p], rows < ns used
    __shared__ float Ms[32][CHUNK + 1];     // [t-local][s]

    // ---- P0: stage cums/dts (s range), Es32 (t range), CsT, BsT
    if (tid < ns) {
        cums[tid] = cumws[(size_t)bh * SEQLEN + c * CHUNK + tid];
        dts[tid]  = dtw[(size_t)(rowbase + tid) * NHEADS + h];
    }
    if (tid < 32)
        Es32[tid] = __expf(cumws[(size_t)bh * SEQLEN + c * CHUNK + tbase + tid]);

    {
        const int t  = tid & 31;
        const int nq = (tid >> 5) * 4;     // 8 groups, stride 32
        const float* rowp = xc + (size_t)(rowbase + tbase + t) * CONV_DIM + D_SSM + D_STATE;
        for (int n = nq; n < D_STATE; n += 32) {
            const float4 cv = *(const float4*)(rowp + n);
            CsT[n + 0][t] = cv.x; CsT[n + 1][t] = cv.y;
            CsT[n + 2][t] = cv.z; CsT[n + 3][t] = cv.w;
        }
        if (half == 0) {
            const int s = tid & 31;
            const float* rowb = xc + (size_t)(rowbase + s) * CONV_DIM + D_SSM;
            for (int n = nq; n < D_STATE; n += 32) {
                const float4 bv = *(const float4*)(rowb + n);
                BHs[n + 0][s] = bv.x; BHs[n + 1][s] = bv.y;
                BHs[n + 2][s] = bv.z; BHs[n + 3][s] = bv.w;
            }
        } else {
            const int s   = tid & 63;
            const int nq2 = (tid >> 6) * 4;  // 4 groups, stride 16
            const float* rowb = xc + (size_t)(rowbase + s) * CONV_DIM + D_SSM;
            for (int n = nq2; n < D_STATE; n += 16) {
                const float4 bv = *(const float4*)(rowb + n);
                BHs[n + 0][s] = bv.x; BHs[n + 1][s] = bv.y;
                BHs[n + 2][s] = bv.z; BHs[n + 3][s] = bv.w;
            }
        }
    }
    __syncthreads();

    // ---- P1: G = C@B^T  (mapping A: 4 t-rows x 2 s-cols per lane)
    const int tmA = (tid & 7) * 4;
    const int tnA = (tid >> 3) * 2;
    float g[4][2] = {};
    for (int n = 0; n < D_STATE; ++n) {
        const float4 ca = *(const float4*)&CsT[n][tmA];
        const float2 bb = *(const float2*)&BHs[n][tnA];
        g[0][0] = fmaf(ca.x, bb.x, g[0][0]); g[0][1] = fmaf(ca.x, bb.y, g[0][1]);
        g[1][0] = fmaf(ca.y, bb.x, g[1][0]); g[1][1] = fmaf(ca.y, bb.y, g[1][1]);
        g[2][0] = fmaf(ca.z, bb.x, g[2][0]); g[2][1] = fmaf(ca.z, bb.y, g[2][1]);
        g[3][0] = fmaf(ca.w, bb.x, g[3][0]); g[3][1] = fmaf(ca.w, bb.y, g[3][1]);
    }
    __syncthreads();   // G reads of BHs and raw CsT done

    // ---- P2: write Ms (+D on diagonal), rescale CsT, stage H^T, stage Xs
    const float Dh = Dp[h];
#pragma unroll
    for (int i = 0; i < 4; ++i) {
        const int tl = tmA + i;
        const int tg = tbase + tl;
        float2 mv;
        float* mp = (float*)&mv;
#pragma unroll
        for (int j = 0; j < 2; ++j) {
            const int s = tnA + j;
            float m = 0.f;
            if (s <= tg) {
                m = g[i][j] * __expf(cums[tg] - cums[s]) * dts[s];
                if (s == tg) m += Dh;
            }
            mp[j] = m;
        }
        *(float2*)&Ms[tl][tnA] = mv;
    }
    for (int e = tid; e < D_STATE * 32; e += 256) {
        const int n = e >> 5, t = e & 31;
        CsT[n][t] *= Es32[t];
    }
    {
        const int p  = tid & 63;
        const int nq = (tid >> 6) * 4;
        const float* Hp = Hbuf + (size_t)(bh * NC + c) * HSTATE + (size_t)p * D_STATE;
        for (int n = nq; n < D_STATE; n += 16) {
            const float4 hv = *(const float4*)(Hp + n);
            BHs[n + 0][p] = hv.x; BHs[n + 1][p] = hv.y;
            BHs[n + 2][p] = hv.z; BHs[n + 3][p] = hv.w;
        }
        const int p0 = (tid & 15) * 4;
        for (int s = tid >> 4; s < ns; s += 16)
            *(float4*)&Xs[s][p0] =
                *(const float4*)(xc + (size_t)(rowbase + s) * CONV_DIM + h * HEADDIM + p0);
    }
    __syncthreads();

    // ---- P3: y = Ms@Xs + Ĉ@H^T  (mapping B: 2 t-rows x 4 p-cols per lane)
    const int p0   = (tid & 15) * 4;
    const int trow = (tid >> 4) * 2;
    float acc[2][4] = {};
    for (int s = 0; s < ns; ++s) {
        const float m0 = Ms[trow][s], m1 = Ms[trow + 1][s];
        const float4 xv = *(const float4*)&Xs[s][p0];
        acc[0][0] = fmaf(m0, xv.x, acc[0][0]); acc[0][1] = fmaf(m0, xv.y, acc[0][1]);
        acc[0][2] = fmaf(m0, xv.z, acc[0][2]); acc[0][3] = fmaf(m0, xv.w, acc[0][3]);
        acc[1][0] = fmaf(m1, xv.x, acc[1][0]); acc[1][1] = fmaf(m1, xv.y, acc[1][1]);
        acc[1][2] = fmaf(m1, xv.z, acc[1][2]); acc[1][3] = fmaf(m1, xv.w, acc[1][3]);
    }
    for (int n = 0; n < D_STATE; ++n) {
        const float2 cv = *(const float2*)&CsT[n][trow];
        const float4 hv = *(const float4*)&BHs[n][p0];
        acc[0][0] = fmaf(cv.x, hv.x, acc[0][0]); acc[0][1] = fmaf(cv.x, hv.y, acc[0][1]);
        acc[0][2] = fmaf(cv.x, hv.z, acc[0][2]); acc[0][3] = fmaf(cv.x, hv.w, acc[0][3]);
        acc[1][0] = fmaf(cv.y, hv.x, acc[1][0]); acc[1][1] = fmaf(cv.y, hv.y, acc[1][1]);
        acc[1][2] = fmaf(cv.y, hv.z, acc[1][2]); acc[1][3] = fmaf(cv.y, hv.w, acc[1][3]);
    }
#pragma unroll
    for (int i = 0; i < 2; ++i) {
        const float4 ov = make_float4(acc[i][0], acc[i][1], acc[i][2], acc[i][3]);
        *(float4*)(y + (size_t)(rowbase + tbase + trow + i) * D_SSM + h * HEADDIM + p0) = ov;
    }
}

// ---------------------------------------------------------------------------
// Fallback sequential scan.
// ---------------------------------------------------------------------------
__global__ __launch_bounds__(256) void scan_kernel(
    const float* __restrict__ xc, const float* __restrict__ dtw,
    const float* __restrict__ A_log, const float* __restrict__ Dp,
    float* __restrict__ y)
{
    const int b   = blockIdx.x / NHEADS;
    const int h   = blockIdx.x % NHEADS;
    const int tid = threadIdx.x;
    const int p   = tid >> 2;
    const int q   = tid & 3;

    __shared__ float dt_s[SEQLEN];
    __shared__ float Bs[4][36];
    __shared__ float Cs[4][36];
    __shared__ float xs[64];

    for (int i = tid; i < SEQLEN; i += 256)
        dt_s[i] = dtw[((size_t)b * SEQLEN + i) * NHEADS + h];

    const float Aneg = -__expf(A_log[h]);
    const float Dh   = Dp[h];

    float hst[32];
#pragma unroll
    for (int i = 0; i < 32; ++i) hst[i] = 0.f;

    const float* row0 = xc + (size_t)b * SEQLEN * CONV_DIM;
    float rBC = row0[D_SSM + tid];
    float rx  = (tid < 64) ? row0[h * HEADDIM + tid] : 0.f;

    for (int t = 0; t < SEQLEN; ++t) {
        __syncthreads();
        if (tid < 128) Bs[tid >> 5][tid & 31] = rBC;
        else           Cs[(tid >> 5) & 3][tid & 31] = rBC;
        if (tid < 64)  xs[tid] = rx;
        if (t + 1 < SEQLEN) {
            const float* rp = row0 + (size_t)(t + 1) * CONV_DIM;
            rBC = rp[D_SSM + tid];
            if (tid < 64) rx = rp[h * HEADDIM + tid];
        }
        __syncthreads();

        const float dtv = dt_s[t];
        const float dA  = __expf(dtv * Aneg);
        const float dtx = dtv * xs[p];
        float ysum = 0.f;
#pragma unroll
        for (int j4 = 0; j4 < 8; ++j4) {
            const float4 Bv = *(const float4*)&Bs[q][j4 * 4];
            const float4 Cv = *(const float4*)&Cs[q][j4 * 4];
            float* hp = &hst[j4 * 4];
            hp[0] = fmaf(hp[0], dA, dtx * Bv.x); ysum = fmaf(hp[0], Cv.x, ysum);
            hp[1] = fmaf(hp[1], dA, dtx * Bv.y); ysum = fmaf(hp[1], Cv.y, ysum);
            hp[2] = fmaf(hp[2], dA, dtx * Bv.z); ysum = fmaf(hp[2], Cv.z, ysum);
            hp[3] = fmaf(hp[3], dA, dtx * Bv.w); ysum = fmaf(hp[3], Cv.w, ysum);
        }
        ysum += __shfl_xor(ysum, 1);
        ysum += __shfl_xor(ysum, 2);
        if (q == 0)
            y[((size_t)b * SEQLEN + t) * D_SSM + h * HEADDIM + p] = ysum + Dh * xs[p];
    }
}

// ---------------------------------------------------------------------------
// Gate + RMSNorm -> bf16x3 rows (A-pattern [hi|hi|lo]).
// ---------------------------------------------------------------------------
__global__ __launch_bounds__(256) void gatenorm_x3_kernel(
    const float* __restrict__ y, const float* __restrict__ zbuf,
    const float* __restrict__ norm_w, __hip_bfloat16* __restrict__ ybx3)
{
    const int row = blockIdx.x;
    const int tid = threadIdx.x;
    const float* yr = y + (size_t)row * D_SSM;
    const float* zr = zbuf + (size_t)row * D_SSM;

    float v[6];
    float ss = 0.f;
#pragma unroll
    for (int i = 0; i < 6; ++i) {
        const int e = tid + i * 256;
        const float yv = yr[e];
        const float zv = zr[e];
        const float g  = yv * (zv * sigmoidf_(zv));
        v[i] = g;
        ss = fmaf(g, g, ss);
    }
#pragma unroll
    for (int m = 1; m < 64; m <<= 1) ss += __shfl_xor(ss, m);
    __shared__ float ws[4];
    if ((tid & 63) == 0) ws[tid >> 6] = ss;
    __syncthreads();
    const float tot = ws[0] + ws[1] + ws[2] + ws[3];
    const float r = rsqrtf(tot * (1.0f / D_SSM) + EPS);
    __hip_bfloat16* orow = ybx3 + (size_t)row * K3_OUT;
#pragma unroll
    for (int i = 0; i < 6; ++i) {
        const int e = tid + i * 256;
        const float g = v[i] * r * norm_w[e];
        const __hip_bfloat16 hi = __float2bfloat16(g);
        const __hip_bfloat16 lo = __float2bfloat16(g - __bfloat162float(hi));
        orow[e] = hi;
        orow[D_SSM + e] = hi;
        orow[2 * D_SSM + e] = lo;
    }
}

// ---------------------------------------------------------------------------
// Gate + RMSNorm in place (fallback path).
// ---------------------------------------------------------------------------
__global__ __launch_bounds__(256) void gatenorm_kernel(
    float* y, const float* __restrict__ zbuf, const float* __restrict__ norm_w)
{
    const int row = blockIdx.x;
    const int tid = threadIdx.x;
    float* yr = y + (size_t)row * D_SSM;
    const float* zr = zbuf + (size_t)row * D_SSM;

    float v[6];
    float ss = 0.f;
#pragma unroll
    for (int i = 0; i < 6; ++i) {
        const int e = tid + i * 256;
        const float yv = yr[e];
        const float zv = zr[e];
        const float g  = yv * (zv * sigmoidf_(zv));
        v[i] = g;
        ss = fmaf(g, g, ss);
    }
#pragma unroll
    for (int m = 1; m < 64; m <<= 1) ss += __shfl_xor(ss, m);
    __shared__ float ws[4];
    if ((tid & 63) == 0) ws[tid >> 6] = ss;
    __syncthreads();
    const float tot = ws[0] + ws[1] + ws[2] + ws[3];
    const float r = rsqrtf(tot * (1.0f / D_SSM) + EPS);
#pragma unroll
    for (int i = 0; i < 6; ++i) {
        const int e = tid + i * 256;
        yr[e] = v[i] * r * norm_w[e];
    }
}

// ---------------------------------------------------------------------------
extern "C" void kernel_launch(void* const* d_in, const int* in_sizes, int n_in,
                              void* d_out, int out_size, void* d_ws, size_t ws_size,
                              hipStream_t stream)
{
    const float* u       = (const float*)d_in[0];
    const float* W_in    = (const float*)d_in[1];
    const float* conv_w  = (const float*)d_in[2];
    const float* conv_b  = (const float*)d_in[3];
    const float* dt_bias = (const float*)d_in[4];
    const float* A_log   = (const float*)d_in[5];
    const float* Dp      = (const float*)d_in[6];
    const float* norm_w  = (const float*)d_in[7];
    const float* W_out   = (const float*)d_in[8];
    float* out = (float*)d_out;

    const size_t SZ_Z   = (size_t)NROWS * D_SSM;
    const size_t SZ_XBC = (size_t)NROWS * CONV_DIM;
    const size_t SZ_DT  = (size_t)NROWS * NHEADS;
    const size_t SZ_S   = (size_t)NBH * NC * HSTATE;
    const size_t SZ_CUM = (size_t)NBH * SEQLEN;

    const size_t need_new = (SZ_Z + SZ_S + SZ_Z + SZ_XBC + SZ_DT + SZ_CUM) * sizeof(float);
    const bool use_new = ws_size >= need_new;

    if (use_new) {
        float* zbuf = (float*)d_ws;
        float* Breg = zbuf + SZ_Z;
        float* Creg = Breg + SZ_S;
        float* Xreg = Creg + SZ_Z;
        float* dtw   = Xreg + SZ_XBC;
        float* cumws = dtw + SZ_DT;

        float* xbc   = Breg;
        float* dtraw = Breg + SZ_XBC;
        float* Sbuf  = Breg;
        __hip_bfloat16* ybx3 = (__hip_bfloat16*)Breg;
        __hip_bfloat16* u3   = (__hip_bfloat16*)Creg;
        float* yb    = Creg;
        __hip_bfloat16* W_in3  = (__hip_bfloat16*)Xreg;
        float* xc    = Xreg;
        __hip_bfloat16* W_out3 = (__hip_bfloat16*)Xreg;

        decompose3<1><<<(NROWS * (D_MODEL / 4) + 255) / 256, 256, 0, stream>>>(
            u, u3, NROWS, NROWS, D_MODEL);
        decompose3<0><<<(NPAD_IN * (D_MODEL / 4) + 255) / 256, 256, 0, stream>>>(
            W_in, W_in3, D_IN_PROJ, NPAD_IN, D_MODEL);

        gemm_bf16x3<1><<<dim3(NPAD_IN / 128, NROWS / 128), 256, 0, stream>>>(
            u3, W_in3, zbuf, xbc, dtraw, 0, K3_IN);

        conv_silu_kernel<<<(NROWS * (CONV_DIM / 4) + 255) / 256, 256, 0, stream>>>(
            xbc, conv_w, conv_b, xc);

        dt_kernel<<<NROWS, 64, 0, stream>>>(dtraw, dt_bias, dtw);

        chunk_state_kernel<<<NBH * NC, 256, 0, stream>>>(xc, dtw, A_log, Sbuf, cumws);
        state_scan_kernel<<<dim3(NBH, HSTATE / 256), 256, 0, stream>>>(cumws, Sbuf);
        chunk_output_kernel<<<NBH * NC * 2, 256, 0, stream>>>(xc, dtw, Dp, Sbuf, cumws, yb);

        decompose3<0><<<(D_MODEL * (D_SSM / 4) + 255) / 256, 256, 0, stream>>>(
            W_out, W_out3, D_MODEL, D_MODEL, D_SSM);

        gatenorm_x3_kernel<<<NROWS, 256, 0, stream>>>(yb, zbuf, norm_w, ybx3);

        gemm_bf16x3<0><<<dim3(D_MODEL / 128, NROWS / 128), 256, 0, stream>>>(
            ybx3, W_out3, out, nullptr, nullptr, D_MODEL, K3_OUT);
    } else {
        float* zbuf  = (float*)d_ws;
        float* Rp    = zbuf + SZ_Z;
        float* xbc   = Rp;
        float* yb    = Rp;
        float* dtraw = Rp + SZ_XBC;
        float* xc    = dtraw + SZ_DT;
        float* dtw   = xc + SZ_XBC;

        gemm_inproj<<<dim3((D_IN_PROJ + 63) / 64, NROWS / 64), 256, 0, stream>>>(
            u, W_in, zbuf, xbc, dtraw);
        conv_silu_kernel<<<(NROWS * (CONV_DIM / 4) + 255) / 256, 256, 0, stream>>>(
            xbc, conv_w, conv_b, xc);
        dt_kernel<<<NROWS, 64, 0, stream>>>(dtraw, dt_bias, dtw);
        scan_kernel<<<NBH, 256, 0, stream>>>(xc, dtw, A_log, Dp, yb);
        gatenorm_kernel<<<NROWS, 256, 0, stream>>>(yb, zbuf, norm_w);
        gemm_nt<64, 64, 16><<<dim3(D_MODEL / 64, NROWS / 64), 256, 0, stream>>>(
            yb, W_out, out, NROWS, D_MODEL, D_SSM);
    }
}

// Round 7
// 727.285 us; speedup vs baseline: 3.6383x; 1.1574x over previous
//
#include <hip/hip_runtime.h>
#include <hip/hip_bf16.h>
#include <math.h>

#define D_MODEL   768
#define D_SSM     1536
#define D_STATE   128
#define D_CONV    4
#define HEADDIM   64
#define NHEADS    24
#define CONV_DIM  1792          // D_SSM + 2*D_STATE
#define D_IN_PROJ 3352          // 2*D_SSM + 2*D_STATE + NHEADS
#define BATCH     4
#define SEQLEN    2048
#define NROWS     (BATCH * SEQLEN)   // 8192
#define EPS       1e-5f

#define CHUNK     64
#define NC        (SEQLEN / CHUNK)    // 32
#define NBH       (BATCH * NHEADS)    // 96
#define HSTATE    (HEADDIM * D_STATE) // 8192

#define K3_IN     (3 * D_MODEL)       // 2304
#define K3_OUT    (3 * D_SSM)         // 4608
#define NPAD_IN   3456                // 27 * 128 (>= D_IN_PROJ)

typedef __attribute__((ext_vector_type(8))) short bf16x8;
typedef __attribute__((ext_vector_type(4))) float f32x4;

__device__ __forceinline__ float sigmoidf_(float x) {
    return 1.0f / (1.0f + __expf(-x));
}

__device__ __forceinline__ void gload16(void* lds, const void* g) {
    __builtin_amdgcn_global_load_lds(
        (const __attribute__((address_space(1))) unsigned int*)g,
        (__attribute__((address_space(3))) unsigned int*)lds, 16, 0, 0);
}

// cvt 8 fp32 -> bf16 hi/lo planes, one b128 write each
__device__ __forceinline__ void cvt_wr8(__hip_bfloat16* hb, __hip_bfloat16* lb,
                                        int off, float4 a, float4 b)
{
    union { __hip_bfloat16 h[8]; uint4 u; } hi, lo;
    const float f[8] = {a.x, a.y, a.z, a.w, b.x, b.y, b.z, b.w};
#pragma unroll
    for (int j = 0; j < 8; ++j) {
        const __hip_bfloat16 h = __float2bfloat16(f[j]);
        hi.h[j] = h;
        lo.h[j] = __float2bfloat16(f[j] - __bfloat162float(h));
    }
    *(uint4*)((char*)hb + off) = hi.u;
    *(uint4*)((char*)lb + off) = lo.u;
}

// ---------------------------------------------------------------------------
// Decompose fp32 [R][K] -> bf16 [Rpad][3K].
// APAT=1 (A-side): [hi | hi | lo]   APAT=0 (B-side): [hi | lo | hi]
// ---------------------------------------------------------------------------
template<int APAT>
__global__ __launch_bounds__(256) void decompose3(
    const float* __restrict__ X, __hip_bfloat16* __restrict__ X3,
    int R, int Rpad, int K)
{
    const int idx = blockIdx.x * 256 + threadIdx.x;
    if (idx >= Rpad * (K / 4)) return;
    const int r = idx / (K / 4);
    const int k = (idx % (K / 4)) * 4;

    union { __hip_bfloat16 h[4]; uint2 u; } phi, plo;
    if (r < R) {
        const float4 x = *(const float4*)(X + (size_t)r * K + k);
        const float xs[4] = {x.x, x.y, x.z, x.w};
#pragma unroll
        for (int j = 0; j < 4; ++j) {
            phi.h[j] = __float2bfloat16(xs[j]);
            plo.h[j] = __float2bfloat16(xs[j] - __bfloat162float(phi.h[j]));
        }
    } else {
#pragma unroll
        for (int j = 0; j < 4; ++j) { phi.h[j] = __float2bfloat16(0.f); plo.h[j] = phi.h[j]; }
    }
    __hip_bfloat16* row = X3 + (size_t)r * (3 * K);
    *(uint2*)(row + k)         = phi.u;
    *(uint2*)(row + K + k)     = APAT ? phi.u : plo.u;
    *(uint2*)(row + 2 * K + k) = APAT ? plo.u : phi.u;
}

// ---------------------------------------------------------------------------
// MFMA GEMM (NT): C[M,N] = A''[M,K3] * B''[N,K3]^T, bf16 in / fp32 out.
// 128x128 tile, 4 waves, 16x16x32 MFMA, BK=32, gload_lds dbuf.
// ---------------------------------------------------------------------------
template<int MODE>
__global__ __launch_bounds__(256) void gemm_bf16x3(
    const __hip_bfloat16* __restrict__ Ab, const __hip_bfloat16* __restrict__ Bb,
    float* __restrict__ C0, float* __restrict__ C1, float* __restrict__ C2,
    int Nreal, int K3)
{
    __shared__ __hip_bfloat16 Asm[2][128][32];
    __shared__ __hip_bfloat16 Bsm[2][128][32];
    const int tid  = threadIdx.x;
    const int lane = tid & 63;
    const int w    = tid >> 6;
    const int wr   = w >> 1, wc = w & 1;
    const int bm   = blockIdx.y * 128;
    const int bn   = blockIdx.x * 128;

    const __hip_bfloat16* gA[2];
    const __hip_bfloat16* gB[2];
    int ldsrow[2];
#pragma unroll
    for (int i = 0; i < 2; ++i) {
        const int r  = w * 32 + i * 16 + (lane >> 2);
        const int sl = (lane & 3) ^ ((r ^ (r >> 2)) & 3);
        ldsrow[i] = w * 32 + i * 16;
        gA[i] = Ab + (size_t)(bm + r) * K3 + sl * 8;
        gB[i] = Bb + (size_t)(bn + r) * K3 + sl * 8;
    }

    int aoff[4], boff[4];
#pragma unroll
    for (int mi = 0; mi < 4; ++mi) {
        const int ra = wr * 64 + mi * 16 + (lane & 15);
        aoff[mi] = ra * 64 + (((lane >> 4) ^ ((ra ^ (ra >> 2)) & 3)) << 4);
        const int rb = wc * 64 + mi * 16 + (lane & 15);
        boff[mi] = rb * 64 + (((lane >> 4) ^ ((rb ^ (rb >> 2)) & 3)) << 4);
    }

    f32x4 acc[4][4] = {};

    const int nk = K3 / 32;
#pragma unroll
    for (int i = 0; i < 2; ++i) {
        gload16(&Asm[0][ldsrow[i]][0], gA[i]);
        gload16(&Bsm[0][ldsrow[i]][0], gB[i]);
    }
    __syncthreads();

    int buf = 0;
    for (int kt = 0; kt < nk; ++kt) {
        if (kt + 1 < nk) {
            const int ko = (kt + 1) * 32;
#pragma unroll
            for (int i = 0; i < 2; ++i) {
                gload16(&Asm[buf ^ 1][ldsrow[i]][0], gA[i] + ko);
                gload16(&Bsm[buf ^ 1][ldsrow[i]][0], gB[i] + ko);
            }
        }
        const char* ab = (const char*)&Asm[buf][0][0];
        const char* bb = (const char*)&Bsm[buf][0][0];
        bf16x8 afr[4], bfr[4];
#pragma unroll
        for (int i = 0; i < 4; ++i) {
            afr[i] = *(const bf16x8*)(ab + aoff[i]);
            bfr[i] = *(const bf16x8*)(bb + boff[i]);
        }
#pragma unroll
        for (int mi = 0; mi < 4; ++mi)
#pragma unroll
            for (int ni = 0; ni < 4; ++ni)
                acc[mi][ni] = __builtin_amdgcn_mfma_f32_16x16x32_bf16(
                    afr[mi], bfr[ni], acc[mi][ni], 0, 0, 0);
        __syncthreads();
        buf ^= 1;
    }

#pragma unroll
    for (int mi = 0; mi < 4; ++mi) {
        const int rn = bm + wr * 64 + mi * 16 + ((lane >> 4) << 2);
#pragma unroll
        for (int ni = 0; ni < 4; ++ni) {
            const int cn = bn + wc * 64 + ni * 16 + (lane & 15);
#pragma unroll
            for (int j = 0; j < 4; ++j) {
                const float v = acc[mi][ni][j];
                const int r = rn + j;
                if (MODE == 0) {
                    C0[(size_t)r * Nreal + cn] = v;
                } else {
                    if (cn < D_SSM)                 C0[(size_t)r * D_SSM + cn] = v;
                    else if (cn < D_SSM + CONV_DIM) C1[(size_t)r * CONV_DIM + (cn - D_SSM)] = v;
                    else if (cn < D_IN_PROJ)        C2[(size_t)r * NHEADS + (cn - D_SSM - CONV_DIM)] = v;
                }
            }
        }
    }
}

// ---------------------------------------------------------------------------
// fp32 GEMM kernels (fallback path only)
// ---------------------------------------------------------------------------
template<int BM, int BN, int BK>
__global__ __launch_bounds__(256) void gemm_nt(
    const float* __restrict__ A, const float* __restrict__ B,
    float* __restrict__ C, int M, int N, int K)
{
    __shared__ float As[BK][BM];
    __shared__ float Bs[BK][BN];
    const int tid = threadIdx.x;
    const int bm  = blockIdx.y * BM;
    const int bn  = blockIdx.x * BN;
    const int tm  = (tid & 15) << 2;
    const int tn  = (tid >> 4) << 2;
    const int am  = tid & 63;
    const int ak  = (tid >> 6) << 2;
    float acc[4][4] = {};
    for (int k0 = 0; k0 < K; k0 += BK) {
        const float4 av = *(const float4*)(A + (size_t)(bm + am) * K + (k0 + ak));
        float4 bv = make_float4(0.f, 0.f, 0.f, 0.f);
        if (bn + am < N)
            bv = *(const float4*)(B + (size_t)(bn + am) * K + (k0 + ak));
        __syncthreads();
        As[ak + 0][am] = av.x; As[ak + 1][am] = av.y;
        As[ak + 2][am] = av.z; As[ak + 3][am] = av.w;
        Bs[ak + 0][am] = bv.x; Bs[ak + 1][am] = bv.y;
        Bs[ak + 2][am] = bv.z; Bs[ak + 3][am] = bv.w;
        __syncthreads();
#pragma unroll
        for (int kk = 0; kk < BK; ++kk) {
            const float4 a4 = *(const float4*)&As[kk][tm];
            const float4 b4 = *(const float4*)&Bs[kk][tn];
            const float a[4]  = {a4.x, a4.y, a4.z, a4.w};
            const float bb[4] = {b4.x, b4.y, b4.z, b4.w};
#pragma unroll
            for (int i = 0; i < 4; ++i)
#pragma unroll
                for (int j = 0; j < 4; ++j)
                    acc[i][j] = fmaf(a[i], bb[j], acc[i][j]);
        }
    }
#pragma unroll
    for (int i = 0; i < 4; ++i)
#pragma unroll
        for (int j = 0; j < 4; ++j) {
            const int cn = bn + tn + j;
            if (cn < N)
                C[(size_t)(bm + tm + i) * N + cn] = acc[i][j];
        }
}

__global__ __launch_bounds__(256) void gemm_inproj(
    const float* __restrict__ A, const float* __restrict__ B,
    float* __restrict__ zbuf, float* __restrict__ xbc, float* __restrict__ dtraw)
{
    constexpr int BM = 64, BN = 64, BK = 16;
    __shared__ float As[BK][BM];
    __shared__ float Bs[BK][BN];
    const int tid = threadIdx.x;
    const int bm  = blockIdx.y * BM;
    const int bn  = blockIdx.x * BN;
    const int tm  = (tid & 15) << 2;
    const int tn  = (tid >> 4) << 2;
    const int am  = tid & 63;
    const int ak  = (tid >> 6) << 2;
    float acc[4][4] = {};
    for (int k0 = 0; k0 < D_MODEL; k0 += BK) {
        const float4 av = *(const float4*)(A + (size_t)(bm + am) * D_MODEL + (k0 + ak));
        float4 bv = make_float4(0.f, 0.f, 0.f, 0.f);
        if (bn + am < D_IN_PROJ)
            bv = *(const float4*)(B + (size_t)(bn + am) * D_MODEL + (k0 + ak));
        __syncthreads();
        As[ak + 0][am] = av.x; As[ak + 1][am] = av.y;
        As[ak + 2][am] = av.z; As[ak + 3][am] = av.w;
        Bs[ak + 0][am] = bv.x; Bs[ak + 1][am] = bv.y;
        Bs[ak + 2][am] = bv.z; Bs[ak + 3][am] = bv.w;
        __syncthreads();
#pragma unroll
        for (int kk = 0; kk < BK; ++kk) {
            const float4 a4 = *(const float4*)&As[kk][tm];
            const float4 b4 = *(const float4*)&Bs[kk][tn];
            const float a[4]  = {a4.x, a4.y, a4.z, a4.w};
            const float bb[4] = {b4.x, b4.y, b4.z, b4.w};
#pragma unroll
            for (int i = 0; i < 4; ++i)
#pragma unroll
                for (int j = 0; j < 4; ++j)
                    acc[i][j] = fmaf(a[i], bb[j], acc[i][j]);
        }
    }
    float* Cp; int ldc, cb, nlim = BN;
    if (bn < D_SSM)                  { Cp = zbuf;  ldc = D_SSM;    cb = bn; }
    else if (bn < D_SSM + CONV_DIM)  { Cp = xbc;   ldc = CONV_DIM; cb = bn - D_SSM; }
    else { Cp = dtraw; ldc = NHEADS; cb = bn - (D_SSM + CONV_DIM); nlim = NHEADS; }
#pragma unroll
    for (int i = 0; i < 4; ++i)
#pragma unroll
        for (int j = 0; j < 4; ++j)
            if (tn + j < nlim)
                Cp[(size_t)(bm + tm + i) * ldc + cb + tn + j] = acc[i][j];
}

// ---------------------------------------------------------------------------
// Depthwise causal conv (width 4) + bias + SiLU.
// ---------------------------------------------------------------------------
__global__ __launch_bounds__(256) void conv_silu_kernel(
    const float* __restrict__ xbc, const float* __restrict__ cw,
    const float* __restrict__ cb, float* __restrict__ xc)
{
    const int idx = blockIdx.x * 256 + threadIdx.x;
    if (idx >= NROWS * (CONV_DIM / 4)) return;
    const int row = idx / (CONV_DIM / 4);
    const int c   = (idx % (CONV_DIM / 4)) * 4;
    const int l   = row & (SEQLEN - 1);

    const float* base = xbc + (size_t)row * CONV_DIM + c;
    const float4 cbv = *(const float4*)(cb + c);
    float acc[4] = {cbv.x, cbv.y, cbv.z, cbv.w};
    const float* w = cw + (size_t)c * D_CONV;
#pragma unroll
    for (int k = 0; k < D_CONV; ++k) {
        const int ls = l + k - 3;
        if (ls >= 0) {
            const float4 xv = *(const float4*)(base + (ptrdiff_t)(k - 3) * CONV_DIM);
            acc[0] = fmaf(w[0 * D_CONV + k], xv.x, acc[0]);
            acc[1] = fmaf(w[1 * D_CONV + k], xv.y, acc[1]);
            acc[2] = fmaf(w[2 * D_CONV + k], xv.z, acc[2]);
            acc[3] = fmaf(w[3 * D_CONV + k], xv.w, acc[3]);
        }
    }
    float4 o;
    o.x = acc[0] * sigmoidf_(acc[0]);
    o.y = acc[1] * sigmoidf_(acc[1]);
    o.z = acc[2] * sigmoidf_(acc[2]);
    o.w = acc[3] * sigmoidf_(acc[3]);
    *(float4*)(xc + (size_t)row * CONV_DIM + c) = o;
}

// ---------------------------------------------------------------------------
// dt = softplus(dt_raw + dt_bias)
// ---------------------------------------------------------------------------
__global__ __launch_bounds__(64) void dt_kernel(
    const float* __restrict__ dtraw, const float* __restrict__ dt_bias,
    float* __restrict__ dtw)
{
    const int row = blockIdx.x;
    const int tid = threadIdx.x;
    if (tid < NHEADS) {
        const float x = dtraw[(size_t)row * NHEADS + tid] + dt_bias[tid];
        const float sp = fmaxf(x, 0.f) + log1pf(__expf(-fabsf(x)));
        dtw[(size_t)row * NHEADS + tid] = sp;
    }
}

// ---------------------------------------------------------------------------
// Pass A: chunk-local cumsum of a=A*dt (-> cumws) and local end-state.
// ---------------------------------------------------------------------------
__global__ __launch_bounds__(256) void chunk_state_kernel(
    const float* __restrict__ xc, const float* __restrict__ dtw,
    const float* __restrict__ A_log,
    float* __restrict__ Sbuf, float* __restrict__ cumws)
{
    const int c  = blockIdx.x / NBH;
    const int bh = blockIdx.x % NBH;
    const int b  = bh / NHEADS, h = bh % NHEADS;
    const int tid = threadIdx.x;
    const int rowbase = b * SEQLEN + c * CHUNK;

    __shared__ float cums[CHUNK];
    __shared__ float wls[CHUNK];
    __shared__ float Xw[CHUNK][HEADDIM];
    __shared__ float Bsh[CHUNK][D_STATE];

    const float Aneg = -__expf(A_log[h]);

    float dtv = 0.f;
    if (tid < CHUNK) dtv = dtw[(size_t)(rowbase + tid) * NHEADS + h];
    float v = Aneg * dtv;
#pragma unroll
    for (int d = 1; d < 64; d <<= 1) {
        const float o = __shfl_up(v, d);
        if ((tid & 63) >= d) v += o;
    }
    if (tid < CHUNK) {
        cums[tid] = v;
        cumws[(size_t)bh * SEQLEN + c * CHUNK + tid] = v;
    }
    __syncthreads();
    const float clast = cums[CHUNK - 1];
    if (tid < CHUNK) wls[tid] = __expf(clast - v) * dtv;
    __syncthreads();

    {
        const int p0 = (tid & 15) * 4, s0 = tid >> 4;
        for (int s = s0; s < CHUNK; s += 16) {
            const float4 xv = *(const float4*)(xc + (size_t)(rowbase + s) * CONV_DIM + h * HEADDIM + p0);
            const float w = wls[s];
            *(float4*)&Xw[s][p0] = make_float4(xv.x * w, xv.y * w, xv.z * w, xv.w * w);
        }
        const int n0 = (tid & 31) * 4, s1 = tid >> 5;
        for (int s = s1; s < CHUNK; s += 8)
            *(float4*)&Bsh[s][n0] = *(const float4*)(xc + (size_t)(rowbase + s) * CONV_DIM + D_SSM + n0);
    }
    __syncthreads();

    const int tp = (tid & 15) * 4;
    const int tn = (tid >> 4) * 8;
    float acc[4][8] = {};
    for (int s = 0; s < CHUNK; ++s) {
        const float4 xa = *(const float4*)&Xw[s][tp];
        const float4 b0 = *(const float4*)&Bsh[s][tn];
        const float4 b1 = *(const float4*)&Bsh[s][tn + 4];
        const float xr[4] = {xa.x, xa.y, xa.z, xa.w};
        const float br[8] = {b0.x, b0.y, b0.z, b0.w, b1.x, b1.y, b1.z, b1.w};
#pragma unroll
        for (int i = 0; i < 4; ++i)
#pragma unroll
            for (int j = 0; j < 8; ++j)
                acc[i][j] = fmaf(xr[i], br[j], acc[i][j]);
    }
    float* Sp = Sbuf + (size_t)(bh * NC + c) * HSTATE;
#pragma unroll
    for (int i = 0; i < 4; ++i) {
        *(float4*)(Sp + (size_t)(tp + i) * D_STATE + tn)     = make_float4(acc[i][0], acc[i][1], acc[i][2], acc[i][3]);
        *(float4*)(Sp + (size_t)(tp + i) * D_STATE + tn + 4) = make_float4(acc[i][4], acc[i][5], acc[i][6], acc[i][7]);
    }
}

// ---------------------------------------------------------------------------
// Pass B: per-element scan over chunks, in-place S -> H_in.
// ---------------------------------------------------------------------------
__global__ __launch_bounds__(256) void state_scan_kernel(
    const float* __restrict__ cumws, float* __restrict__ Sbuf)
{
    const int bh = blockIdx.x;
    const int e  = blockIdx.y * 256 + threadIdx.x;
    float* base = Sbuf + (size_t)bh * NC * HSTATE + e;
    const float* cw = cumws + (size_t)bh * SEQLEN;
    float H = 0.f;
    for (int c = 0; c < NC; ++c) {
        const float P = __expf(cw[c * CHUNK + CHUNK - 1]);
        const float s = base[(size_t)c * HSTATE];
        base[(size_t)c * HSTATE] = H;
        H = fmaf(P, H, s);
    }
}

// ---------------------------------------------------------------------------
// Pass C, MFMA bf16x3: per block (bh,c), 4 waves, wave w owns t-rows
// [w*16, w*16+16).
//   P0: stage C,B (hi/lo, XOR slot-swizzle); issue H,X loads early (T14)
//   P1: G = C@B^T (3 passes x K=128 MFMA); build M in-reg (mask, decay, +D),
//       decompose -> M LDS
//   P2: stage H (reuses B region), X^T (transpose + decompose)
//   P3: acc = C@H^T (MFMA); acc *= Es[t]; acc += M@X (MFMA); store y
// All products hi*hi + hi*lo + lo*hi  => fp32-grade (same as projections).
// ---------------------------------------------------------------------------
__global__ __launch_bounds__(256) void chunk_output_mfma(
    const float* __restrict__ xc, const float* __restrict__ dtw,
    const float* __restrict__ Dp,
    const float* __restrict__ Hbuf, const float* __restrict__ cumws,
    float* __restrict__ y)
{
    const int c  = blockIdx.x / NBH;
    const int bh = blockIdx.x % NBH;
    const int b  = bh / NHEADS, h = bh % NHEADS;
    const int tid  = threadIdx.x;
    const int lane = tid & 63;
    const int w    = tid >> 6;
    const int rowbase = b * SEQLEN + c * CHUNK;

    __shared__ float s_cums[CHUNK], s_dts[CHUNK], s_Es[CHUNK];
    __shared__ __align__(16) __hip_bfloat16 Chi[CHUNK][D_STATE];  // 16 KB
    __shared__ __align__(16) __hip_bfloat16 Clo[CHUNK][D_STATE];  // 16 KB
    __shared__ __align__(16) __hip_bfloat16 BHhi[CHUNK][D_STATE]; // 16 KB (B then H)
    __shared__ __align__(16) __hip_bfloat16 BHlo[CHUNK][D_STATE]; // 16 KB
    __shared__ __align__(16) __hip_bfloat16 Mhi[CHUNK][CHUNK];    // 8 KB
    __shared__ __align__(16) __hip_bfloat16 Mlo[CHUNK][CHUNK];    // 8 KB
    __shared__ __align__(16) __hip_bfloat16 XThi[CHUNK][CHUNK];   // 8 KB
    __shared__ __align__(16) __hip_bfloat16 XTlo[CHUNK][CHUNK];   // 8 KB

    // ---- P0: load C,B (8 fp32 chunks per thread each)
    float4 cv[4][2], bvv[4][2];
#pragma unroll
    for (int k = 0; k < 4; ++k) {
        const int q = tid + k * 256;
        const int row = q >> 4, slot = q & 15;
        const float* rp = xc + (size_t)(rowbase + row) * CONV_DIM + D_SSM;
        bvv[k][0] = *(const float4*)(rp + slot * 8);
        bvv[k][1] = *(const float4*)(rp + slot * 8 + 4);
        cv[k][0]  = *(const float4*)(rp + D_STATE + slot * 8);
        cv[k][1]  = *(const float4*)(rp + D_STATE + slot * 8 + 4);
    }
    if (tid < CHUNK) {
        const float cu = cumws[(size_t)bh * SEQLEN + c * CHUNK + tid];
        s_cums[tid] = cu;
        s_Es[tid]   = __expf(cu);
        s_dts[tid]  = dtw[(size_t)(rowbase + tid) * NHEADS + h];
    }
#pragma unroll
    for (int k = 0; k < 4; ++k) {
        const int q = tid + k * 256;
        const int row = q >> 4, slot = q & 15;
        const int off = row * 256 + ((slot ^ (row & 7)) << 4);
        cvt_wr8(&Chi[0][0],  &Clo[0][0],  off, cv[k][0],  cv[k][1]);
        cvt_wr8(&BHhi[0][0], &BHlo[0][0], off, bvv[k][0], bvv[k][1]);
    }
    // issue H and X loads now; consumed in P2 (latency hidden under P1)
    float4 hv[4][2];
#pragma unroll
    for (int k = 0; k < 4; ++k) {
        const int q = tid + k * 256;
        const int p = q >> 4, slot = q & 15;
        const float* hp = Hbuf + (size_t)(bh * NC + c) * HSTATE + (size_t)p * D_STATE + slot * 8;
        hv[k][0] = *(const float4*)hp;
        hv[k][1] = *(const float4*)(hp + 4);
    }
    float4 xv[4];
#pragma unroll
    for (int k = 0; k < 4; ++k) {
        const int q = tid + k * 256;
        const int s = q >> 4, p4 = (q & 15) * 4;
        xv[k] = *(const float4*)(xc + (size_t)(rowbase + s) * CONV_DIM + h * HEADDIM + p4);
    }
    __syncthreads();

    // ---- P1: G = C @ B^T   (64x64 per block; wave w -> 16 t-rows)
    const int fr = lane & 15;   // row/col within 16-tile (A-row / B-col)
    const int fs = lane >> 4;   // k-slot sub-index
    const int rA = w * 16 + fr; // C row (t) for A-frags

    f32x4 g[4] = {};
#pragma unroll
    for (int pass = 0; pass < 3; ++pass) {
        const char* Ab = (const char*)(pass == 2 ? &Clo[0][0]  : &Chi[0][0]);
        const char* Bb = (const char*)(pass == 1 ? &BHlo[0][0] : &BHhi[0][0]);
#pragma unroll
        for (int kt = 0; kt < 4; ++kt) {
            const bf16x8 af = *(const bf16x8*)(Ab + rA * 256 + (((kt * 4 + fs) ^ (rA & 7)) << 4));
#pragma unroll
            for (int nt = 0; nt < 4; ++nt) {
                const int rb = nt * 16 + fr;
                const bf16x8 bf = *(const bf16x8*)(Bb + rb * 256 + (((kt * 4 + fs) ^ (rb & 7)) << 4));
                g[nt] = __builtin_amdgcn_mfma_f32_16x16x32_bf16(af, bf, g[nt], 0, 0, 0);
            }
        }
    }

    // build M = mask(G * exp(cum_t - cum_s) * dt_s) + D on diag; -> LDS hi/lo
    // acc layout: col s_in = lane&15, row t_in = (lane>>4)*4 + j
    const float Dh = Dp[h];
#pragma unroll
    for (int nt = 0; nt < 4; ++nt) {
        const int s = nt * 16 + fr;
#pragma unroll
        for (int j = 0; j < 4; ++j) {
            const int t = w * 16 + fs * 4 + j;
            float m = 0.f;
            if (s <= t) {
                m = g[nt][j] * __expf(s_cums[t] - s_cums[s]) * s_dts[s];
                if (s == t) m += Dh;
            }
            const __hip_bfloat16 mh = __float2bfloat16(m);
            const __hip_bfloat16 ml = __float2bfloat16(m - __bfloat162float(mh));
            const int moff = t * 128 + ((((s >> 3) ^ (t & 7))) << 4) + ((s & 7) << 1);
            *(__hip_bfloat16*)((char*)&Mhi[0][0] + moff) = mh;
            *(__hip_bfloat16*)((char*)&Mlo[0][0] + moff) = ml;
        }
    }
    __syncthreads();   // all G reads of BH done; M writes done

    // ---- P2: stage H into BH region; X^T (transpose) into XT
#pragma unroll
    for (int k = 0; k < 4; ++k) {
        const int q = tid + k * 256;
        const int p = q >> 4, slot = q & 15;
        const int off = p * 256 + ((slot ^ (p & 7)) << 4);
        cvt_wr8(&BHhi[0][0], &BHlo[0][0], off, hv[k][0], hv[k][1]);
    }
#pragma unroll
    for (int k = 0; k < 4; ++k) {
        const int q = tid + k * 256;
        const int s = q >> 4, p4 = (q & 15) * 4;
        const float f[4] = {xv[k].x, xv[k].y, xv[k].z, xv[k].w};
#pragma unroll
        for (int j = 0; j < 4; ++j) {
            const int p = p4 + j;
            const __hip_bfloat16 xh = __float2bfloat16(f[j]);
            const __hip_bfloat16 xl = __float2bfloat16(f[j] - __bfloat162float(xh));
            const int off = p * 128 + ((((s >> 3) ^ (p & 7))) << 4) + ((s & 7) << 1);
            *(__hip_bfloat16*)((char*)&XThi[0][0] + off) = xh;
            *(__hip_bfloat16*)((char*)&XTlo[0][0] + off) = xl;
        }
    }
    __syncthreads();

    // ---- P3: acc = C@H^T ; acc *= Es[t] ; acc += M@X ; store
    f32x4 acc[4] = {};
#pragma unroll
    for (int pass = 0; pass < 3; ++pass) {
        const char* Ab = (const char*)(pass == 2 ? &Clo[0][0]  : &Chi[0][0]);
        const char* Bb = (const char*)(pass == 1 ? &BHlo[0][0] : &BHhi[0][0]);
#pragma unroll
        for (int kt = 0; kt < 4; ++kt) {
            const bf16x8 af = *(const bf16x8*)(Ab + rA * 256 + (((kt * 4 + fs) ^ (rA & 7)) << 4));
#pragma unroll
            for (int nt = 0; nt < 4; ++nt) {
                const int rp = nt * 16 + fr;
                const bf16x8 bf = *(const bf16x8*)(Bb + rp * 256 + (((kt * 4 + fs) ^ (rp & 7)) << 4));
                acc[nt] = __builtin_amdgcn_mfma_f32_16x16x32_bf16(af, bf, acc[nt], 0, 0, 0);
            }
        }
    }
#pragma unroll
    for (int nt = 0; nt < 4; ++nt)
#pragma unroll
        for (int j = 0; j < 4; ++j)
            acc[nt][j] *= s_Es[w * 16 + fs * 4 + j];

    const int rM = w * 16 + fr;
#pragma unroll
    for (int pass = 0; pass < 3; ++pass) {
        const char* Ab = (const char*)(pass == 2 ? &Mlo[0][0]  : &Mhi[0][0]);
        const char* Bb = (const char*)(pass == 1 ? &XTlo[0][0] : &XThi[0][0]);
#pragma unroll
        for (int kt = 0; kt < 2; ++kt) {
            const bf16x8 af = *(const bf16x8*)(Ab + rM * 128 + (((kt * 4 + fs) ^ (rM & 7)) << 4));
#pragma unroll
            for (int nt = 0; nt < 4; ++nt) {
                const int rp = nt * 16 + fr;
                const bf16x8 bf = *(const bf16x8*)(Bb + rp * 128 + (((kt * 4 + fs) ^ (rp & 7)) << 4));
                acc[nt] = __builtin_amdgcn_mfma_f32_16x16x32_bf16(af, bf, acc[nt], 0, 0, 0);
            }
        }
    }

#pragma unroll
    for (int nt = 0; nt < 4; ++nt) {
        const int p = nt * 16 + fr;
#pragma unroll
        for (int j = 0; j < 4; ++j) {
            const int t = w * 16 + fs * 4 + j;
            y[(size_t)(rowbase + t) * D_SSM + h * HEADDIM + p] = acc[nt][j];
        }
    }
}

// ---------------------------------------------------------------------------
// Fallback sequential scan.
// ---------------------------------------------------------------------------
__global__ __launch_bounds__(256) void scan_kernel(
    const float* __restrict__ xc, const float* __restrict__ dtw,
    const float* __restrict__ A_log, const float* __restrict__ Dp,
    float* __restrict__ y)
{
    const int b   = blockIdx.x / NHEADS;
    const int h   = blockIdx.x % NHEADS;
    const int tid = threadIdx.x;
    const int p   = tid >> 2;
    const int q   = tid & 3;

    __shared__ float dt_s[SEQLEN];
    __shared__ float Bs[4][36];
    __shared__ float Cs[4][36];
    __shared__ float xs[64];

    for (int i = tid; i < SEQLEN; i += 256)
        dt_s[i] = dtw[((size_t)b * SEQLEN + i) * NHEADS + h];

    const float Aneg = -__expf(A_log[h]);
    const float Dh   = Dp[h];

    float hst[32];
#pragma unroll
    for (int i = 0; i < 32; ++i) hst[i] = 0.f;

    const float* row0 = xc + (size_t)b * SEQLEN * CONV_DIM;
    float rBC = row0[D_SSM + tid];
    float rx  = (tid < 64) ? row0[h * HEADDIM + tid] : 0.f;

    for (int t = 0; t < SEQLEN; ++t) {
        __syncthreads();
        if (tid < 128) Bs[tid >> 5][tid & 31] = rBC;
        else           Cs[(tid >> 5) & 3][tid & 31] = rBC;
        if (tid < 64)  xs[tid] = rx;
        if (t + 1 < SEQLEN) {
            const float* rp = row0 + (size_t)(t + 1) * CONV_DIM;
            rBC = rp[D_SSM + tid];
            if (tid < 64) rx = rp[h * HEADDIM + tid];
        }
        __syncthreads();

        const float dtv = dt_s[t];
        const float dA  = __expf(dtv * Aneg);
        const float dtx = dtv * xs[p];
        float ysum = 0.f;
#pragma unroll
        for (int j4 = 0; j4 < 8; ++j4) {
            const float4 Bv = *(const float4*)&Bs[q][j4 * 4];
            const float4 Cv = *(const float4*)&Cs[q][j4 * 4];
            float* hp = &hst[j4 * 4];
            hp[0] = fmaf(hp[0], dA, dtx * Bv.x); ysum = fmaf(hp[0], Cv.x, ysum);
            hp[1] = fmaf(hp[1], dA, dtx * Bv.y); ysum = fmaf(hp[1], Cv.y, ysum);
            hp[2] = fmaf(hp[2], dA, dtx * Bv.z); ysum = fmaf(hp[2], Cv.z, ysum);
            hp[3] = fmaf(hp[3], dA, dtx * Bv.w); ysum = fmaf(hp[3], Cv.w, ysum);
        }
        ysum += __shfl_xor(ysum, 1);
        ysum += __shfl_xor(ysum, 2);
        if (q == 0)
            y[((size_t)b * SEQLEN + t) * D_SSM + h * HEADDIM + p] = ysum + Dh * xs[p];
    }
}

// ---------------------------------------------------------------------------
// Gate + RMSNorm -> bf16x3 rows (A-pattern [hi|hi|lo]).
// ---------------------------------------------------------------------------
__global__ __launch_bounds__(256) void gatenorm_x3_kernel(
    const float* __restrict__ y, const float* __restrict__ zbuf,
    const float* __restrict__ norm_w, __hip_bfloat16* __restrict__ ybx3)
{
    const int row = blockIdx.x;
    const int tid = threadIdx.x;
    const float* yr = y + (size_t)row * D_SSM;
    const float* zr = zbuf + (size_t)row * D_SSM;

    float v[6];
    float ss = 0.f;
#pragma unroll
    for (int i = 0; i < 6; ++i) {
        const int e = tid + i * 256;
        const float yv = yr[e];
        const float zv = zr[e];
        const float g  = yv * (zv * sigmoidf_(zv));
        v[i] = g;
        ss = fmaf(g, g, ss);
    }
#pragma unroll
    for (int m = 1; m < 64; m <<= 1) ss += __shfl_xor(ss, m);
    __shared__ float ws[4];
    if ((tid & 63) == 0) ws[tid >> 6] = ss;
    __syncthreads();
    const float tot = ws[0] + ws[1] + ws[2] + ws[3];
    const float r = rsqrtf(tot * (1.0f / D_SSM) + EPS);
    __hip_bfloat16* orow = ybx3 + (size_t)row * K3_OUT;
#pragma unroll
    for (int i = 0; i < 6; ++i) {
        const int e = tid + i * 256;
        const float g = v[i] * r * norm_w[e];
        const __hip_bfloat16 hi = __float2bfloat16(g);
        const __hip_bfloat16 lo = __float2bfloat16(g - __bfloat162float(hi));
        orow[e] = hi;
        orow[D_SSM + e] = hi;
        orow[2 * D_SSM + e] = lo;
    }
}

// ---------------------------------------------------------------------------
// Gate + RMSNorm in place (fallback path).
// ---------------------------------------------------------------------------
__global__ __launch_bounds__(256) void gatenorm_kernel(
    float* y, const float* __restrict__ zbuf, const float* __restrict__ norm_w)
{
    const int row = blockIdx.x;
    const int tid = threadIdx.x;
    float* yr = y + (size_t)row * D_SSM;
    const float* zr = zbuf + (size_t)row * D_SSM;

    float v[6];
    float ss = 0.f;
#pragma unroll
    for (int i = 0; i < 6; ++i) {
        const int e = tid + i * 256;
        const float yv = yr[e];
        const float zv = zr[e];
        const float g  = yv * (zv * sigmoidf_(zv));
        v[i] = g;
        ss = fmaf(g, g, ss);
    }
#pragma unroll
    for (int m = 1; m < 64; m <<= 1) ss += __shfl_xor(ss, m);
    __shared__ float ws[4];
    if ((tid & 63) == 0) ws[tid >> 6] = ss;
    __syncthreads();
    const float tot = ws[0] + ws[1] + ws[2] + ws[3];
    const float r = rsqrtf(tot * (1.0f / D_SSM) + EPS);
#pragma unroll
    for (int i = 0; i < 6; ++i) {
        const int e = tid + i * 256;
        yr[e] = v[i] * r * norm_w[e];
    }
}

// ---------------------------------------------------------------------------
extern "C" void kernel_launch(void* const* d_in, const int* in_sizes, int n_in,
                              void* d_out, int out_size, void* d_ws, size_t ws_size,
                              hipStream_t stream)
{
    const float* u       = (const float*)d_in[0];
    const float* W_in    = (const float*)d_in[1];
    const float* conv_w  = (const float*)d_in[2];
    const float* conv_b  = (const float*)d_in[3];
    const float* dt_bias = (const float*)d_in[4];
    const float* A_log   = (const float*)d_in[5];
    const float* Dp      = (const float*)d_in[6];
    const float* norm_w  = (const float*)d_in[7];
    const float* W_out   = (const float*)d_in[8];
    float* out = (float*)d_out;

    const size_t SZ_Z   = (size_t)NROWS * D_SSM;
    const size_t SZ_XBC = (size_t)NROWS * CONV_DIM;
    const size_t SZ_DT  = (size_t)NROWS * NHEADS;
    const size_t SZ_S   = (size_t)NBH * NC * HSTATE;
    const size_t SZ_CUM = (size_t)NBH * SEQLEN;

    const size_t need_new = (SZ_Z + SZ_S + SZ_Z + SZ_XBC + SZ_DT + SZ_CUM) * sizeof(float);
    const bool use_new = ws_size >= need_new;

    if (use_new) {
        float* zbuf = (float*)d_ws;
        float* Breg = zbuf + SZ_Z;
        float* Creg = Breg + SZ_S;
        float* Xreg = Creg + SZ_Z;
        float* dtw   = Xreg + SZ_XBC;
        float* cumws = dtw + SZ_DT;

        float* xbc   = Breg;
        float* dtraw = Breg + SZ_XBC;
        float* Sbuf  = Breg;
        __hip_bfloat16* ybx3 = (__hip_bfloat16*)Breg;
        __hip_bfloat16* u3   = (__hip_bfloat16*)Creg;
        float* yb    = Creg;
        __hip_bfloat16* W_in3  = (__hip_bfloat16*)Xreg;
        float* xc    = Xreg;
        __hip_bfloat16* W_out3 = (__hip_bfloat16*)Xreg;

        decompose3<1><<<(NROWS * (D_MODEL / 4) + 255) / 256, 256, 0, stream>>>(
            u, u3, NROWS, NROWS, D_MODEL);
        decompose3<0><<<(NPAD_IN * (D_MODEL / 4) + 255) / 256, 256, 0, stream>>>(
            W_in, W_in3, D_IN_PROJ, NPAD_IN, D_MODEL);

        gemm_bf16x3<1><<<dim3(NPAD_IN / 128, NROWS / 128), 256, 0, stream>>>(
            u3, W_in3, zbuf, xbc, dtraw, 0, K3_IN);

        conv_silu_kernel<<<(NROWS * (CONV_DIM / 4) + 255) / 256, 256, 0, stream>>>(
            xbc, conv_w, conv_b, xc);

        dt_kernel<<<NROWS, 64, 0, stream>>>(dtraw, dt_bias, dtw);

        chunk_state_kernel<<<NBH * NC, 256, 0, stream>>>(xc, dtw, A_log, Sbuf, cumws);
        state_scan_kernel<<<dim3(NBH, HSTATE / 256), 256, 0, stream>>>(cumws, Sbuf);
        chunk_output_mfma<<<NBH * NC, 256, 0, stream>>>(xc, dtw, Dp, Sbuf, cumws, yb);

        decompose3<0><<<(D_MODEL * (D_SSM / 4) + 255) / 256, 256, 0, stream>>>(
            W_out, W_out3, D_MODEL, D_MODEL, D_SSM);

        gatenorm_x3_kernel<<<NROWS, 256, 0, stream>>>(yb, zbuf, norm_w, ybx3);

        gemm_bf16x3<0><<<dim3(D_MODEL / 128, NROWS / 128), 256, 0, stream>>>(
            ybx3, W_out3, out, nullptr, nullptr, D_MODEL, K3_OUT);
    } else {
        float* zbuf  = (float*)d_ws;
        float* Rp    = zbuf + SZ_Z;
        float* xbc   = Rp;
        float* yb    = Rp;
        float* dtraw = Rp + SZ_XBC;
        float* xc    = dtraw + SZ_DT;
        float* dtw   = xc + SZ_XBC;

        gemm_inproj<<<dim3((D_IN_PROJ + 63) / 64, NROWS / 64), 256, 0, stream>>>(
            u, W_in, zbuf, xbc, dtraw);
        conv_silu_kernel<<<(NROWS * (CONV_DIM / 4) + 255) / 256, 256, 0, stream>>>(
            xbc, conv_w, conv_b, xc);
        dt_kernel<<<NROWS, 64, 0, stream>>>(dtraw, dt_bias, dtw);
        scan_kernel<<<NBH, 256, 0, stream>>>(xc, dtw, A_log, Dp, yb);
        gatenorm_kernel<<<NROWS, 256, 0, stream>>>(yb, zbuf, norm_w);
        gemm_nt<64, 64, 16><<<dim3(D_MODEL / 64, NROWS / 64), 256, 0, stream>>>(
            yb, W_out, out, NROWS, D_MODEL, D_SSM);
    }
}

// Round 8
// 695.604 us; speedup vs baseline: 3.8040x; 1.0455x over previous
//
#include <hip/hip_runtime.h>
#include <hip/hip_bf16.h>
#include <math.h>

#define D_MODEL   768
#define D_SSM     1536
#define D_STATE   128
#define D_CONV    4
#define HEADDIM   64
#define NHEADS    24
#define CONV_DIM  1792          // D_SSM + 2*D_STATE
#define D_IN_PROJ 3352          // 2*D_SSM + 2*D_STATE + NHEADS
#define BATCH     4
#define SEQLEN    2048
#define NROWS     (BATCH * SEQLEN)   // 8192
#define EPS       1e-5f

#define CHUNK     64
#define NC        (SEQLEN / CHUNK)    // 32
#define NBH       (BATCH * NHEADS)    // 96
#define HSTATE    (HEADDIM * D_STATE) // 8192

#define K3_IN     (3 * D_MODEL)       // 2304
#define K3_OUT    (3 * D_SSM)         // 4608
#define NPAD_IN   3456                // 27 * 128 (>= D_IN_PROJ)

typedef __attribute__((ext_vector_type(8))) short bf16x8;
typedef __attribute__((ext_vector_type(4))) float f32x4;

__device__ __forceinline__ float sigmoidf_(float x) {
    return 1.0f / (1.0f + __expf(-x));
}

__device__ __forceinline__ float softplusf_(float x) {
    return fmaxf(x, 0.f) + log1pf(__expf(-fabsf(x)));
}

__device__ __forceinline__ void gload16(void* lds, const void* g) {
    __builtin_amdgcn_global_load_lds(
        (const __attribute__((address_space(1))) unsigned int*)g,
        (__attribute__((address_space(3))) unsigned int*)lds, 16, 0, 0);
}

// cvt 8 fp32 -> bf16 hi/lo planes, one b128 write each
__device__ __forceinline__ void cvt_wr8(__hip_bfloat16* hb, __hip_bfloat16* lb,
                                        int off, float4 a, float4 b)
{
    union { __hip_bfloat16 h[8]; uint4 u; } hi, lo;
    const float f[8] = {a.x, a.y, a.z, a.w, b.x, b.y, b.z, b.w};
#pragma unroll
    for (int j = 0; j < 8; ++j) {
        const __hip_bfloat16 h = __float2bfloat16(f[j]);
        hi.h[j] = h;
        lo.h[j] = __float2bfloat16(f[j] - __bfloat162float(h));
    }
    *(uint4*)((char*)hb + off) = hi.u;
    *(uint4*)((char*)lb + off) = lo.u;
}

// ---------------------------------------------------------------------------
// Decompose fp32 [R][K] -> bf16 [Rpad][3K].
// APAT=1 (A-side): [hi | hi | lo]   APAT=0 (B-side): [hi | lo | hi]
// ---------------------------------------------------------------------------
template<int APAT>
__global__ __launch_bounds__(256) void decompose3(
    const float* __restrict__ X, __hip_bfloat16* __restrict__ X3,
    int R, int Rpad, int K)
{
    const int idx = blockIdx.x * 256 + threadIdx.x;
    if (idx >= Rpad * (K / 4)) return;
    const int r = idx / (K / 4);
    const int k = (idx % (K / 4)) * 4;

    union { __hip_bfloat16 h[4]; uint2 u; } phi, plo;
    if (r < R) {
        const float4 x = *(const float4*)(X + (size_t)r * K + k);
        const float xs[4] = {x.x, x.y, x.z, x.w};
#pragma unroll
        for (int j = 0; j < 4; ++j) {
            phi.h[j] = __float2bfloat16(xs[j]);
            plo.h[j] = __float2bfloat16(xs[j] - __bfloat162float(phi.h[j]));
        }
    } else {
#pragma unroll
        for (int j = 0; j < 4; ++j) { phi.h[j] = __float2bfloat16(0.f); plo.h[j] = phi.h[j]; }
    }
    __hip_bfloat16* row = X3 + (size_t)r * (3 * K);
    *(uint2*)(row + k)         = phi.u;
    *(uint2*)(row + K + k)     = APAT ? phi.u : plo.u;
    *(uint2*)(row + 2 * K + k) = APAT ? plo.u : phi.u;
}

// ---------------------------------------------------------------------------
// MFMA GEMM (NT): C[M,N] = A''[M,K3] * B''[N,K3]^T, bf16 in / fp32 out.
// 128x128 tile, 4 waves, 16x16x32 MFMA, BK=32, gload_lds dbuf.
// 1D grid with bijective XCD swizzle (T1): consecutive swz ids share the
// A-row-panel (bx-minor), one XCD gets a contiguous chunk.
// ---------------------------------------------------------------------------
template<int MODE>
__global__ __launch_bounds__(256) void gemm_bf16x3(
    const __hip_bfloat16* __restrict__ Ab, const __hip_bfloat16* __restrict__ Bb,
    float* __restrict__ C0, float* __restrict__ C1, float* __restrict__ C2,
    int Nreal, int K3, int nx)
{
    __shared__ __hip_bfloat16 Asm[2][128][32];
    __shared__ __hip_bfloat16 Bsm[2][128][32];
    const int tid  = threadIdx.x;
    const int lane = tid & 63;
    const int w    = tid >> 6;
    const int wr   = w >> 1, wc = w & 1;

    // T1: bijective XCD swizzle (gridDim.x % 8 == 0)
    const int cpx = gridDim.x >> 3;
    const int swz = (blockIdx.x & 7) * cpx + (blockIdx.x >> 3);
    const int bm  = (swz / nx) * 128;
    const int bn  = (swz % nx) * 128;

    const __hip_bfloat16* gA[2];
    const __hip_bfloat16* gB[2];
    int ldsrow[2];
#pragma unroll
    for (int i = 0; i < 2; ++i) {
        const int r  = w * 32 + i * 16 + (lane >> 2);
        const int sl = (lane & 3) ^ ((r ^ (r >> 2)) & 3);
        ldsrow[i] = w * 32 + i * 16;
        gA[i] = Ab + (size_t)(bm + r) * K3 + sl * 8;
        gB[i] = Bb + (size_t)(bn + r) * K3 + sl * 8;
    }

    int aoff[4], boff[4];
#pragma unroll
    for (int mi = 0; mi < 4; ++mi) {
        const int ra = wr * 64 + mi * 16 + (lane & 15);
        aoff[mi] = ra * 64 + (((lane >> 4) ^ ((ra ^ (ra >> 2)) & 3)) << 4);
        const int rb = wc * 64 + mi * 16 + (lane & 15);
        boff[mi] = rb * 64 + (((lane >> 4) ^ ((rb ^ (rb >> 2)) & 3)) << 4);
    }

    f32x4 acc[4][4] = {};

    const int nk = K3 / 32;
#pragma unroll
    for (int i = 0; i < 2; ++i) {
        gload16(&Asm[0][ldsrow[i]][0], gA[i]);
        gload16(&Bsm[0][ldsrow[i]][0], gB[i]);
    }
    __syncthreads();

    int buf = 0;
    for (int kt = 0; kt < nk; ++kt) {
        if (kt + 1 < nk) {
            const int ko = (kt + 1) * 32;
#pragma unroll
            for (int i = 0; i < 2; ++i) {
                gload16(&Asm[buf ^ 1][ldsrow[i]][0], gA[i] + ko);
                gload16(&Bsm[buf ^ 1][ldsrow[i]][0], gB[i] + ko);
            }
        }
        const char* ab = (const char*)&Asm[buf][0][0];
        const char* bb = (const char*)&Bsm[buf][0][0];
        bf16x8 afr[4], bfr[4];
#pragma unroll
        for (int i = 0; i < 4; ++i) {
            afr[i] = *(const bf16x8*)(ab + aoff[i]);
            bfr[i] = *(const bf16x8*)(bb + boff[i]);
        }
#pragma unroll
        for (int mi = 0; mi < 4; ++mi)
#pragma unroll
            for (int ni = 0; ni < 4; ++ni)
                acc[mi][ni] = __builtin_amdgcn_mfma_f32_16x16x32_bf16(
                    afr[mi], bfr[ni], acc[mi][ni], 0, 0, 0);
        __syncthreads();
        buf ^= 1;
    }

#pragma unroll
    for (int mi = 0; mi < 4; ++mi) {
        const int rn = bm + wr * 64 + mi * 16 + ((lane >> 4) << 2);
#pragma unroll
        for (int ni = 0; ni < 4; ++ni) {
            const int cn = bn + wc * 64 + ni * 16 + (lane & 15);
#pragma unroll
            for (int j = 0; j < 4; ++j) {
                const float v = acc[mi][ni][j];
                const int r = rn + j;
                if (MODE == 0) {
                    C0[(size_t)r * Nreal + cn] = v;
                } else {
                    if (cn < D_SSM)                 C0[(size_t)r * D_SSM + cn] = v;
                    else if (cn < D_SSM + CONV_DIM) C1[(size_t)r * CONV_DIM + (cn - D_SSM)] = v;
                    else if (cn < D_IN_PROJ)        C2[(size_t)r * NHEADS + (cn - D_SSM - CONV_DIM)] = v;
                }
            }
        }
    }
}

// ---------------------------------------------------------------------------
// fp32 GEMM kernels (fallback path only)
// ---------------------------------------------------------------------------
template<int BM, int BN, int BK>
__global__ __launch_bounds__(256) void gemm_nt(
    const float* __restrict__ A, const float* __restrict__ B,
    float* __restrict__ C, int M, int N, int K)
{
    __shared__ float As[BK][BM];
    __shared__ float Bs[BK][BN];
    const int tid = threadIdx.x;
    const int bm  = blockIdx.y * BM;
    const int bn  = blockIdx.x * BN;
    const int tm  = (tid & 15) << 2;
    const int tn  = (tid >> 4) << 2;
    const int am  = tid & 63;
    const int ak  = (tid >> 6) << 2;
    float acc[4][4] = {};
    for (int k0 = 0; k0 < K; k0 += BK) {
        const float4 av = *(const float4*)(A + (size_t)(bm + am) * K + (k0 + ak));
        float4 bv = make_float4(0.f, 0.f, 0.f, 0.f);
        if (bn + am < N)
            bv = *(const float4*)(B + (size_t)(bn + am) * K + (k0 + ak));
        __syncthreads();
        As[ak + 0][am] = av.x; As[ak + 1][am] = av.y;
        As[ak + 2][am] = av.z; As[ak + 3][am] = av.w;
        Bs[ak + 0][am] = bv.x; Bs[ak + 1][am] = bv.y;
        Bs[ak + 2][am] = bv.z; Bs[ak + 3][am] = bv.w;
        __syncthreads();
#pragma unroll
        for (int kk = 0; kk < BK; ++kk) {
            const float4 a4 = *(const float4*)&As[kk][tm];
            const float4 b4 = *(const float4*)&Bs[kk][tn];
            const float a[4]  = {a4.x, a4.y, a4.z, a4.w};
            const float bb[4] = {b4.x, b4.y, b4.z, b4.w};
#pragma unroll
            for (int i = 0; i < 4; ++i)
#pragma unroll
                for (int j = 0; j < 4; ++j)
                    acc[i][j] = fmaf(a[i], bb[j], acc[i][j]);
        }
    }
#pragma unroll
    for (int i = 0; i < 4; ++i)
#pragma unroll
        for (int j = 0; j < 4; ++j) {
            const int cn = bn + tn + j;
            if (cn < N)
                C[(size_t)(bm + tm + i) * N + cn] = acc[i][j];
        }
}

__global__ __launch_bounds__(256) void gemm_inproj(
    const float* __restrict__ A, const float* __restrict__ B,
    float* __restrict__ zbuf, float* __restrict__ xbc, float* __restrict__ dtraw)
{
    constexpr int BM = 64, BN = 64, BK = 16;
    __shared__ float As[BK][BM];
    __shared__ float Bs[BK][BN];
    const int tid = threadIdx.x;
    const int bm  = blockIdx.y * BM;
    const int bn  = blockIdx.x * BN;
    const int tm  = (tid & 15) << 2;
    const int tn  = (tid >> 4) << 2;
    const int am  = tid & 63;
    const int ak  = (tid >> 6) << 2;
    float acc[4][4] = {};
    for (int k0 = 0; k0 < D_MODEL; k0 += BK) {
        const float4 av = *(const float4*)(A + (size_t)(bm + am) * D_MODEL + (k0 + ak));
        float4 bv = make_float4(0.f, 0.f, 0.f, 0.f);
        if (bn + am < D_IN_PROJ)
            bv = *(const float4*)(B + (size_t)(bn + am) * D_MODEL + (k0 + ak));
        __syncthreads();
        As[ak + 0][am] = av.x; As[ak + 1][am] = av.y;
        As[ak + 2][am] = av.z; As[ak + 3][am] = av.w;
        Bs[ak + 0][am] = bv.x; Bs[ak + 1][am] = bv.y;
        Bs[ak + 2][am] = bv.z; Bs[ak + 3][am] = bv.w;
        __syncthreads();
#pragma unroll
        for (int kk = 0; kk < BK; ++kk) {
            const float4 a4 = *(const float4*)&As[kk][tm];
            const float4 b4 = *(const float4*)&Bs[kk][tn];
            const float a[4]  = {a4.x, a4.y, a4.z, a4.w};
            const float bb[4] = {b4.x, b4.y, b4.z, b4.w};
#pragma unroll
            for (int i = 0; i < 4; ++i)
#pragma unroll
                for (int j = 0; j < 4; ++j)
                    acc[i][j] = fmaf(a[i], bb[j], acc[i][j]);
        }
    }
    float* Cp; int ldc, cb, nlim = BN;
    if (bn < D_SSM)                  { Cp = zbuf;  ldc = D_SSM;    cb = bn; }
    else if (bn < D_SSM + CONV_DIM)  { Cp = xbc;   ldc = CONV_DIM; cb = bn - D_SSM; }
    else { Cp = dtraw; ldc = NHEADS; cb = bn - (D_SSM + CONV_DIM); nlim = NHEADS; }
#pragma unroll
    for (int i = 0; i < 4; ++i)
#pragma unroll
        for (int j = 0; j < 4; ++j)
            if (tn + j < nlim)
                Cp[(size_t)(bm + tm + i) * ldc + cb + tn + j] = acc[i][j];
}

// ---------------------------------------------------------------------------
// Depthwise causal conv (width 4) + bias + SiLU.
// ---------------------------------------------------------------------------
__global__ __launch_bounds__(256) void conv_silu_kernel(
    const float* __restrict__ xbc, const float* __restrict__ cw,
    const float* __restrict__ cb, float* __restrict__ xc)
{
    const int idx = blockIdx.x * 256 + threadIdx.x;
    if (idx >= NROWS * (CONV_DIM / 4)) return;
    const int row = idx / (CONV_DIM / 4);
    const int c   = (idx % (CONV_DIM / 4)) * 4;
    const int l   = row & (SEQLEN - 1);

    const float* base = xbc + (size_t)row * CONV_DIM + c;
    const float4 cbv = *(const float4*)(cb + c);
    float acc[4] = {cbv.x, cbv.y, cbv.z, cbv.w};
    const float* w = cw + (size_t)c * D_CONV;
#pragma unroll
    for (int k = 0; k < D_CONV; ++k) {
        const int ls = l + k - 3;
        if (ls >= 0) {
            const float4 xv = *(const float4*)(base + (ptrdiff_t)(k - 3) * CONV_DIM);
            acc[0] = fmaf(w[0 * D_CONV + k], xv.x, acc[0]);
            acc[1] = fmaf(w[1 * D_CONV + k], xv.y, acc[1]);
            acc[2] = fmaf(w[2 * D_CONV + k], xv.z, acc[2]);
            acc[3] = fmaf(w[3 * D_CONV + k], xv.w, acc[3]);
        }
    }
    float4 o;
    o.x = acc[0] * sigmoidf_(acc[0]);
    o.y = acc[1] * sigmoidf_(acc[1]);
    o.z = acc[2] * sigmoidf_(acc[2]);
    o.w = acc[3] * sigmoidf_(acc[3]);
    *(float4*)(xc + (size_t)row * CONV_DIM + c) = o;
}

// ---------------------------------------------------------------------------
// dt = softplus(dt_raw + dt_bias)   (fallback path only)
// ---------------------------------------------------------------------------
__global__ __launch_bounds__(64) void dt_kernel(
    const float* __restrict__ dtraw, const float* __restrict__ dt_bias,
    float* __restrict__ dtw)
{
    const int row = blockIdx.x;
    const int tid = threadIdx.x;
    if (tid < NHEADS)
        dtw[(size_t)row * NHEADS + tid] = softplusf_(dtraw[(size_t)row * NHEADS + tid] + dt_bias[tid]);
}

// ---------------------------------------------------------------------------
// Pass A, MFMA bf16x3: per block (bh,c), 4 waves; wave w owns p-rows
// [w*16, w*16+16). S[p][n] = sum_s (x[s][p]*wls[s]) * B[s][n], K=64 over s.
// dt computed inline from dtraw (softplus); cumsum via wave-0 shfl scan.
// Operands transposed into LDS hi/lo planes with slot-XOR swizzle.
// ---------------------------------------------------------------------------
__global__ __launch_bounds__(256) void chunk_state_mfma(
    const float* __restrict__ xc, const float* __restrict__ dtraw,
    const float* __restrict__ dt_bias, const float* __restrict__ A_log,
    float* __restrict__ Sbuf, float* __restrict__ cumws)
{
    const int c  = blockIdx.x / NBH;
    const int bh = blockIdx.x % NBH;
    const int b  = bh / NHEADS, h = bh % NHEADS;
    const int tid  = threadIdx.x;
    const int lane = tid & 63;
    const int w    = tid >> 6;
    const int rowbase = b * SEQLEN + c * CHUNK;

    __shared__ float s_wls[CHUNK];
    __shared__ __align__(16) __hip_bfloat16 Ahi[CHUNK][CHUNK];    // Xw^T [p][s], 8 KB
    __shared__ __align__(16) __hip_bfloat16 Alo[CHUNK][CHUNK];
    __shared__ __align__(16) __hip_bfloat16 Bhi[D_STATE][CHUNK];  // B^T [n][s], 16 KB
    __shared__ __align__(16) __hip_bfloat16 Blo[D_STATE][CHUNK];

    // issue all staging loads early (independent of the scan)
    float4 bv[8];
#pragma unroll
    for (int k = 0; k < 8; ++k) {
        const int q = tid + k * 256;
        const int s = q >> 5, n4 = (q & 31) * 4;
        bv[k] = *(const float4*)(xc + (size_t)(rowbase + s) * CONV_DIM + D_SSM + n4);
    }
    float4 xv[4];
#pragma unroll
    for (int k = 0; k < 4; ++k) {
        const int q = tid + k * 256;
        const int s = q >> 4, p4 = (q & 15) * 4;
        xv[k] = *(const float4*)(xc + (size_t)(rowbase + s) * CONV_DIM + h * HEADDIM + p4);
    }

    // wave 0: dt softplus, inclusive scan, wls
    if (tid < CHUNK) {
        const float Aneg = -__expf(A_log[h]);
        const float dtv = softplusf_(dtraw[(size_t)(rowbase + tid) * NHEADS + h] + dt_bias[h]);
        float v = Aneg * dtv;
#pragma unroll
        for (int d = 1; d < 64; d <<= 1) {
            const float o = __shfl_up(v, d);
            if (lane >= d) v += o;
        }
        cumws[(size_t)bh * SEQLEN + c * CHUNK + tid] = v;
        const float clast = __shfl(v, 63);
        s_wls[tid] = __expf(clast - v) * dtv;
    }

    // B^T staging (no wls dependency)
#pragma unroll
    for (int k = 0; k < 8; ++k) {
        const int q = tid + k * 256;
        const int s = q >> 5, n4 = (q & 31) * 4;
        const float f[4] = {bv[k].x, bv[k].y, bv[k].z, bv[k].w};
#pragma unroll
        for (int j = 0; j < 4; ++j) {
            const int n = n4 + j;
            const __hip_bfloat16 hh = __float2bfloat16(f[j]);
            const __hip_bfloat16 ll = __float2bfloat16(f[j] - __bfloat162float(hh));
            const int off = n * 128 + ((((s >> 3) ^ (n & 7))) << 4) + ((s & 7) << 1);
            *(__hip_bfloat16*)((char*)&Bhi[0][0] + off) = hh;
            *(__hip_bfloat16*)((char*)&Blo[0][0] + off) = ll;
        }
    }
    __syncthreads();   // s_wls visible

    // Xw^T staging
#pragma unroll
    for (int k = 0; k < 4; ++k) {
        const int q = tid + k * 256;
        const int s = q >> 4, p4 = (q & 15) * 4;
        const float wl = s_wls[s];
        const float f[4] = {xv[k].x * wl, xv[k].y * wl, xv[k].z * wl, xv[k].w * wl};
#pragma unroll
        for (int j = 0; j < 4; ++j) {
            const int p = p4 + j;
            const __hip_bfloat16 hh = __float2bfloat16(f[j]);
            const __hip_bfloat16 ll = __float2bfloat16(f[j] - __bfloat162float(hh));
            const int off = p * 128 + ((((s >> 3) ^ (p & 7))) << 4) + ((s & 7) << 1);
            *(__hip_bfloat16*)((char*)&Ahi[0][0] + off) = hh;
            *(__hip_bfloat16*)((char*)&Alo[0][0] + off) = ll;
        }
    }
    __syncthreads();

    // MFMA: S[p][n], 3 passes (hi*hi + hi*lo + lo*hi)
    const int fr = lane & 15;
    const int fs = lane >> 4;
    const int rA = w * 16 + fr;
    f32x4 acc[8] = {};
#pragma unroll
    for (int pass = 0; pass < 3; ++pass) {
        const char* Ab = (const char*)(pass == 2 ? &Alo[0][0] : &Ahi[0][0]);
        const char* Bb = (const char*)(pass == 1 ? &Blo[0][0] : &Bhi[0][0]);
#pragma unroll
        for (int kh = 0; kh < 2; ++kh) {
            const int sl = kh * 4 + fs;
            const bf16x8 af = *(const bf16x8*)(Ab + rA * 128 + ((sl ^ (rA & 7)) << 4));
#pragma unroll
            for (int nt = 0; nt < 8; ++nt) {
                const int rB = nt * 16 + fr;
                const bf16x8 bf = *(const bf16x8*)(Bb + rB * 128 + ((sl ^ (rB & 7)) << 4));
                acc[nt] = __builtin_amdgcn_mfma_f32_16x16x32_bf16(af, bf, acc[nt], 0, 0, 0);
            }
        }
    }

    float* Sp = Sbuf + (size_t)(bh * NC + c) * HSTATE;
#pragma unroll
    for (int nt = 0; nt < 8; ++nt) {
        const int n = nt * 16 + fr;
#pragma unroll
        for (int j = 0; j < 4; ++j) {
            const int p = w * 16 + fs * 4 + j;
            Sp[(size_t)p * D_STATE + n] = acc[nt][j];
        }
    }
}

// ---------------------------------------------------------------------------
// Pass B: per-element scan over chunks, in-place S -> H_in.
// ---------------------------------------------------------------------------
__global__ __launch_bounds__(256) void state_scan_kernel(
    const float* __restrict__ cumws, float* __restrict__ Sbuf)
{
    const int bh = blockIdx.x;
    const int e  = blockIdx.y * 256 + threadIdx.x;
    float* base = Sbuf + (size_t)bh * NC * HSTATE + e;
    const float* cw = cumws + (size_t)bh * SEQLEN;
    float H = 0.f;
    for (int c = 0; c < NC; ++c) {
        const float P = __expf(cw[c * CHUNK + CHUNK - 1]);
        const float s = base[(size_t)c * HSTATE];
        base[(size_t)c * HSTATE] = H;
        H = fmaf(P, H, s);
    }
}

// ---------------------------------------------------------------------------
// Pass C, MFMA bf16x3 (round-7 kernel; dt now inline from dtraw).
// ---------------------------------------------------------------------------
__global__ __launch_bounds__(256) void chunk_output_mfma(
    const float* __restrict__ xc, const float* __restrict__ dtraw,
    const float* __restrict__ dt_bias, const float* __restrict__ Dp,
    const float* __restrict__ Hbuf, const float* __restrict__ cumws,
    float* __restrict__ y)
{
    const int c  = blockIdx.x / NBH;
    const int bh = blockIdx.x % NBH;
    const int b  = bh / NHEADS, h = bh % NHEADS;
    const int tid  = threadIdx.x;
    const int lane = tid & 63;
    const int w    = tid >> 6;
    const int rowbase = b * SEQLEN + c * CHUNK;

    __shared__ float s_cums[CHUNK], s_dts[CHUNK], s_Es[CHUNK];
    __shared__ __align__(16) __hip_bfloat16 Chi[CHUNK][D_STATE];
    __shared__ __align__(16) __hip_bfloat16 Clo[CHUNK][D_STATE];
    __shared__ __align__(16) __hip_bfloat16 BHhi[CHUNK][D_STATE];
    __shared__ __align__(16) __hip_bfloat16 BHlo[CHUNK][D_STATE];
    __shared__ __align__(16) __hip_bfloat16 Mhi[CHUNK][CHUNK];
    __shared__ __align__(16) __hip_bfloat16 Mlo[CHUNK][CHUNK];
    __shared__ __align__(16) __hip_bfloat16 XThi[CHUNK][CHUNK];
    __shared__ __align__(16) __hip_bfloat16 XTlo[CHUNK][CHUNK];

    // ---- P0: load C,B
    float4 cv[4][2], bvv[4][2];
#pragma unroll
    for (int k = 0; k < 4; ++k) {
        const int q = tid + k * 256;
        const int row = q >> 4, slot = q & 15;
        const float* rp = xc + (size_t)(rowbase + row) * CONV_DIM + D_SSM;
        bvv[k][0] = *(const float4*)(rp + slot * 8);
        bvv[k][1] = *(const float4*)(rp + slot * 8 + 4);
        cv[k][0]  = *(const float4*)(rp + D_STATE + slot * 8);
        cv[k][1]  = *(const float4*)(rp + D_STATE + slot * 8 + 4);
    }
    if (tid < CHUNK) {
        const float cu = cumws[(size_t)bh * SEQLEN + c * CHUNK + tid];
        s_cums[tid] = cu;
        s_Es[tid]   = __expf(cu);
        s_dts[tid]  = softplusf_(dtraw[(size_t)(rowbase + tid) * NHEADS + h] + dt_bias[h]);
    }
#pragma unroll
    for (int k = 0; k < 4; ++k) {
        const int q = tid + k * 256;
        const int row = q >> 4, slot = q & 15;
        const int off = row * 256 + ((slot ^ (row & 7)) << 4);
        cvt_wr8(&Chi[0][0],  &Clo[0][0],  off, cv[k][0],  cv[k][1]);
        cvt_wr8(&BHhi[0][0], &BHlo[0][0], off, bvv[k][0], bvv[k][1]);
    }
    // issue H and X loads now; consumed in P2 (latency hidden under P1)
    float4 hv[4][2];
#pragma unroll
    for (int k = 0; k < 4; ++k) {
        const int q = tid + k * 256;
        const int p = q >> 4, slot = q & 15;
        const float* hp = Hbuf + (size_t)(bh * NC + c) * HSTATE + (size_t)p * D_STATE + slot * 8;
        hv[k][0] = *(const float4*)hp;
        hv[k][1] = *(const float4*)(hp + 4);
    }
    float4 xv[4];
#pragma unroll
    for (int k = 0; k < 4; ++k) {
        const int q = tid + k * 256;
        const int s = q >> 4, p4 = (q & 15) * 4;
        xv[k] = *(const float4*)(xc + (size_t)(rowbase + s) * CONV_DIM + h * HEADDIM + p4);
    }
    __syncthreads();

    // ---- P1: G = C @ B^T
    const int fr = lane & 15;
    const int fs = lane >> 4;
    const int rA = w * 16 + fr;

    f32x4 g[4] = {};
#pragma unroll
    for (int pass = 0; pass < 3; ++pass) {
        const char* Ab = (const char*)(pass == 2 ? &Clo[0][0]  : &Chi[0][0]);
        const char* Bb = (const char*)(pass == 1 ? &BHlo[0][0] : &BHhi[0][0]);
#pragma unroll
        for (int kt = 0; kt < 4; ++kt) {
            const bf16x8 af = *(const bf16x8*)(Ab + rA * 256 + (((kt * 4 + fs) ^ (rA & 7)) << 4));
#pragma unroll
            for (int nt = 0; nt < 4; ++nt) {
                const int rb = nt * 16 + fr;
                const bf16x8 bf = *(const bf16x8*)(Bb + rb * 256 + (((kt * 4 + fs) ^ (rb & 7)) << 4));
                g[nt] = __builtin_amdgcn_mfma_f32_16x16x32_bf16(af, bf, g[nt], 0, 0, 0);
            }
        }
    }

    // build M; acc layout: col s = lane&15, row t = (lane>>4)*4 + j
    const float Dh = Dp[h];
#pragma unroll
    for (int nt = 0; nt < 4; ++nt) {
        const int s = nt * 16 + fr;
#pragma unroll
        for (int j = 0; j < 4; ++j) {
            const int t = w * 16 + fs * 4 + j;
            float m = 0.f;
            if (s <= t) {
                m = g[nt][j] * __expf(s_cums[t] - s_cums[s]) * s_dts[s];
                if (s == t) m += Dh;
            }
            const __hip_bfloat16 mh = __float2bfloat16(m);
            const __hip_bfloat16 ml = __float2bfloat16(m - __bfloat162float(mh));
            const int moff = t * 128 + ((((s >> 3) ^ (t & 7))) << 4) + ((s & 7) << 1);
            *(__hip_bfloat16*)((char*)&Mhi[0][0] + moff) = mh;
            *(__hip_bfloat16*)((char*)&Mlo[0][0] + moff) = ml;
        }
    }
    __syncthreads();

    // ---- P2: stage H into BH region; X^T into XT
#pragma unroll
    for (int k = 0; k < 4; ++k) {
        const int q = tid + k * 256;
        const int p = q >> 4, slot = q & 15;
        const int off = p * 256 + ((slot ^ (p & 7)) << 4);
        cvt_wr8(&BHhi[0][0], &BHlo[0][0], off, hv[k][0], hv[k][1]);
    }
#pragma unroll
    for (int k = 0; k < 4; ++k) {
        const int q = tid + k * 256;
        const int s = q >> 4, p4 = (q & 15) * 4;
        const float f[4] = {xv[k].x, xv[k].y, xv[k].z, xv[k].w};
#pragma unroll
        for (int j = 0; j < 4; ++j) {
            const int p = p4 + j;
            const __hip_bfloat16 xh = __float2bfloat16(f[j]);
            const __hip_bfloat16 xl = __float2bfloat16(f[j] - __bfloat162float(xh));
            const int off = p * 128 + ((((s >> 3) ^ (p & 7))) << 4) + ((s & 7) << 1);
            *(__hip_bfloat16*)((char*)&XThi[0][0] + off) = xh;
            *(__hip_bfloat16*)((char*)&XTlo[0][0] + off) = xl;
        }
    }
    __syncthreads();

    // ---- P3: acc = C@H^T ; acc *= Es[t] ; acc += M@X ; store
    f32x4 acc[4] = {};
#pragma unroll
    for (int pass = 0; pass < 3; ++pass) {
        const char* Ab = (const char*)(pass == 2 ? &Clo[0][0]  : &Chi[0][0]);
        const char* Bb = (const char*)(pass == 1 ? &BHlo[0][0] : &BHhi[0][0]);
#pragma unroll
        for (int kt = 0; kt < 4; ++kt) {
            const bf16x8 af = *(const bf16x8*)(Ab + rA * 256 + (((kt * 4 + fs) ^ (rA & 7)) << 4));
#pragma unroll
            for (int nt = 0; nt < 4; ++nt) {
                const int rp = nt * 16 + fr;
                const bf16x8 bf = *(const bf16x8*)(Bb + rp * 256 + (((kt * 4 + fs) ^ (rp & 7)) << 4));
                acc[nt] = __builtin_amdgcn_mfma_f32_16x16x32_bf16(af, bf, acc[nt], 0, 0, 0);
            }
        }
    }
#pragma unroll
    for (int nt = 0; nt < 4; ++nt)
#pragma unroll
        for (int j = 0; j < 4; ++j)
            acc[nt][j] *= s_Es[w * 16 + fs * 4 + j];

    const int rM = w * 16 + fr;
#pragma unroll
    for (int pass = 0; pass < 3; ++pass) {
        const char* Ab = (const char*)(pass == 2 ? &Mlo[0][0]  : &Mhi[0][0]);
        const char* Bb = (const char*)(pass == 1 ? &XTlo[0][0] : &XThi[0][0]);
#pragma unroll
        for (int kt = 0; kt < 2; ++kt) {
            const bf16x8 af = *(const bf16x8*)(Ab + rM * 128 + (((kt * 4 + fs) ^ (rM & 7)) << 4));
#pragma unroll
            for (int nt = 0; nt < 4; ++nt) {
                const int rp = nt * 16 + fr;
                const bf16x8 bf = *(const bf16x8*)(Bb + rp * 128 + (((kt * 4 + fs) ^ (rp & 7)) << 4));
                acc[nt] = __builtin_amdgcn_mfma_f32_16x16x32_bf16(af, bf, acc[nt], 0, 0, 0);
            }
        }
    }

#pragma unroll
    for (int nt = 0; nt < 4; ++nt) {
        const int p = nt * 16 + fr;
#pragma unroll
        for (int j = 0; j < 4; ++j) {
            const int t = w * 16 + fs * 4 + j;
            y[(size_t)(rowbase + t) * D_SSM + h * HEADDIM + p] = acc[nt][j];
        }
    }
}

// ---------------------------------------------------------------------------
// Fallback sequential scan.
// ---------------------------------------------------------------------------
__global__ __launch_bounds__(256) void scan_kernel(
    const float* __restrict__ xc, const float* __restrict__ dtw,
    const float* __restrict__ A_log, const float* __restrict__ Dp,
    float* __restrict__ y)
{
    const int b   = blockIdx.x / NHEADS;
    const int h   = blockIdx.x % NHEADS;
    const int tid = threadIdx.x;
    const int p   = tid >> 2;
    const int q   = tid & 3;

    __shared__ float dt_s[SEQLEN];
    __shared__ float Bs[4][36];
    __shared__ float Cs[4][36];
    __shared__ float xs[64];

    for (int i = tid; i < SEQLEN; i += 256)
        dt_s[i] = dtw[((size_t)b * SEQLEN + i) * NHEADS + h];

    const float Aneg = -__expf(A_log[h]);
    const float Dh   = Dp[h];

    float hst[32];
#pragma unroll
    for (int i = 0; i < 32; ++i) hst[i] = 0.f;

    const float* row0 = xc + (size_t)b * SEQLEN * CONV_DIM;
    float rBC = row0[D_SSM + tid];
    float rx  = (tid < 64) ? row0[h * HEADDIM + tid] : 0.f;

    for (int t = 0; t < SEQLEN; ++t) {
        __syncthreads();
        if (tid < 128) Bs[tid >> 5][tid & 31] = rBC;
        else           Cs[(tid >> 5) & 3][tid & 31] = rBC;
        if (tid < 64)  xs[tid] = rx;
        if (t + 1 < SEQLEN) {
            const float* rp = row0 + (size_t)(t + 1) * CONV_DIM;
            rBC = rp[D_SSM + tid];
            if (tid < 64) rx = rp[h * HEADDIM + tid];
        }
        __syncthreads();

        const float dtv = dt_s[t];
        const float dA  = __expf(dtv * Aneg);
        const float dtx = dtv * xs[p];
        float ysum = 0.f;
#pragma unroll
        for (int j4 = 0; j4 < 8; ++j4) {
            const float4 Bv = *(const float4*)&Bs[q][j4 * 4];
            const float4 Cv = *(const float4*)&Cs[q][j4 * 4];
            float* hp = &hst[j4 * 4];
            hp[0] = fmaf(hp[0], dA, dtx * Bv.x); ysum = fmaf(hp[0], Cv.x, ysum);
            hp[1] = fmaf(hp[1], dA, dtx * Bv.y); ysum = fmaf(hp[1], Cv.y, ysum);
            hp[2] = fmaf(hp[2], dA, dtx * Bv.z); ysum = fmaf(hp[2], Cv.z, ysum);
            hp[3] = fmaf(hp[3], dA, dtx * Bv.w); ysum = fmaf(hp[3], Cv.w, ysum);
        }
        ysum += __shfl_xor(ysum, 1);
        ysum += __shfl_xor(ysum, 2);
        if (q == 0)
            y[((size_t)b * SEQLEN + t) * D_SSM + h * HEADDIM + p] = ysum + Dh * xs[p];
    }
}

// ---------------------------------------------------------------------------
// Gate + RMSNorm -> bf16x3 rows (A-pattern [hi|hi|lo]).
// ---------------------------------------------------------------------------
__global__ __launch_bounds__(256) void gatenorm_x3_kernel(
    const float* __restrict__ y, const float* __restrict__ zbuf,
    const float* __restrict__ norm_w, __hip_bfloat16* __restrict__ ybx3)
{
    const int row = blockIdx.x;
    const int tid = threadIdx.x;
    const float* yr = y + (size_t)row * D_SSM;
    const float* zr = zbuf + (size_t)row * D_SSM;

    float v[6];
    float ss = 0.f;
#pragma unroll
    for (int i = 0; i < 6; ++i) {
        const int e = tid + i * 256;
        const float yv = yr[e];
        const float zv = zr[e];
        const float g  = yv * (zv * sigmoidf_(zv));
        v[i] = g;
        ss = fmaf(g, g, ss);
    }
#pragma unroll
    for (int m = 1; m < 64; m <<= 1) ss += __shfl_xor(ss, m);
    __shared__ float ws[4];
    if ((tid & 63) == 0) ws[tid >> 6] = ss;
    __syncthreads();
    const float tot = ws[0] + ws[1] + ws[2] + ws[3];
    const float r = rsqrtf(tot * (1.0f / D_SSM) + EPS);
    __hip_bfloat16* orow = ybx3 + (size_t)row * K3_OUT;
#pragma unroll
    for (int i = 0; i < 6; ++i) {
        const int e = tid + i * 256;
        const float g = v[i] * r * norm_w[e];
        const __hip_bfloat16 hi = __float2bfloat16(g);
        const __hip_bfloat16 lo = __float2bfloat16(g - __bfloat162float(hi));
        orow[e] = hi;
        orow[D_SSM + e] = hi;
        orow[2 * D_SSM + e] = lo;
    }
}

// ---------------------------------------------------------------------------
// Gate + RMSNorm in place (fallback path).
// ---------------------------------------------------------------------------
__global__ __launch_bounds__(256) void gatenorm_kernel(
    float* y, const float* __restrict__ zbuf, const float* __restrict__ norm_w)
{
    const int row = blockIdx.x;
    const int tid = threadIdx.x;
    float* yr = y + (size_t)row * D_SSM;
    const float* zr = zbuf + (size_t)row * D_SSM;

    float v[6];
    float ss = 0.f;
#pragma unroll
    for (int i = 0; i < 6; ++i) {
        const int e = tid + i * 256;
        const float yv = yr[e];
        const float zv = zr[e];
        const float g  = yv * (zv * sigmoidf_(zv));
        v[i] = g;
        ss = fmaf(g, g, ss);
    }
#pragma unroll
    for (int m = 1; m < 64; m <<= 1) ss += __shfl_xor(ss, m);
    __shared__ float ws[4];
    if ((tid & 63) == 0) ws[tid >> 6] = ss;
    __syncthreads();
    const float tot = ws[0] + ws[1] + ws[2] + ws[3];
    const float r = rsqrtf(tot * (1.0f / D_SSM) + EPS);
#pragma unroll
    for (int i = 0; i < 6; ++i) {
        const int e = tid + i * 256;
        yr[e] = v[i] * r * norm_w[e];
    }
}

// ---------------------------------------------------------------------------
extern "C" void kernel_launch(void* const* d_in, const int* in_sizes, int n_in,
                              void* d_out, int out_size, void* d_ws, size_t ws_size,
                              hipStream_t stream)
{
    const float* u       = (const float*)d_in[0];
    const float* W_in    = (const float*)d_in[1];
    const float* conv_w  = (const float*)d_in[2];
    const float* conv_b  = (const float*)d_in[3];
    const float* dt_bias = (const float*)d_in[4];
    const float* A_log   = (const float*)d_in[5];
    const float* Dp      = (const float*)d_in[6];
    const float* norm_w  = (const float*)d_in[7];
    const float* W_out   = (const float*)d_in[8];
    float* out = (float*)d_out;

    const size_t SZ_Z   = (size_t)NROWS * D_SSM;
    const size_t SZ_XBC = (size_t)NROWS * CONV_DIM;
    const size_t SZ_DT  = (size_t)NROWS * NHEADS;
    const size_t SZ_S   = (size_t)NBH * NC * HSTATE;
    const size_t SZ_CUM = (size_t)NBH * SEQLEN;

    const size_t need_new = (SZ_Z + SZ_S + SZ_Z + SZ_XBC + SZ_DT + SZ_CUM) * sizeof(float);
    const bool use_new = ws_size >= need_new;

    if (use_new) {
        float* zbuf = (float*)d_ws;
        float* Breg = zbuf + SZ_Z;     // xbc | Sbuf | ybx3
        float* Creg = Breg + SZ_S;     // u3 | yb
        float* Xreg = Creg + SZ_Z;     // W_in3 | xc | W_out3
        float* dtraw = Xreg + SZ_XBC;  // tail (never overlaid)
        float* cumws = dtraw + SZ_DT;

        float* xbc   = Breg;
        float* Sbuf  = Breg;
        __hip_bfloat16* ybx3 = (__hip_bfloat16*)Breg;
        __hip_bfloat16* u3   = (__hip_bfloat16*)Creg;
        float* yb    = Creg;
        __hip_bfloat16* W_in3  = (__hip_bfloat16*)Xreg;
        float* xc    = Xreg;
        __hip_bfloat16* W_out3 = (__hip_bfloat16*)Xreg;

        decompose3<1><<<(NROWS * (D_MODEL / 4) + 255) / 256, 256, 0, stream>>>(
            u, u3, NROWS, NROWS, D_MODEL);
        decompose3<0><<<(NPAD_IN * (D_MODEL / 4) + 255) / 256, 256, 0, stream>>>(
            W_in, W_in3, D_IN_PROJ, NPAD_IN, D_MODEL);

        // in-projection (1D grid, XCD-swizzled; 1728 = 8*216)
        gemm_bf16x3<1><<<(NPAD_IN / 128) * (NROWS / 128), 256, 0, stream>>>(
            u3, W_in3, zbuf, xbc, dtraw, 0, K3_IN, NPAD_IN / 128);

        conv_silu_kernel<<<(NROWS * (CONV_DIM / 4) + 255) / 256, 256, 0, stream>>>(
            xbc, conv_w, conv_b, xc);

        // chunked scan (dt inline from dtraw)
        chunk_state_mfma<<<NBH * NC, 256, 0, stream>>>(
            xc, dtraw, dt_bias, A_log, Sbuf, cumws);
        state_scan_kernel<<<dim3(NBH, HSTATE / 256), 256, 0, stream>>>(cumws, Sbuf);
        chunk_output_mfma<<<NBH * NC, 256, 0, stream>>>(
            xc, dtraw, dt_bias, Dp, Sbuf, cumws, yb);

        decompose3<0><<<(D_MODEL * (D_SSM / 4) + 255) / 256, 256, 0, stream>>>(
            W_out, W_out3, D_MODEL, D_MODEL, D_SSM);

        gatenorm_x3_kernel<<<NROWS, 256, 0, stream>>>(yb, zbuf, norm_w, ybx3);

        // out-projection (1D grid, XCD-swizzled; 384 = 8*48)
        gemm_bf16x3<0><<<(D_MODEL / 128) * (NROWS / 128), 256, 0, stream>>>(
            ybx3, W_out3, out, nullptr, nullptr, D_MODEL, K3_OUT, D_MODEL / 128);
    } else {
        float* zbuf  = (float*)d_ws;
        float* Rp    = zbuf + SZ_Z;
        float* xbc   = Rp;
        float* yb    = Rp;
        float* dtraw = Rp + SZ_XBC;
        float* xc    = dtraw + SZ_DT;
        float* dtw   = xc + SZ_XBC;

        gemm_inproj<<<dim3((D_IN_PROJ + 63) / 64, NROWS / 64), 256, 0, stream>>>(
            u, W_in, zbuf, xbc, dtraw);
        conv_silu_kernel<<<(NROWS * (CONV_DIM / 4) + 255) / 256, 256, 0, stream>>>(
            xbc, conv_w, conv_b, xc);
        dt_kernel<<<NROWS, 64, 0, stream>>>(dtraw, dt_bias, dtw);
        scan_kernel<<<NBH, 256, 0, stream>>>(xc, dtw, A_log, Dp, yb);
        gatenorm_kernel<<<NROWS, 256, 0, stream>>>(yb, zbuf, norm_w);
        gemm_nt<64, 64, 16><<<dim3(D_MODEL / 64, NROWS / 64), 256, 0, stream>>>(
            yb, W_out, out, NROWS, D_MODEL, D_SSM);
    }
}

// Round 9
// 633.492 us; speedup vs baseline: 4.1769x; 1.0980x over previous
//
#include <hip/hip_runtime.h>
#include <hip/hip_bf16.h>
#include <math.h>

#define D_MODEL   768
#define D_SSM     1536
#define D_STATE   128
#define D_CONV    4
#define HEADDIM   64
#define NHEADS    24
#define CONV_DIM  1792          // D_SSM + 2*D_STATE
#define D_IN_PROJ 3352          // 2*D_SSM + 2*D_STATE + NHEADS
#define BATCH     4
#define SEQLEN    2048
#define NROWS     (BATCH * SEQLEN)   // 8192
#define EPS       1e-5f

#define CHUNK     64
#define NC        (SEQLEN / CHUNK)    // 32
#define NBH       (BATCH * NHEADS)    // 96
#define HSTATE    (HEADDIM * D_STATE) // 8192

#define NPAD_IN   3456                // 27 * 128 (>= D_IN_PROJ)
#define K2_OUT    (2 * D_SSM)         // 3072

typedef __attribute__((ext_vector_type(8))) short bf16x8;
typedef __attribute__((ext_vector_type(4))) float f32x4;

__device__ __forceinline__ float sigmoidf_(float x) {
    return 1.0f / (1.0f + __expf(-x));
}

__device__ __forceinline__ float softplusf_(float x) {
    return fmaxf(x, 0.f) + log1pf(__expf(-fabsf(x)));
}

__device__ __forceinline__ void gload16(void* lds, const void* g) {
    __builtin_amdgcn_global_load_lds(
        (const __attribute__((address_space(1))) unsigned int*)g,
        (__attribute__((address_space(3))) unsigned int*)lds, 16, 0, 0);
}

// cvt 8 fp32 -> bf16 hi/lo planes, one b128 write each
__device__ __forceinline__ void cvt_wr8(__hip_bfloat16* hb, __hip_bfloat16* lb,
                                        int off, float4 a, float4 b)
{
    union { __hip_bfloat16 h[8]; uint4 u; } hi, lo;
    const float f[8] = {a.x, a.y, a.z, a.w, b.x, b.y, b.z, b.w};
#pragma unroll
    for (int j = 0; j < 8; ++j) {
        const __hip_bfloat16 h = __float2bfloat16(f[j]);
        hi.h[j] = h;
        lo.h[j] = __float2bfloat16(f[j] - __bfloat162float(h));
    }
    *(uint4*)((char*)hb + off) = hi.u;
    *(uint4*)((char*)lb + off) = lo.u;
}

// ---------------------------------------------------------------------------
// Decompose fp32 [R][K] -> bf16 [Rpad][2K] as [hi(K) | lo(K)].
// ---------------------------------------------------------------------------
__global__ __launch_bounds__(256) void decompose2(
    const float* __restrict__ X, __hip_bfloat16* __restrict__ X2,
    int R, int Rpad, int K)
{
    const int idx = blockIdx.x * 256 + threadIdx.x;
    if (idx >= Rpad * (K / 4)) return;
    const int r = idx / (K / 4);
    const int k = (idx % (K / 4)) * 4;

    union { __hip_bfloat16 h[4]; uint2 u; } phi, plo;
    if (r < R) {
        const float4 x = *(const float4*)(X + (size_t)r * K + k);
        const float xs[4] = {x.x, x.y, x.z, x.w};
#pragma unroll
        for (int j = 0; j < 4; ++j) {
            phi.h[j] = __float2bfloat16(xs[j]);
            plo.h[j] = __float2bfloat16(xs[j] - __bfloat162float(phi.h[j]));
        }
    } else {
#pragma unroll
        for (int j = 0; j < 4; ++j) { phi.h[j] = __float2bfloat16(0.f); plo.h[j] = phi.h[j]; }
    }
    __hip_bfloat16* row = X2 + (size_t)r * (2 * K);
    *(uint2*)(row + k)     = phi.u;
    *(uint2*)(row + K + k) = plo.u;
}

// ---------------------------------------------------------------------------
// MFMA GEMM (NT, split-fp32): C[M,N] = A*B^T with A,B stored [hi(K)|lo(K)].
// Per 32-K tile: stage 4 planes (Ahi/Alo/Bhi/Blo, each [128][32] with the
// proven slot-XOR swizzle + global_load_lds), 3 MFMAs per fragment pair
// (hi*hi + hi*lo + lo*hi) -> fp32-grade. 24 (in) / 48 (out) iterations.
// 128x128 tile, 4 waves, dbuf 64 KB LDS, bijective XCD swizzle (T1).
// ---------------------------------------------------------------------------
template<int MODE>
__global__ __launch_bounds__(256) void gemm_bf16x2(
    const __hip_bfloat16* __restrict__ Ab, const __hip_bfloat16* __restrict__ Bb,
    float* __restrict__ C0, float* __restrict__ C1, float* __restrict__ C2,
    int Nreal, int K, int nx)
{
    __shared__ __hip_bfloat16 AhiS[2][128][32];
    __shared__ __hip_bfloat16 AloS[2][128][32];
    __shared__ __hip_bfloat16 BhiS[2][128][32];
    __shared__ __hip_bfloat16 BloS[2][128][32];
    const int tid  = threadIdx.x;
    const int lane = tid & 63;
    const int w    = tid >> 6;
    const int wr   = w >> 1, wc = w & 1;

    // T1: bijective XCD swizzle (gridDim.x % 8 == 0)
    const int cpx = gridDim.x >> 3;
    const int swz = (blockIdx.x & 7) * cpx + (blockIdx.x >> 3);
    const int bm  = (swz / nx) * 128;
    const int bn  = (swz % nx) * 128;

    const __hip_bfloat16 *gAh[2], *gAl[2], *gBh[2], *gBl[2];
    int ldsrow[2];
#pragma unroll
    for (int i = 0; i < 2; ++i) {
        const int r  = w * 32 + i * 16 + (lane >> 2);
        const int sl = (lane & 3) ^ ((r ^ (r >> 2)) & 3);
        ldsrow[i] = w * 32 + i * 16;
        gAh[i] = Ab + (size_t)(bm + r) * (2 * K) + sl * 8;
        gAl[i] = gAh[i] + K;
        gBh[i] = Bb + (size_t)(bn + r) * (2 * K) + sl * 8;
        gBl[i] = gBh[i] + K;
    }

    int aoff[4], boff[4];
#pragma unroll
    for (int mi = 0; mi < 4; ++mi) {
        const int ra = wr * 64 + mi * 16 + (lane & 15);
        aoff[mi] = ra * 64 + (((lane >> 4) ^ ((ra ^ (ra >> 2)) & 3)) << 4);
        const int rb = wc * 64 + mi * 16 + (lane & 15);
        boff[mi] = rb * 64 + (((lane >> 4) ^ ((rb ^ (rb >> 2)) & 3)) << 4);
    }

    f32x4 acc[4][4] = {};

    const int nk = K / 32;
#pragma unroll
    for (int i = 0; i < 2; ++i) {
        gload16(&AhiS[0][ldsrow[i]][0], gAh[i]);
        gload16(&AloS[0][ldsrow[i]][0], gAl[i]);
        gload16(&BhiS[0][ldsrow[i]][0], gBh[i]);
        gload16(&BloS[0][ldsrow[i]][0], gBl[i]);
    }
    __syncthreads();

    int buf = 0;
    for (int kt = 0; kt < nk; ++kt) {
        if (kt + 1 < nk) {
            const int ko = (kt + 1) * 32;
#pragma unroll
            for (int i = 0; i < 2; ++i) {
                gload16(&AhiS[buf ^ 1][ldsrow[i]][0], gAh[i] + ko);
                gload16(&AloS[buf ^ 1][ldsrow[i]][0], gAl[i] + ko);
                gload16(&BhiS[buf ^ 1][ldsrow[i]][0], gBh[i] + ko);
                gload16(&BloS[buf ^ 1][ldsrow[i]][0], gBl[i] + ko);
            }
        }
        const char* ah = (const char*)&AhiS[buf][0][0];
        const char* al = (const char*)&AloS[buf][0][0];
        const char* bh = (const char*)&BhiS[buf][0][0];
        const char* bl = (const char*)&BloS[buf][0][0];
        bf16x8 fah[4], fal[4], fbh[4], fbl[4];
#pragma unroll
        for (int i = 0; i < 4; ++i) {
            fah[i] = *(const bf16x8*)(ah + aoff[i]);
            fal[i] = *(const bf16x8*)(al + aoff[i]);
            fbh[i] = *(const bf16x8*)(bh + boff[i]);
            fbl[i] = *(const bf16x8*)(bl + boff[i]);
        }
#pragma unroll
        for (int mi = 0; mi < 4; ++mi)
#pragma unroll
            for (int ni = 0; ni < 4; ++ni) {
                acc[mi][ni] = __builtin_amdgcn_mfma_f32_16x16x32_bf16(
                    fah[mi], fbh[ni], acc[mi][ni], 0, 0, 0);
                acc[mi][ni] = __builtin_amdgcn_mfma_f32_16x16x32_bf16(
                    fah[mi], fbl[ni], acc[mi][ni], 0, 0, 0);
                acc[mi][ni] = __builtin_amdgcn_mfma_f32_16x16x32_bf16(
                    fal[mi], fbh[ni], acc[mi][ni], 0, 0, 0);
            }
        __syncthreads();
        buf ^= 1;
    }

#pragma unroll
    for (int mi = 0; mi < 4; ++mi) {
        const int rn = bm + wr * 64 + mi * 16 + ((lane >> 4) << 2);
#pragma unroll
        for (int ni = 0; ni < 4; ++ni) {
            const int cn = bn + wc * 64 + ni * 16 + (lane & 15);
#pragma unroll
            for (int j = 0; j < 4; ++j) {
                const float v = acc[mi][ni][j];
                const int r = rn + j;
                if (MODE == 0) {
                    C0[(size_t)r * Nreal + cn] = v;
                } else {
                    if (cn < D_SSM)                 C0[(size_t)r * D_SSM + cn] = v;
                    else if (cn < D_SSM + CONV_DIM) C1[(size_t)r * CONV_DIM + (cn - D_SSM)] = v;
                    else if (cn < D_IN_PROJ)        C2[(size_t)r * NHEADS + (cn - D_SSM - CONV_DIM)] = v;
                }
            }
        }
    }
}

// ---------------------------------------------------------------------------
// fp32 GEMM kernels (fallback path only)
// ---------------------------------------------------------------------------
template<int BM, int BN, int BK>
__global__ __launch_bounds__(256) void gemm_nt(
    const float* __restrict__ A, const float* __restrict__ B,
    float* __restrict__ C, int M, int N, int K)
{
    __shared__ float As[BK][BM];
    __shared__ float Bs[BK][BN];
    const int tid = threadIdx.x;
    const int bm  = blockIdx.y * BM;
    const int bn  = blockIdx.x * BN;
    const int tm  = (tid & 15) << 2;
    const int tn  = (tid >> 4) << 2;
    const int am  = tid & 63;
    const int ak  = (tid >> 6) << 2;
    float acc[4][4] = {};
    for (int k0 = 0; k0 < K; k0 += BK) {
        const float4 av = *(const float4*)(A + (size_t)(bm + am) * K + (k0 + ak));
        float4 bv = make_float4(0.f, 0.f, 0.f, 0.f);
        if (bn + am < N)
            bv = *(const float4*)(B + (size_t)(bn + am) * K + (k0 + ak));
        __syncthreads();
        As[ak + 0][am] = av.x; As[ak + 1][am] = av.y;
        As[ak + 2][am] = av.z; As[ak + 3][am] = av.w;
        Bs[ak + 0][am] = bv.x; Bs[ak + 1][am] = bv.y;
        Bs[ak + 2][am] = bv.z; Bs[ak + 3][am] = bv.w;
        __syncthreads();
#pragma unroll
        for (int kk = 0; kk < BK; ++kk) {
            const float4 a4 = *(const float4*)&As[kk][tm];
            const float4 b4 = *(const float4*)&Bs[kk][tn];
            const float a[4]  = {a4.x, a4.y, a4.z, a4.w};
            const float bb[4] = {b4.x, b4.y, b4.z, b4.w};
#pragma unroll
            for (int i = 0; i < 4; ++i)
#pragma unroll
                for (int j = 0; j < 4; ++j)
                    acc[i][j] = fmaf(a[i], bb[j], acc[i][j]);
        }
    }
#pragma unroll
    for (int i = 0; i < 4; ++i)
#pragma unroll
        for (int j = 0; j < 4; ++j) {
            const int cn = bn + tn + j;
            if (cn < N)
                C[(size_t)(bm + tm + i) * N + cn] = acc[i][j];
        }
}

__global__ __launch_bounds__(256) void gemm_inproj(
    const float* __restrict__ A, const float* __restrict__ B,
    float* __restrict__ zbuf, float* __restrict__ xbc, float* __restrict__ dtraw)
{
    constexpr int BM = 64, BN = 64, BK = 16;
    __shared__ float As[BK][BM];
    __shared__ float Bs[BK][BN];
    const int tid = threadIdx.x;
    const int bm  = blockIdx.y * BM;
    const int bn  = blockIdx.x * BN;
    const int tm  = (tid & 15) << 2;
    const int tn  = (tid >> 4) << 2;
    const int am  = tid & 63;
    const int ak  = (tid >> 6) << 2;
    float acc[4][4] = {};
    for (int k0 = 0; k0 < D_MODEL; k0 += BK) {
        const float4 av = *(const float4*)(A + (size_t)(bm + am) * D_MODEL + (k0 + ak));
        float4 bv = make_float4(0.f, 0.f, 0.f, 0.f);
        if (bn + am < D_IN_PROJ)
            bv = *(const float4*)(B + (size_t)(bn + am) * D_MODEL + (k0 + ak));
        __syncthreads();
        As[ak + 0][am] = av.x; As[ak + 1][am] = av.y;
        As[ak + 2][am] = av.z; As[ak + 3][am] = av.w;
        Bs[ak + 0][am] = bv.x; Bs[ak + 1][am] = bv.y;
        Bs[ak + 2][am] = bv.z; Bs[ak + 3][am] = bv.w;
        __syncthreads();
#pragma unroll
        for (int kk = 0; kk < BK; ++kk) {
            const float4 a4 = *(const float4*)&As[kk][tm];
            const float4 b4 = *(const float4*)&Bs[kk][tn];
            const float a[4]  = {a4.x, a4.y, a4.z, a4.w};
            const float bb[4] = {b4.x, b4.y, b4.z, b4.w};
#pragma unroll
            for (int i = 0; i < 4; ++i)
#pragma unroll
                for (int j = 0; j < 4; ++j)
                    acc[i][j] = fmaf(a[i], bb[j], acc[i][j]);
        }
    }
    float* Cp; int ldc, cb, nlim = BN;
    if (bn < D_SSM)                  { Cp = zbuf;  ldc = D_SSM;    cb = bn; }
    else if (bn < D_SSM + CONV_DIM)  { Cp = xbc;   ldc = CONV_DIM; cb = bn - D_SSM; }
    else { Cp = dtraw; ldc = NHEADS; cb = bn - (D_SSM + CONV_DIM); nlim = NHEADS; }
#pragma unroll
    for (int i = 0; i < 4; ++i)
#pragma unroll
        for (int j = 0; j < 4; ++j)
            if (tn + j < nlim)
                Cp[(size_t)(bm + tm + i) * ldc + cb + tn + j] = acc[i][j];
}

// ---------------------------------------------------------------------------
// Depthwise causal conv (width 4) + bias + SiLU.
// ---------------------------------------------------------------------------
__global__ __launch_bounds__(256) void conv_silu_kernel(
    const float* __restrict__ xbc, const float* __restrict__ cw,
    const float* __restrict__ cb, float* __restrict__ xc)
{
    const int idx = blockIdx.x * 256 + threadIdx.x;
    if (idx >= NROWS * (CONV_DIM / 4)) return;
    const int row = idx / (CONV_DIM / 4);
    const int c   = (idx % (CONV_DIM / 4)) * 4;
    const int l   = row & (SEQLEN - 1);

    const float* base = xbc + (size_t)row * CONV_DIM + c;
    const float4 cbv = *(const float4*)(cb + c);
    float acc[4] = {cbv.x, cbv.y, cbv.z, cbv.w};
    const float* w = cw + (size_t)c * D_CONV;
#pragma unroll
    for (int k = 0; k < D_CONV; ++k) {
        const int ls = l + k - 3;
        if (ls >= 0) {
            const float4 xv = *(const float4*)(base + (ptrdiff_t)(k - 3) * CONV_DIM);
            acc[0] = fmaf(w[0 * D_CONV + k], xv.x, acc[0]);
            acc[1] = fmaf(w[1 * D_CONV + k], xv.y, acc[1]);
            acc[2] = fmaf(w[2 * D_CONV + k], xv.z, acc[2]);
            acc[3] = fmaf(w[3 * D_CONV + k], xv.w, acc[3]);
        }
    }
    float4 o;
    o.x = acc[0] * sigmoidf_(acc[0]);
    o.y = acc[1] * sigmoidf_(acc[1]);
    o.z = acc[2] * sigmoidf_(acc[2]);
    o.w = acc[3] * sigmoidf_(acc[3]);
    *(float4*)(xc + (size_t)row * CONV_DIM + c) = o;
}

// ---------------------------------------------------------------------------
// dt = softplus(dt_raw + dt_bias)   (fallback path only)
// ---------------------------------------------------------------------------
__global__ __launch_bounds__(64) void dt_kernel(
    const float* __restrict__ dtraw, const float* __restrict__ dt_bias,
    float* __restrict__ dtw)
{
    const int row = blockIdx.x;
    const int tid = threadIdx.x;
    if (tid < NHEADS)
        dtw[(size_t)row * NHEADS + tid] = softplusf_(dtraw[(size_t)row * NHEADS + tid] + dt_bias[tid]);
}

// ---------------------------------------------------------------------------
// Pass A, MFMA bf16x3: per block (bh,c), 4 waves; wave w owns p-rows
// [w*16, w*16+16). S[p][n] = sum_s (x[s][p]*wls[s]) * B[s][n], K=64 over s.
// ---------------------------------------------------------------------------
__global__ __launch_bounds__(256) void chunk_state_mfma(
    const float* __restrict__ xc, const float* __restrict__ dtraw,
    const float* __restrict__ dt_bias, const float* __restrict__ A_log,
    float* __restrict__ Sbuf, float* __restrict__ cumws)
{
    const int c  = blockIdx.x / NBH;
    const int bh = blockIdx.x % NBH;
    const int b  = bh / NHEADS, h = bh % NHEADS;
    const int tid  = threadIdx.x;
    const int lane = tid & 63;
    const int w    = tid >> 6;
    const int rowbase = b * SEQLEN + c * CHUNK;

    __shared__ float s_wls[CHUNK];
    __shared__ __align__(16) __hip_bfloat16 Ahi[CHUNK][CHUNK];
    __shared__ __align__(16) __hip_bfloat16 Alo[CHUNK][CHUNK];
    __shared__ __align__(16) __hip_bfloat16 Bhi[D_STATE][CHUNK];
    __shared__ __align__(16) __hip_bfloat16 Blo[D_STATE][CHUNK];

    float4 bv[8];
#pragma unroll
    for (int k = 0; k < 8; ++k) {
        const int q = tid + k * 256;
        const int s = q >> 5, n4 = (q & 31) * 4;
        bv[k] = *(const float4*)(xc + (size_t)(rowbase + s) * CONV_DIM + D_SSM + n4);
    }
    float4 xv[4];
#pragma unroll
    for (int k = 0; k < 4; ++k) {
        const int q = tid + k * 256;
        const int s = q >> 4, p4 = (q & 15) * 4;
        xv[k] = *(const float4*)(xc + (size_t)(rowbase + s) * CONV_DIM + h * HEADDIM + p4);
    }

    if (tid < CHUNK) {
        const float Aneg = -__expf(A_log[h]);
        const float dtv = softplusf_(dtraw[(size_t)(rowbase + tid) * NHEADS + h] + dt_bias[h]);
        float v = Aneg * dtv;
#pragma unroll
        for (int d = 1; d < 64; d <<= 1) {
            const float o = __shfl_up(v, d);
            if (lane >= d) v += o;
        }
        cumws[(size_t)bh * SEQLEN + c * CHUNK + tid] = v;
        const float clast = __shfl(v, 63);
        s_wls[tid] = __expf(clast - v) * dtv;
    }

#pragma unroll
    for (int k = 0; k < 8; ++k) {
        const int q = tid + k * 256;
        const int s = q >> 5, n4 = (q & 31) * 4;
        const float f[4] = {bv[k].x, bv[k].y, bv[k].z, bv[k].w};
#pragma unroll
        for (int j = 0; j < 4; ++j) {
            const int n = n4 + j;
            const __hip_bfloat16 hh = __float2bfloat16(f[j]);
            const __hip_bfloat16 ll = __float2bfloat16(f[j] - __bfloat162float(hh));
            const int off = n * 128 + ((((s >> 3) ^ (n & 7))) << 4) + ((s & 7) << 1);
            *(__hip_bfloat16*)((char*)&Bhi[0][0] + off) = hh;
            *(__hip_bfloat16*)((char*)&Blo[0][0] + off) = ll;
        }
    }
    __syncthreads();

#pragma unroll
    for (int k = 0; k < 4; ++k) {
        const int q = tid + k * 256;
        const int s = q >> 4, p4 = (q & 15) * 4;
        const float wl = s_wls[s];
        const float f[4] = {xv[k].x * wl, xv[k].y * wl, xv[k].z * wl, xv[k].w * wl};
#pragma unroll
        for (int j = 0; j < 4; ++j) {
            const int p = p4 + j;
            const __hip_bfloat16 hh = __float2bfloat16(f[j]);
            const __hip_bfloat16 ll = __float2bfloat16(f[j] - __bfloat162float(hh));
            const int off = p * 128 + ((((s >> 3) ^ (p & 7))) << 4) + ((s & 7) << 1);
            *(__hip_bfloat16*)((char*)&Ahi[0][0] + off) = hh;
            *(__hip_bfloat16*)((char*)&Alo[0][0] + off) = ll;
        }
    }
    __syncthreads();

    const int fr = lane & 15;
    const int fs = lane >> 4;
    const int rA = w * 16 + fr;
    f32x4 acc[8] = {};
#pragma unroll
    for (int pass = 0; pass < 3; ++pass) {
        const char* Ab = (const char*)(pass == 2 ? &Alo[0][0] : &Ahi[0][0]);
        const char* Bb = (const char*)(pass == 1 ? &Blo[0][0] : &Bhi[0][0]);
#pragma unroll
        for (int kh = 0; kh < 2; ++kh) {
            const int sl = kh * 4 + fs;
            const bf16x8 af = *(const bf16x8*)(Ab + rA * 128 + ((sl ^ (rA & 7)) << 4));
#pragma unroll
            for (int nt = 0; nt < 8; ++nt) {
                const int rB = nt * 16 + fr;
                const bf16x8 bf = *(const bf16x8*)(Bb + rB * 128 + ((sl ^ (rB & 7)) << 4));
                acc[nt] = __builtin_amdgcn_mfma_f32_16x16x32_bf16(af, bf, acc[nt], 0, 0, 0);
            }
        }
    }

    float* Sp = Sbuf + (size_t)(bh * NC + c) * HSTATE;
#pragma unroll
    for (int nt = 0; nt < 8; ++nt) {
        const int n = nt * 16 + fr;
#pragma unroll
        for (int j = 0; j < 4; ++j) {
            const int p = w * 16 + fs * 4 + j;
            Sp[(size_t)p * D_STATE + n] = acc[nt][j];
        }
    }
}

// ---------------------------------------------------------------------------
// Pass B: per-element scan over chunks, in-place S -> H_in.
// ---------------------------------------------------------------------------
__global__ __launch_bounds__(256) void state_scan_kernel(
    const float* __restrict__ cumws, float* __restrict__ Sbuf)
{
    const int bh = blockIdx.x;
    const int e  = blockIdx.y * 256 + threadIdx.x;
    float* base = Sbuf + (size_t)bh * NC * HSTATE + e;
    const float* cw = cumws + (size_t)bh * SEQLEN;
    float H = 0.f;
    for (int c = 0; c < NC; ++c) {
        const float P = __expf(cw[c * CHUNK + CHUNK - 1]);
        const float s = base[(size_t)c * HSTATE];
        base[(size_t)c * HSTATE] = H;
        H = fmaf(P, H, s);
    }
}

// ---------------------------------------------------------------------------
// Pass C, MFMA bf16x3.
// ---------------------------------------------------------------------------
__global__ __launch_bounds__(256) void chunk_output_mfma(
    const float* __restrict__ xc, const float* __restrict__ dtraw,
    const float* __restrict__ dt_bias, const float* __restrict__ Dp,
    const float* __restrict__ Hbuf, const float* __restrict__ cumws,
    float* __restrict__ y)
{
    const int c  = blockIdx.x / NBH;
    const int bh = blockIdx.x % NBH;
    const int b  = bh / NHEADS, h = bh % NHEADS;
    const int tid  = threadIdx.x;
    const int lane = tid & 63;
    const int w    = tid >> 6;
    const int rowbase = b * SEQLEN + c * CHUNK;

    __shared__ float s_cums[CHUNK], s_dts[CHUNK], s_Es[CHUNK];
    __shared__ __align__(16) __hip_bfloat16 Chi[CHUNK][D_STATE];
    __shared__ __align__(16) __hip_bfloat16 Clo[CHUNK][D_STATE];
    __shared__ __align__(16) __hip_bfloat16 BHhi[CHUNK][D_STATE];
    __shared__ __align__(16) __hip_bfloat16 BHlo[CHUNK][D_STATE];
    __shared__ __align__(16) __hip_bfloat16 Mhi[CHUNK][CHUNK];
    __shared__ __align__(16) __hip_bfloat16 Mlo[CHUNK][CHUNK];
    __shared__ __align__(16) __hip_bfloat16 XThi[CHUNK][CHUNK];
    __shared__ __align__(16) __hip_bfloat16 XTlo[CHUNK][CHUNK];

    float4 cv[4][2], bvv[4][2];
#pragma unroll
    for (int k = 0; k < 4; ++k) {
        const int q = tid + k * 256;
        const int row = q >> 4, slot = q & 15;
        const float* rp = xc + (size_t)(rowbase + row) * CONV_DIM + D_SSM;
        bvv[k][0] = *(const float4*)(rp + slot * 8);
        bvv[k][1] = *(const float4*)(rp + slot * 8 + 4);
        cv[k][0]  = *(const float4*)(rp + D_STATE + slot * 8);
        cv[k][1]  = *(const float4*)(rp + D_STATE + slot * 8 + 4);
    }
    if (tid < CHUNK) {
        const float cu = cumws[(size_t)bh * SEQLEN + c * CHUNK + tid];
        s_cums[tid] = cu;
        s_Es[tid]   = __expf(cu);
        s_dts[tid]  = softplusf_(dtraw[(size_t)(rowbase + tid) * NHEADS + h] + dt_bias[h]);
    }
#pragma unroll
    for (int k = 0; k < 4; ++k) {
        const int q = tid + k * 256;
        const int row = q >> 4, slot = q & 15;
        const int off = row * 256 + ((slot ^ (row & 7)) << 4);
        cvt_wr8(&Chi[0][0],  &Clo[0][0],  off, cv[k][0],  cv[k][1]);
        cvt_wr8(&BHhi[0][0], &BHlo[0][0], off, bvv[k][0], bvv[k][1]);
    }
    float4 hv[4][2];
#pragma unroll
    for (int k = 0; k < 4; ++k) {
        const int q = tid + k * 256;
        const int p = q >> 4, slot = q & 15;
        const float* hp = Hbuf + (size_t)(bh * NC + c) * HSTATE + (size_t)p * D_STATE + slot * 8;
        hv[k][0] = *(const float4*)hp;
        hv[k][1] = *(const float4*)(hp + 4);
    }
    float4 xv[4];
#pragma unroll
    for (int k = 0; k < 4; ++k) {
        const int q = tid + k * 256;
        const int s = q >> 4, p4 = (q & 15) * 4;
        xv[k] = *(const float4*)(xc + (size_t)(rowbase + s) * CONV_DIM + h * HEADDIM + p4);
    }
    __syncthreads();

    const int fr = lane & 15;
    const int fs = lane >> 4;
    const int rA = w * 16 + fr;

    f32x4 g[4] = {};
#pragma unroll
    for (int pass = 0; pass < 3; ++pass) {
        const char* Ab = (const char*)(pass == 2 ? &Clo[0][0]  : &Chi[0][0]);
        const char* Bb = (const char*)(pass == 1 ? &BHlo[0][0] : &BHhi[0][0]);
#pragma unroll
        for (int kt = 0; kt < 4; ++kt) {
            const bf16x8 af = *(const bf16x8*)(Ab + rA * 256 + (((kt * 4 + fs) ^ (rA & 7)) << 4));
#pragma unroll
            for (int nt = 0; nt < 4; ++nt) {
                const int rb = nt * 16 + fr;
                const bf16x8 bf = *(const bf16x8*)(Bb + rb * 256 + (((kt * 4 + fs) ^ (rb & 7)) << 4));
                g[nt] = __builtin_amdgcn_mfma_f32_16x16x32_bf16(af, bf, g[nt], 0, 0, 0);
            }
        }
    }

    const float Dh = Dp[h];
#pragma unroll
    for (int nt = 0; nt < 4; ++nt) {
        const int s = nt * 16 + fr;
#pragma unroll
        for (int j = 0; j < 4; ++j) {
            const int t = w * 16 + fs * 4 + j;
            float m = 0.f;
            if (s <= t) {
                m = g[nt][j] * __expf(s_cums[t] - s_cums[s]) * s_dts[s];
                if (s == t) m += Dh;
            }
            const __hip_bfloat16 mh = __float2bfloat16(m);
            const __hip_bfloat16 ml = __float2bfloat16(m - __bfloat162float(mh));
            const int moff = t * 128 + ((((s >> 3) ^ (t & 7))) << 4) + ((s & 7) << 1);
            *(__hip_bfloat16*)((char*)&Mhi[0][0] + moff) = mh;
            *(__hip_bfloat16*)((char*)&Mlo[0][0] + moff) = ml;
        }
    }
    __syncthreads();

#pragma unroll
    for (int k = 0; k < 4; ++k) {
        const int q = tid + k * 256;
        const int p = q >> 4, slot = q & 15;
        const int off = p * 256 + ((slot ^ (p & 7)) << 4);
        cvt_wr8(&BHhi[0][0], &BHlo[0][0], off, hv[k][0], hv[k][1]);
    }
#pragma unroll
    for (int k = 0; k < 4; ++k) {
        const int q = tid + k * 256;
        const int s = q >> 4, p4 = (q & 15) * 4;
        const float f[4] = {xv[k].x, xv[k].y, xv[k].z, xv[k].w};
#pragma unroll
        for (int j = 0; j < 4; ++j) {
            const int p = p4 + j;
            const __hip_bfloat16 xh = __float2bfloat16(f[j]);
            const __hip_bfloat16 xl = __float2bfloat16(f[j] - __bfloat162float(xh));
            const int off = p * 128 + ((((s >> 3) ^ (p & 7))) << 4) + ((s & 7) << 1);
            *(__hip_bfloat16*)((char*)&XThi[0][0] + off) = xh;
            *(__hip_bfloat16*)((char*)&XTlo[0][0] + off) = xl;
        }
    }
    __syncthreads();

    f32x4 acc[4] = {};
#pragma unroll
    for (int pass = 0; pass < 3; ++pass) {
        const char* Ab = (const char*)(pass == 2 ? &Clo[0][0]  : &Chi[0][0]);
        const char* Bb = (const char*)(pass == 1 ? &BHlo[0][0] : &BHhi[0][0]);
#pragma unroll
        for (int kt = 0; kt < 4; ++kt) {
            const bf16x8 af = *(const bf16x8*)(Ab + rA * 256 + (((kt * 4 + fs) ^ (rA & 7)) << 4));
#pragma unroll
            for (int nt = 0; nt < 4; ++nt) {
                const int rp = nt * 16 + fr;
                const bf16x8 bf = *(const bf16x8*)(Bb + rp * 256 + (((kt * 4 + fs) ^ (rp & 7)) << 4));
                acc[nt] = __builtin_amdgcn_mfma_f32_16x16x32_bf16(af, bf, acc[nt], 0, 0, 0);
            }
        }
    }
#pragma unroll
    for (int nt = 0; nt < 4; ++nt)
#pragma unroll
        for (int j = 0; j < 4; ++j)
            acc[nt][j] *= s_Es[w * 16 + fs * 4 + j];

    const int rM = w * 16 + fr;
#pragma unroll
    for (int pass = 0; pass < 3; ++pass) {
        const char* Ab = (const char*)(pass == 2 ? &Mlo[0][0]  : &Mhi[0][0]);
        const char* Bb = (const char*)(pass == 1 ? &XTlo[0][0] : &XThi[0][0]);
#pragma unroll
        for (int kt = 0; kt < 2; ++kt) {
            const bf16x8 af = *(const bf16x8*)(Ab + rM * 128 + (((kt * 4 + fs) ^ (rM & 7)) << 4));
#pragma unroll
            for (int nt = 0; nt < 4; ++nt) {
                const int rp = nt * 16 + fr;
                const bf16x8 bf = *(const bf16x8*)(Bb + rp * 128 + (((kt * 4 + fs) ^ (rp & 7)) << 4));
                acc[nt] = __builtin_amdgcn_mfma_f32_16x16x32_bf16(af, bf, acc[nt], 0, 0, 0);
            }
        }
    }

#pragma unroll
    for (int nt = 0; nt < 4; ++nt) {
        const int p = nt * 16 + fr;
#pragma unroll
        for (int j = 0; j < 4; ++j) {
            const int t = w * 16 + fs * 4 + j;
            y[(size_t)(rowbase + t) * D_SSM + h * HEADDIM + p] = acc[nt][j];
        }
    }
}

// ---------------------------------------------------------------------------
// Fallback sequential scan.
// ---------------------------------------------------------------------------
__global__ __launch_bounds__(256) void scan_kernel(
    const float* __restrict__ xc, const float* __restrict__ dtw,
    const float* __restrict__ A_log, const float* __restrict__ Dp,
    float* __restrict__ y)
{
    const int b   = blockIdx.x / NHEADS;
    const int h   = blockIdx.x % NHEADS;
    const int tid = threadIdx.x;
    const int p   = tid >> 2;
    const int q   = tid & 3;

    __shared__ float dt_s[SEQLEN];
    __shared__ float Bs[4][36];
    __shared__ float Cs[4][36];
    __shared__ float xs[64];

    for (int i = tid; i < SEQLEN; i += 256)
        dt_s[i] = dtw[((size_t)b * SEQLEN + i) * NHEADS + h];

    const float Aneg = -__expf(A_log[h]);
    const float Dh   = Dp[h];

    float hst[32];
#pragma unroll
    for (int i = 0; i < 32; ++i) hst[i] = 0.f;

    const float* row0 = xc + (size_t)b * SEQLEN * CONV_DIM;
    float rBC = row0[D_SSM + tid];
    float rx  = (tid < 64) ? row0[h * HEADDIM + tid] : 0.f;

    for (int t = 0; t < SEQLEN; ++t) {
        __syncthreads();
        if (tid < 128) Bs[tid >> 5][tid & 31] = rBC;
        else           Cs[(tid >> 5) & 3][tid & 31] = rBC;
        if (tid < 64)  xs[tid] = rx;
        if (t + 1 < SEQLEN) {
            const float* rp = row0 + (size_t)(t + 1) * CONV_DIM;
            rBC = rp[D_SSM + tid];
            if (tid < 64) rx = rp[h * HEADDIM + tid];
        }
        __syncthreads();

        const float dtv = dt_s[t];
        const float dA  = __expf(dtv * Aneg);
        const float dtx = dtv * xs[p];
        float ysum = 0.f;
#pragma unroll
        for (int j4 = 0; j4 < 8; ++j4) {
            const float4 Bv = *(const float4*)&Bs[q][j4 * 4];
            const float4 Cv = *(const float4*)&Cs[q][j4 * 4];
            float* hp = &hst[j4 * 4];
            hp[0] = fmaf(hp[0], dA, dtx * Bv.x); ysum = fmaf(hp[0], Cv.x, ysum);
            hp[1] = fmaf(hp[1], dA, dtx * Bv.y); ysum = fmaf(hp[1], Cv.y, ysum);
            hp[2] = fmaf(hp[2], dA, dtx * Bv.z); ysum = fmaf(hp[2], Cv.z, ysum);
            hp[3] = fmaf(hp[3], dA, dtx * Bv.w); ysum = fmaf(hp[3], Cv.w, ysum);
        }
        ysum += __shfl_xor(ysum, 1);
        ysum += __shfl_xor(ysum, 2);
        if (q == 0)
            y[((size_t)b * SEQLEN + t) * D_SSM + h * HEADDIM + p] = ysum + Dh * xs[p];
    }
}

// ---------------------------------------------------------------------------
// Gate + RMSNorm -> bf16x2 rows [hi(1536) | lo(1536)].
// ---------------------------------------------------------------------------
__global__ __launch_bounds__(256) void gatenorm_x2_kernel(
    const float* __restrict__ y, const float* __restrict__ zbuf,
    const float* __restrict__ norm_w, __hip_bfloat16* __restrict__ ybx2)
{
    const int row = blockIdx.x;
    const int tid = threadIdx.x;
    const float* yr = y + (size_t)row * D_SSM;
    const float* zr = zbuf + (size_t)row * D_SSM;

    float v[6];
    float ss = 0.f;
#pragma unroll
    for (int i = 0; i < 6; ++i) {
        const int e = tid + i * 256;
        const float yv = yr[e];
        const float zv = zr[e];
        const float g  = yv * (zv * sigmoidf_(zv));
        v[i] = g;
        ss = fmaf(g, g, ss);
    }
#pragma unroll
    for (int m = 1; m < 64; m <<= 1) ss += __shfl_xor(ss, m);
    __shared__ float ws[4];
    if ((tid & 63) == 0) ws[tid >> 6] = ss;
    __syncthreads();
    const float tot = ws[0] + ws[1] + ws[2] + ws[3];
    const float r = rsqrtf(tot * (1.0f / D_SSM) + EPS);
    __hip_bfloat16* orow = ybx2 + (size_t)row * K2_OUT;
#pragma unroll
    for (int i = 0; i < 6; ++i) {
        const int e = tid + i * 256;
        const float g = v[i] * r * norm_w[e];
        const __hip_bfloat16 hi = __float2bfloat16(g);
        const __hip_bfloat16 lo = __float2bfloat16(g - __bfloat162float(hi));
        orow[e] = hi;
        orow[D_SSM + e] = lo;
    }
}

// ---------------------------------------------------------------------------
// Gate + RMSNorm in place (fallback path).
// ---------------------------------------------------------------------------
__global__ __launch_bounds__(256) void gatenorm_kernel(
    float* y, const float* __restrict__ zbuf, const float* __restrict__ norm_w)
{
    const int row = blockIdx.x;
    const int tid = threadIdx.x;
    float* yr = y + (size_t)row * D_SSM;
    const float* zr = zbuf + (size_t)row * D_SSM;

    float v[6];
    float ss = 0.f;
#pragma unroll
    for (int i = 0; i < 6; ++i) {
        const int e = tid + i * 256;
        const float yv = yr[e];
        const float zv = zr[e];
        const float g  = yv * (zv * sigmoidf_(zv));
        v[i] = g;
        ss = fmaf(g, g, ss);
    }
#pragma unroll
    for (int m = 1; m < 64; m <<= 1) ss += __shfl_xor(ss, m);
    __shared__ float ws[4];
    if ((tid & 63) == 0) ws[tid >> 6] = ss;
    __syncthreads();
    const float tot = ws[0] + ws[1] + ws[2] + ws[3];
    const float r = rsqrtf(tot * (1.0f / D_SSM) + EPS);
#pragma unroll
    for (int i = 0; i < 6; ++i) {
        const int e = tid + i * 256;
        yr[e] = v[i] * r * norm_w[e];
    }
}

// ---------------------------------------------------------------------------
extern "C" void kernel_launch(void* const* d_in, const int* in_sizes, int n_in,
                              void* d_out, int out_size, void* d_ws, size_t ws_size,
                              hipStream_t stream)
{
    const float* u       = (const float*)d_in[0];
    const float* W_in    = (const float*)d_in[1];
    const float* conv_w  = (const float*)d_in[2];
    const float* conv_b  = (const float*)d_in[3];
    const float* dt_bias = (const float*)d_in[4];
    const float* A_log   = (const float*)d_in[5];
    const float* Dp      = (const float*)d_in[6];
    const float* norm_w  = (const float*)d_in[7];
    const float* W_out   = (const float*)d_in[8];
    float* out = (float*)d_out;

    const size_t SZ_Z   = (size_t)NROWS * D_SSM;
    const size_t SZ_XBC = (size_t)NROWS * CONV_DIM;
    const size_t SZ_DT  = (size_t)NROWS * NHEADS;
    const size_t SZ_S   = (size_t)NBH * NC * HSTATE;
    const size_t SZ_CUM = (size_t)NBH * SEQLEN;

    const size_t need_new = (SZ_Z + SZ_S + SZ_Z + SZ_XBC + SZ_DT + SZ_CUM) * sizeof(float);
    const bool use_new = ws_size >= need_new;

    if (use_new) {
        float* zbuf = (float*)d_ws;
        float* Breg = zbuf + SZ_Z;     // xbc | Sbuf | ybx2
        float* Creg = Breg + SZ_S;     // u2 | yb
        float* Xreg = Creg + SZ_Z;     // W_in2 | xc | W_out2
        float* dtraw = Xreg + SZ_XBC;  // tail (never overlaid)
        float* cumws = dtraw + SZ_DT;

        float* xbc   = Breg;
        float* Sbuf  = Breg;
        __hip_bfloat16* ybx2 = (__hip_bfloat16*)Breg;
        __hip_bfloat16* u2   = (__hip_bfloat16*)Creg;
        float* yb    = Creg;
        __hip_bfloat16* W_in2  = (__hip_bfloat16*)Xreg;
        float* xc    = Xreg;
        __hip_bfloat16* W_out2 = (__hip_bfloat16*)Xreg;

        decompose2<<<(NROWS * (D_MODEL / 4) + 255) / 256, 256, 0, stream>>>(
            u, u2, NROWS, NROWS, D_MODEL);
        decompose2<<<(NPAD_IN * (D_MODEL / 4) + 255) / 256, 256, 0, stream>>>(
            W_in, W_in2, D_IN_PROJ, NPAD_IN, D_MODEL);

        // in-projection (1D grid, XCD-swizzled; 1728 = 8*216)
        gemm_bf16x2<1><<<(NPAD_IN / 128) * (NROWS / 128), 256, 0, stream>>>(
            u2, W_in2, zbuf, xbc, dtraw, 0, D_MODEL, NPAD_IN / 128);

        conv_silu_kernel<<<(NROWS * (CONV_DIM / 4) + 255) / 256, 256, 0, stream>>>(
            xbc, conv_w, conv_b, xc);

        // chunked scan (dt inline from dtraw)
        chunk_state_mfma<<<NBH * NC, 256, 0, stream>>>(
            xc, dtraw, dt_bias, A_log, Sbuf, cumws);
        state_scan_kernel<<<dim3(NBH, HSTATE / 256), 256, 0, stream>>>(cumws, Sbuf);
        chunk_output_mfma<<<NBH * NC, 256, 0, stream>>>(
            xc, dtraw, dt_bias, Dp, Sbuf, cumws, yb);

        decompose2<<<(D_MODEL * (D_SSM / 4) + 255) / 256, 256, 0, stream>>>(
            W_out, W_out2, D_MODEL, D_MODEL, D_SSM);

        gatenorm_x2_kernel<<<NROWS, 256, 0, stream>>>(yb, zbuf, norm_w, ybx2);

        // out-projection (1D grid, XCD-swizzled; 384 = 8*48)
        gemm_bf16x2<0><<<(D_MODEL / 128) * (NROWS / 128), 256, 0, stream>>>(
            ybx2, W_out2, out, nullptr, nullptr, D_MODEL, D_SSM, D_MODEL / 128);
    } else {
        float* zbuf  = (float*)d_ws;
        float* Rp    = zbuf + SZ_Z;
        float* xbc   = Rp;
        float* yb    = Rp;
        float* dtraw = Rp + SZ_XBC;
        float* xc    = dtraw + SZ_DT;
        float* dtw   = xc + SZ_XBC;

        gemm_inproj<<<dim3((D_IN_PROJ + 63) / 64, NROWS / 64), 256, 0, stream>>>(
            u, W_in, zbuf, xbc, dtraw);
        conv_silu_kernel<<<(NROWS * (CONV_DIM / 4) + 255) / 256, 256, 0, stream>>>(
            xbc, conv_w, conv_b, xc);
        dt_kernel<<<NROWS, 64, 0, stream>>>(dtraw, dt_bias, dtw);
        scan_kernel<<<NBH, 256, 0, stream>>>(xc, dtw, A_log, Dp, yb);
        gatenorm_kernel<<<NROWS, 256, 0, stream>>>(yb, zbuf, norm_w);
        gemm_nt<64, 64, 16><<<dim3(D_MODEL / 64, NROWS / 64), 256, 0, stream>>>(
            yb, W_out, out, NROWS, D_MODEL, D_SSM);
    }
}